// Round 2
// baseline (5436.098 us; speedup 1.0000x reference)
//
#include <hip/hip_runtime.h>
#include <hip/hip_bf16.h>
#include <hip/hip_cooperative_groups.h>

namespace cg = cooperative_groups;

// Problem constants (from reference)
#define BB    512
#define TT    128
#define HID   1024
#define EMBD  512
#define VOC   1024
#define OUTN  1024
#define DIMG  2048
#define FOURH 4096

typedef __attribute__((ext_vector_type(8))) short  short8;   // 8 bf16 (MFMA A/B frag)
typedef __attribute__((ext_vector_type(4))) float  f32x4;    // MFMA C/D frag
typedef unsigned int u32;

// Wh_t interleave (gate in bits 4-5 of n): n = G*64 + gate*16 + u  -> orig gate*1024 + G*16 + u
__device__ __forceinline__ int hmap(int n) {
    return ((n >> 4) & 3) * HID + ((n >> 6) << 4) + (n & 15);
}
// eproj interleave (gate in bits 0-1 of n): n = G*64 + u*4 + gate -> orig gate*1024 + G*16 + u
// (lets the step kernel fetch all 4 gate preacts for (row, u) with ONE short4 load)
__device__ __forceinline__ int xmap(int n) {
    return (n & 3) * HID + ((n >> 6) << 4) + ((n >> 2) & 15);
}
__device__ __forceinline__ float sigmoidf_(float x) { return 1.0f / (1.0f + expf(-x)); }
__device__ __forceinline__ short f2bf(float x) { __hip_bfloat16 b = __float2bfloat16(x); return *(short*)&b; }
__device__ __forceinline__ float bf2f(short s) { __hip_bfloat16 b; *(short*)&b = s; return __bfloat162float(b); }

// async global->LDS, 16B per lane; lds base wave-uniform (HW adds lane*16)
__device__ __forceinline__ void async_cp16(void* lds, const void* g) {
    __builtin_amdgcn_global_load_lds((const __attribute__((address_space(1))) u32*)g,
                                     (__attribute__((address_space(3))) u32*)lds, 16, 0, 0);
}

// raw workgroup barrier with compiler memory fences (no vmcnt/lgkmcnt drain)
__device__ __forceinline__ void block_bar() {
    asm volatile("" ::: "memory");
    __builtin_amdgcn_s_barrier();
    asm volatile("" ::: "memory");
}

// ---------------------------------------------------------------------------
// Merged prep (one launch): blocks [0,3584) elementwise setup; blocks
// [3584, 3584+9216) the four tiled weight transposes out[n][k] = bf16(in[k][map(n)]).
// mapmode: 0 none, 1 hmap (Wh), 2 xmap (Wx/eproj layout).
__global__ void prep_k(const float* __restrict__ images, short* __restrict__ imgs_c,
                       const float* __restrict__ embed,  short* __restrict__ embed_c,
                       float* __restrict__ c, short* __restrict__ h0,
                       float* __restrict__ o0, float* __restrict__ o1,
                       const float* __restrict__ bimg, const float* __restrict__ bhid,
                       const float* __restrict__ Wc_h, short* __restrict__ Wh_t,
                       const float* __restrict__ Wc_x, short* __restrict__ Wx_t,
                       const float* __restrict__ Wimg, short* __restrict__ Wimg_t,
                       const float* __restrict__ Whid, short* __restrict__ Whid_t) {
    if (blockIdx.x < 3584) {
        int i = blockIdx.x * 256 + threadIdx.x;
        if (i < 262144) {                       // images: 512*2048/4
            float4 v = ((const float4*)images)[i];
            short4 o; o.x = f2bf(v.x); o.y = f2bf(v.y); o.z = f2bf(v.z); o.w = f2bf(v.w);
            ((short4*)imgs_c)[i] = o;
        } else if (i < 393216) {                // embed: 1024*512/4
            int k = i - 262144;
            float4 v = ((const float4*)embed)[k];
            short4 o; o.x = f2bf(v.x); o.y = f2bf(v.y); o.z = f2bf(v.z); o.w = f2bf(v.w);
            ((short4*)embed_c)[k] = o;
        } else {                                // state/out init: 512*1024
            int k = i - 393216;
            int n = k & (OUTN - 1);
            c[k] = 0.0f; h0[k] = 0;
            o0[k] = bimg[n]; o1[k] = bhid[n];
        }
        return;
    }
    int id = blockIdx.x - 3584;
    const float* in; short* out; int K, N_in, bx, by, mapmode;
    if (id < 4096)      { in = Wc_h; out = Wh_t;   K = 1024; N_in = 4096; mapmode = 1; bx = id & 127;  by = id >> 7; }
    else if (id < 6144) { id -= 4096; id = id;     in = Wc_x; out = Wx_t; K = 512;  N_in = 4096; mapmode = 2; bx = id & 127;  by = id >> 7; }
    else if (id < 8192) { id -= 6144; in = Wimg; out = Wimg_t; K = 2048; N_in = 1024; mapmode = 0; bx = id & 31; by = id >> 5; }
    else                { id -= 8192; in = Whid; out = Whid_t; K = 1024; N_in = 1024; mapmode = 0; bx = id & 31; by = id >> 5; }

    __shared__ short tile[32][33];
    int n0 = bx * 32, k0 = by * 32;
    int tx = threadIdx.x & 31, ty = threadIdx.x >> 5;   // 32 x 8
    int nn = n0 + tx;
    int nsrc = (mapmode == 1) ? hmap(nn) : (mapmode == 2) ? xmap(nn) : nn;
#pragma unroll
    for (int j = 0; j < 4; j++) {
        int kw = ty + j * 8;
        tile[kw][tx] = f2bf(in[(size_t)(k0 + kw) * N_in + nsrc]);
    }
    __syncthreads();
#pragma unroll
    for (int j = 0; j < 4; j++) {
        int nw = ty + j * 8;
        out[(size_t)(n0 + nw) * K + k0 + tx] = tile[tx][nw];
    }
}

// ---------------------------------------------------------------------------
// Double-buffered MFMA core, tile 64x128, BK=64, 4 waves 2x2 (used for the
// three one-shot GEMMs only). MAPB=true (eproj) uses the xmap bias order.
template<typename OutT, bool ATOMIC, bool MAPB>
__global__ __launch_bounds__(256) void gemm_bt_k(
    const short* __restrict__ A, const short* __restrict__ Bt,
    const float* __restrict__ bias, OutT* __restrict__ out,
    int Kf, int niter, int N)
{
    __shared__ __align__(16) short As[2][2][64 * 32];
    __shared__ __align__(16) short Bs[2][2][128 * 32];
    const int tid  = threadIdx.x;
    const int lane = tid & 63, wid = tid >> 6;
    const int wm = wid >> 1, wn = wid & 1;
    const int col16 = lane & 15, quad = lane >> 4;
    const int m0 = blockIdx.y * 64;
    const int n0 = blockIdx.x * 128;
    const int kbeg = blockIdx.z * niter * 64;

    const short* agp = A  + (size_t)(m0 + wid * 16 + (lane >> 2)) * Kf + kbeg + (lane & 3) * 8;
    const short* bgp = Bt + (size_t)(n0 + wid * 32 + (lane >> 2)) * Kf + kbeg + (lane & 3) * 8;

    f32x4 acc[2][4];
#pragma unroll
    for (int i = 0; i < 2; i++)
#pragma unroll
        for (int jj = 0; jj < 4; jj++) acc[i][jj] = (f32x4)0.0f;

    async_cp16(&As[0][0][wid * 512], agp);
    async_cp16(&As[0][1][wid * 512], agp + 32);
    async_cp16(&Bs[0][0][wid * 1024],       bgp);
    async_cp16(&Bs[0][0][wid * 1024 + 512], bgp + (size_t)16 * Kf);
    async_cp16(&Bs[0][1][wid * 1024],       bgp + 32);
    async_cp16(&Bs[0][1][wid * 1024 + 512], bgp + (size_t)16 * Kf + 32);
    __syncthreads();

    int buf = 0;
#pragma unroll 1
    for (int it = 0; it < niter; ++it) {
        if (it + 1 < niter) {
            int k0 = (it + 1) * 64;
            async_cp16(&As[buf ^ 1][0][wid * 512], agp + k0);
            async_cp16(&As[buf ^ 1][1][wid * 512], agp + k0 + 32);
            async_cp16(&Bs[buf ^ 1][0][wid * 1024],       bgp + k0);
            async_cp16(&Bs[buf ^ 1][0][wid * 1024 + 512], bgp + (size_t)16 * Kf + k0);
            async_cp16(&Bs[buf ^ 1][1][wid * 1024],       bgp + k0 + 32);
            async_cp16(&Bs[buf ^ 1][1][wid * 1024 + 512], bgp + (size_t)16 * Kf + k0 + 32);
        }
        short8 af[2][2], bf[4][2];
#pragma unroll
        for (int tr = 0; tr < 2; tr++)
#pragma unroll
            for (int p = 0; p < 2; p++)
                af[tr][p] = *(const short8*)&As[buf][p][(wm * 32 + tr * 16 + col16) * 32 + quad * 8];
#pragma unroll
        for (int tc = 0; tc < 4; tc++)
#pragma unroll
            for (int p = 0; p < 2; p++)
                bf[tc][p] = *(const short8*)&Bs[buf][p][(wn * 64 + tc * 16 + col16) * 32 + quad * 8];
#pragma unroll
        for (int p = 0; p < 2; p++)
#pragma unroll
            for (int tr = 0; tr < 2; tr++)
#pragma unroll
                for (int tc = 0; tc < 4; tc++)
                    acc[tr][tc] = __builtin_amdgcn_mfma_f32_16x16x32_bf16(af[tr][p], bf[tc][p], acc[tr][tc], 0, 0, 0);
        __syncthreads();
        buf ^= 1;
    }

#pragma unroll
    for (int tr = 0; tr < 2; tr++)
#pragma unroll
        for (int tc = 0; tc < 4; tc++) {
            int colg = n0 + wn * 64 + tc * 16 + col16;
            float bv = 0.0f;
            if constexpr (!ATOMIC) bv = bias[MAPB ? xmap(colg) : colg];
#pragma unroll
            for (int r = 0; r < 4; r++) {
                int rowg = m0 + wm * 32 + tr * 16 + quad * 4 + r;
                float v = acc[tr][tc][r] + bv;
                if constexpr (ATOMIC) atomicAdd((float*)&out[(size_t)rowg * N + colg], v);
                else                  out[(size_t)rowg * N + colg] = f2bf(v);
            }
        }
}

// ---------------------------------------------------------------------------
// Persistent cooperative LSTM: all 128 steps in one launch, grid 32x8 = 256
// blocks = 1 block/CU (forced by 160KB LDS). Per step: grid.sync() is the h
// ordering point; gathers + (step-invariant) staging are issued BEFORE the sync
// so their latency hides under the barrier wait. c-state lives in registers for
// all 128 steps (each block owns a fixed 64x32 c slice). B tiles 0,1 (64KB) are
// staged ONCE into a persistent LDS region and reused every step.
// LDS (shorts): As dbuf 2x8192 | Bs dbuf 2x16384 | Bperm 2x16384  = 160 KB.
__global__ __launch_bounds__(256, 1) void lstm_all_k(
    const short* __restrict__ Wh_t, const short* __restrict__ eproj,
    const int* __restrict__ msg,
    short* __restrict__ h_a, short* __restrict__ h_b)
{
    constexpr int Kf = HID;
    extern __shared__ __align__(16) short smem[];
    short* As = smem;            // [2][8192]
    short* Bs = smem + 16384;    // [2][16384]
    short* Bp = smem + 49152;    // [2][16384] persistent B tiles 0,1

    const int tid  = threadIdx.x;
    const int lane = tid & 63, wid = tid >> 6;
    const int wm = wid >> 1, wn = wid & 1;
    const int col16 = lane & 15, quad = lane >> 4;
    const int m0 = blockIdx.y * 64;
    const int n0 = blockIdx.x * 128;

    const int swz_st = (((lane & 3) - ((lane >> 3) & 3)) & 3) * 8;
    const size_t aoff = (size_t)(m0 + wid * 16 + (lane >> 2)) * Kf + swz_st;
    const short* agpA = h_a + aoff;
    const short* agpB = h_b + aoff;
    const short* bgp0 = Wh_t + (size_t)(n0 + wid * 32 + (lane >> 2)) * Kf + swz_st;
    const short* bgp1 = bgp0 + (size_t)16 * Kf;

    const int G = (n0 + wn * 64) >> 6;
    const int j = G * 16 + col16;
    const short* egbase = eproj + G * 64 + col16 * 4;   // + v*FOURH -> short4 of 4 gates

    int moff[2][4];      // msg row bases
    int hoff[2][4];      // h/c element offsets (b*HID + j)
#pragma unroll
    for (int tr = 0; tr < 2; tr++)
#pragma unroll
        for (int r = 0; r < 4; r++) {
            int b = m0 + wm * 32 + tr * 16 + quad * 4 + r;
            moff[tr][r] = b * TT;
            hoff[tr][r] = b * HID + j;
        }

    const int swz_rd = ((quad + (col16 >> 1)) & 3) * 8;
    const int arow = (wm * 32 + col16) * 32 + swz_rd;   // + tr*512
    const int brow = (wn * 64 + col16) * 32 + swz_rd;   // + tc*512

    float creg[2][4];
#pragma unroll
    for (int tr = 0; tr < 2; tr++)
#pragma unroll
        for (int r = 0; r < 4; r++) creg[tr][r] = 0.0f;

    // persistent B tiles 0,1 -> Bp (once; drained by the first grid.sync)
#pragma unroll
    for (int p = 0; p < 4; p++) {
        async_cp16(&Bp[p * 4096 + wid * 1024],       bgp0 + p * 32);
        async_cp16(&Bp[p * 4096 + wid * 1024 + 512], bgp1 + p * 32);
        async_cp16(&Bp[16384 + p * 4096 + wid * 1024],       bgp0 + 128 + p * 32);
        async_cp16(&Bp[16384 + p * 4096 + wid * 1024 + 512], bgp1 + 128 + p * 32);
    }

    cg::grid_group grid = cg::this_grid();

#pragma unroll 1
    for (int t = 0; t < TT; ++t) {
        const short* agp = (t & 1) ? agpB : agpA;
        short* hw        = (t & 1) ? h_a : h_b;

        // gate preactivation gather (h-independent; one short4 = all 4 gates)
        float gi[2][4][4];
#pragma unroll
        for (int tr = 0; tr < 2; tr++)
#pragma unroll
            for (int r = 0; r < 4; r++) {
                int v = msg[moff[tr][r] + t];
                short4 s4 = *(const short4*)(egbase + (size_t)v * FOURH);
                gi[tr][0][r] = bf2f(s4.x);
                gi[tr][1][r] = bf2f(s4.y);
                gi[tr][2][r] = bf2f(s4.z);
                gi[tr][3][r] = bf2f(s4.w);
            }

        grid.sync();   // h_{t-1} device-visible; drains all outstanding vmem

        // A tiles 0,1 (depend on h)
#pragma unroll
        for (int p = 0; p < 4; p++)
            async_cp16(&As[p * 2048 + wid * 512], agp + p * 32);
#pragma unroll
        for (int p = 0; p < 4; p++)
            async_cp16(&As[8192 + p * 2048 + wid * 512], agp + 128 + p * 32);

        f32x4 acc[2][4];
#pragma unroll
        for (int i = 0; i < 2; i++)
#pragma unroll
            for (int jj = 0; jj < 4; jj++) acc[i][jj] = (f32x4)0.0f;

        asm volatile("s_waitcnt vmcnt(4)" ::: "memory");   // A0 landed (A1 may fly)
        block_bar();

        int buf = 0;
#pragma unroll 1
        for (int it = 0; it < 8; ++it) {
            const short* Ab = &As[buf * 8192];
            const short* Bb = (it < 2) ? &Bp[it * 16384] : &Bs[buf * 16384];
            __builtin_amdgcn_s_setprio(1);
#pragma unroll
            for (int p = 0; p < 4; p++) {
                short8 af0 = *(const short8*)&Ab[p * 2048 + arow];
                short8 af1 = *(const short8*)&Ab[p * 2048 + arow + 512];
                short8 bf0 = *(const short8*)&Bb[p * 4096 + brow];
                short8 bf1 = *(const short8*)&Bb[p * 4096 + brow + 512];
                short8 bf2 = *(const short8*)&Bb[p * 4096 + brow + 1024];
                short8 bf3 = *(const short8*)&Bb[p * 4096 + brow + 1536];
                acc[0][0] = __builtin_amdgcn_mfma_f32_16x16x32_bf16(af0, bf0, acc[0][0], 0, 0, 0);
                acc[0][1] = __builtin_amdgcn_mfma_f32_16x16x32_bf16(af0, bf1, acc[0][1], 0, 0, 0);
                acc[0][2] = __builtin_amdgcn_mfma_f32_16x16x32_bf16(af0, bf2, acc[0][2], 0, 0, 0);
                acc[0][3] = __builtin_amdgcn_mfma_f32_16x16x32_bf16(af0, bf3, acc[0][3], 0, 0, 0);
                acc[1][0] = __builtin_amdgcn_mfma_f32_16x16x32_bf16(af1, bf0, acc[1][0], 0, 0, 0);
                acc[1][1] = __builtin_amdgcn_mfma_f32_16x16x32_bf16(af1, bf1, acc[1][1], 0, 0, 0);
                acc[1][2] = __builtin_amdgcn_mfma_f32_16x16x32_bf16(af1, bf2, acc[1][2], 0, 0, 0);
                acc[1][3] = __builtin_amdgcn_mfma_f32_16x16x32_bf16(af1, bf3, acc[1][3], 0, 0, 0);
            }
            __builtin_amdgcn_s_setprio(0);

            block_bar();   // all waves done READING buf / Bp(it)

            if (it < 6) {
                const int k0 = (it + 2) * 128;     // tile it+2 -> As[buf], Bs[buf]
#pragma unroll
                for (int p = 0; p < 4; p++) {
                    async_cp16(&As[buf * 8192 + p * 2048 + wid * 512], agp + k0 + p * 32);
                    async_cp16(&Bs[buf * 16384 + p * 4096 + wid * 1024],       bgp0 + k0 + p * 32);
                    async_cp16(&Bs[buf * 16384 + p * 4096 + wid * 1024 + 512], bgp1 + k0 + p * 32);
                }
                // outstanding: 12 (tile it+1) + 12 (tile it+2) -> wait it+1 landed,
                // it+2 stays in flight across the barrier.
                asm volatile("s_waitcnt vmcnt(12)" ::: "memory");
            } else if (it == 6) {
                asm volatile("s_waitcnt vmcnt(0)" ::: "memory");   // tile7 landed
            }
            if (it < 7) block_bar();
            buf ^= 1;
        }

        // fused cell update; c stays in registers across all steps
#pragma unroll
        for (int tr = 0; tr < 2; tr++)
#pragma unroll
            for (int r = 0; r < 4; r++) {
                float i_ = acc[tr][0][r] + gi[tr][0][r];
                float g_ = acc[tr][1][r] + gi[tr][1][r];
                float f_ = acc[tr][2][r] + gi[tr][2][r];
                float o_ = acc[tr][3][r] + gi[tr][3][r];
                float cn = sigmoidf_(f_ + 1.0f) * creg[tr][r] + sigmoidf_(i_) * tanhf(g_);
                creg[tr][r] = cn;
                hw[hoff[tr][r]] = f2bf(sigmoidf_(o_) * tanhf(cn));
            }
    }
}

// ---------------------------------------------------------------------------
// Fallback per-step kernel (R1-proven; used only if cooperative launch fails).
// Updated for the new eproj layout (short4 gate gather).
__global__ __launch_bounds__(256) void lstm_step_k(
    const short* __restrict__ h_prev, const short* __restrict__ Wh_t,
    const short* __restrict__ eproj, const int* __restrict__ msg, int t,
    float* __restrict__ c, short* __restrict__ h_next)
{
    constexpr int Kf = HID;
    extern __shared__ __align__(16) short smem[];
    short* As = smem;           // [2][4][2048] shorts
    short* Bs = smem + 16384;   // [2][4][4096] shorts

    const int tid  = threadIdx.x;
    const int lane = tid & 63, wid = tid >> 6;
    const int wm = wid >> 1, wn = wid & 1;
    const int col16 = lane & 15, quad = lane >> 4;
    const int m0 = blockIdx.y * 64;
    const int n0 = blockIdx.x * 128;

    const int swz_st = (((lane & 3) - ((lane >> 3) & 3)) & 3) * 8;
    const short* agp  = h_prev + (size_t)(m0 + wid * 16 + (lane >> 2)) * Kf + swz_st;
    const short* bgp0 = Wh_t   + (size_t)(n0 + wid * 32 + (lane >> 2)) * Kf + swz_st;
    const short* bgp1 = bgp0 + (size_t)16 * Kf;

    const int G = (n0 + wn * 64) >> 6;
    const int j = G * 16 + col16;
    float gi[2][4][4], cold[2][4];
#pragma unroll
    for (int tr = 0; tr < 2; tr++)
#pragma unroll
        for (int r = 0; r < 4; r++) {
            int b = m0 + wm * 32 + tr * 16 + quad * 4 + r;
            int v = msg[b * TT + t];
            short4 s4 = *(const short4*)(eproj + (size_t)v * FOURH + G * 64 + col16 * 4);
            gi[tr][0][r] = bf2f(s4.x);
            gi[tr][1][r] = bf2f(s4.y);
            gi[tr][2][r] = bf2f(s4.z);
            gi[tr][3][r] = bf2f(s4.w);
            cold[tr][r] = c[(size_t)b * HID + j];
        }

#pragma unroll
    for (int p = 0; p < 4; p++) {
        async_cp16(&As[p * 2048 + wid * 512], agp + p * 32);
        async_cp16(&Bs[p * 4096 + wid * 1024],       bgp0 + p * 32);
        async_cp16(&Bs[p * 4096 + wid * 1024 + 512], bgp1 + p * 32);
    }
#pragma unroll
    for (int p = 0; p < 4; p++) {
        async_cp16(&As[8192 + p * 2048 + wid * 512], agp + 128 + p * 32);
        async_cp16(&Bs[16384 + p * 4096 + wid * 1024],       bgp0 + 128 + p * 32);
        async_cp16(&Bs[16384 + p * 4096 + wid * 1024 + 512], bgp1 + 128 + p * 32);
    }

    f32x4 acc[2][4];
#pragma unroll
    for (int i = 0; i < 2; i++)
#pragma unroll
        for (int jj = 0; jj < 4; jj++) acc[i][jj] = (f32x4)0.0f;

    const int swz_rd = ((quad + (col16 >> 1)) & 3) * 8;
    const int arow = (wm * 32 + col16) * 32 + swz_rd;
    const int brow = (wn * 64 + col16) * 32 + swz_rd;

    asm volatile("s_waitcnt vmcnt(12)" ::: "memory");
    block_bar();

    int buf = 0;
#pragma unroll 1
    for (int it = 0; it < 8; ++it) {
        const short* Ab = &As[buf * 8192];
        const short* Bb = &Bs[buf * 16384];
        __builtin_amdgcn_s_setprio(1);
#pragma unroll
        for (int p = 0; p < 4; p++) {
            short8 af0 = *(const short8*)&Ab[p * 2048 + arow];
            short8 af1 = *(const short8*)&Ab[p * 2048 + arow + 512];
            short8 bf0 = *(const short8*)&Bb[p * 4096 + brow];
            short8 bf1 = *(const short8*)&Bb[p * 4096 + brow + 512];
            short8 bf2 = *(const short8*)&Bb[p * 4096 + brow + 1024];
            short8 bf3 = *(const short8*)&Bb[p * 4096 + brow + 1536];
            acc[0][0] = __builtin_amdgcn_mfma_f32_16x16x32_bf16(af0, bf0, acc[0][0], 0, 0, 0);
            acc[0][1] = __builtin_amdgcn_mfma_f32_16x16x32_bf16(af0, bf1, acc[0][1], 0, 0, 0);
            acc[0][2] = __builtin_amdgcn_mfma_f32_16x16x32_bf16(af0, bf2, acc[0][2], 0, 0, 0);
            acc[0][3] = __builtin_amdgcn_mfma_f32_16x16x32_bf16(af0, bf3, acc[0][3], 0, 0, 0);
            acc[1][0] = __builtin_amdgcn_mfma_f32_16x16x32_bf16(af1, bf0, acc[1][0], 0, 0, 0);
            acc[1][1] = __builtin_amdgcn_mfma_f32_16x16x32_bf16(af1, bf1, acc[1][1], 0, 0, 0);
            acc[1][2] = __builtin_amdgcn_mfma_f32_16x16x32_bf16(af1, bf2, acc[1][2], 0, 0, 0);
            acc[1][3] = __builtin_amdgcn_mfma_f32_16x16x32_bf16(af1, bf3, acc[1][3], 0, 0, 0);
        }
        __builtin_amdgcn_s_setprio(0);
        block_bar();
        if (it < 6) {
            const int k0 = (it + 2) * 128;
#pragma unroll
            for (int p = 0; p < 4; p++) {
                async_cp16(&As[buf * 8192 + p * 2048 + wid * 512], agp + k0 + p * 32);
                async_cp16(&Bs[buf * 16384 + p * 4096 + wid * 1024],       bgp0 + k0 + p * 32);
                async_cp16(&Bs[buf * 16384 + p * 4096 + wid * 1024 + 512], bgp1 + k0 + p * 32);
            }
            asm volatile("s_waitcnt vmcnt(12)" ::: "memory");
        } else if (it == 6) {
            asm volatile("s_waitcnt vmcnt(0)" ::: "memory");
        }
        if (it < 7) block_bar();
        buf ^= 1;
    }

#pragma unroll
    for (int tr = 0; tr < 2; tr++)
#pragma unroll
        for (int r = 0; r < 4; r++) {
            int b = m0 + wm * 32 + tr * 16 + quad * 4 + r;
            float i_ = acc[tr][0][r] + gi[tr][0][r];
            float g_ = acc[tr][1][r] + gi[tr][1][r];
            float f_ = acc[tr][2][r] + gi[tr][2][r];
            float o_ = acc[tr][3][r] + gi[tr][3][r];
            size_t idx = (size_t)b * HID + j;
            float cn = sigmoidf_(f_ + 1.0f) * cold[tr][r] + sigmoidf_(i_) * tanhf(g_);
            c[idx] = cn;
            h_next[idx] = f2bf(sigmoidf_(o_) * tanhf(cn));
        }
}

// ---------------------------------------------------------------------------
extern "C" void kernel_launch(void* const* d_in, const int* in_sizes, int n_in,
                              void* d_out, int out_size, void* d_ws, size_t ws_size,
                              hipStream_t stream) {
    const float* images = (const float*)d_in[0];
    const float* embed  = (const float*)d_in[1];
    const float* Wcell  = (const float*)d_in[2];
    const float* bcell  = (const float*)d_in[3];
    const float* Wimg   = (const float*)d_in[4];
    const float* bimg   = (const float*)d_in[5];
    const float* Whid   = (const float*)d_in[6];
    const float* bhid   = (const float*)d_in[7];
    const int*   msg    = (const int*)d_in[8];

    float* out0 = (float*)d_out;                   // images_encoded [512,1024] f32
    float* out1 = out0 + (size_t)BB * OUTN;        // hidden_encoded [512,1024] f32

    // Workspace layout (33 MB)
    char* ws = (char*)d_ws;
    const size_t MB = 1024 * 1024;
    short* Wh_t    = (short*)(ws);            //  8 MB [4096][1024] bf16, hmap
    short* Wx_t    = (short*)(ws + 8 * MB);   //  4 MB [4096][512]  bf16, xmap
    short* Wimg_t  = (short*)(ws + 12 * MB);  //  4 MB [1024][2048] bf16
    short* Whid_t  = (short*)(ws + 16 * MB);  //  2 MB [1024][1024] bf16
    short* eproj   = (short*)(ws + 18 * MB);  //  8 MB [1024][4096] bf16, bias folded, xmap layout
    short* h_a     = (short*)(ws + 26 * MB);  //  1 MB
    short* h_b     = (short*)(ws + 27 * MB);  //  1 MB
    float* cbuf    = (float*)(ws + 28 * MB);  //  2 MB (fallback path only)
    short* imgs_c  = (short*)(ws + 30 * MB);  //  2 MB [512][2048] bf16
    short* embed_c = (short*)(ws + 32 * MB);  //  1 MB [1024][512] bf16

    (void)hipFuncSetAttribute((const void*)lstm_all_k,  hipFuncAttributeMaxDynamicSharedMemorySize, 163840);
    (void)hipFuncSetAttribute((const void*)lstm_step_k, hipFuncAttributeMaxDynamicSharedMemorySize, 98304);

    // merged prep: elementwise setup + all four weight transposes (one launch)
    prep_k<<<dim3(3584 + 9216), dim3(256), 0, stream>>>(
        images, imgs_c, embed, embed_c, cbuf, h_a, out0, out1, bimg, bhid,
        Wcell + (size_t)EMBD * FOURH, Wh_t, Wcell, Wx_t, Wimg, Wimg_t, Whid, Whid_t);

    // eproj = bf16(embed @ W_x + b_cell), xmap gate-interleaved (single launch)
    gemm_bt_k<short, false, true><<<dim3(FOURH / 128, VOC / 64, 1), dim3(256), 0, stream>>>(
        embed_c, Wx_t, bcell, eproj, EMBD, EMBD / 64, FOURH);

    // images_encoded: split-K=4 in one launch (grid 8x8x4 = 256 blocks)
    gemm_bt_k<float, true, false><<<dim3(OUTN / 128, BB / 64, 4), dim3(256), 0, stream>>>(
        imgs_c, Wimg_t, nullptr, out0, DIMG, 8, OUTN);

    // all 128 LSTM steps: one persistent cooperative kernel (t=127 writes h_a)
    void* kargs[5] = {(void*)&Wh_t, (void*)&eproj, (void*)&msg, (void*)&h_a, (void*)&h_b};
    hipError_t ce = hipLaunchCooperativeKernel((const void*)lstm_all_k,
                                               dim3(FOURH / 128, BB / 64, 1), dim3(256, 1, 1),
                                               kargs, 163840, stream);
    if (ce != hipSuccess) {
        // fallback: proven per-step path
        for (int t = 0; t < TT; t++) {
            const short* hp = (t & 1) ? h_b : h_a;
            short* hn       = (t & 1) ? h_a : h_b;
            lstm_step_k<<<dim3(FOURH / 128, BB / 64), dim3(256), 98304, stream>>>(
                hp, Wh_t, eproj, msg, t, cbuf, hn);
        }
    }

    // hidden_encoded: split-K=4 in one launch
    gemm_bt_k<float, true, false><<<dim3(OUTN / 128, BB / 64, 4), dim3(256), 0, stream>>>(
        h_a, Whid_t, nullptr, out1, HID, 4, OUTN);
}

// Round 3
// 2330.432 us; speedup vs baseline: 2.3327x; 2.3327x over previous
//
#include <hip/hip_runtime.h>
#include <hip/hip_bf16.h>

// Problem constants (from reference)
#define BB    512
#define TT    128
#define HID   1024
#define EMBD  512
#define VOC   1024
#define OUTN  1024
#define DIMG  2048
#define FOURH 4096

typedef __attribute__((ext_vector_type(8))) short  short8;   // 8 bf16 (MFMA A/B frag)
typedef __attribute__((ext_vector_type(4))) float  f32x4;    // MFMA C/D frag
typedef unsigned int u32;
typedef unsigned long long u64;
typedef __attribute__((ext_vector_type(2))) unsigned long long u64x2;  // 16B LDS write

// Wh_t interleave (gate in bits 4-5 of n): n = G*64 + gate*16 + u  -> orig gate*1024 + G*16 + u
__device__ __forceinline__ int hmap(int n) {
    return ((n >> 4) & 3) * HID + ((n >> 6) << 4) + (n & 15);
}
// eproj interleave (gate in bits 0-1 of n): n = G*64 + u*4 + gate -> orig gate*1024 + G*16 + u
__device__ __forceinline__ int xmap(int n) {
    return (n & 3) * HID + ((n >> 6) << 4) + ((n >> 2) & 15);
}
__device__ __forceinline__ float sigmoidf_(float x) { return 1.0f / (1.0f + expf(-x)); }
__device__ __forceinline__ short f2bf(float x) { __hip_bfloat16 b = __float2bfloat16(x); return *(short*)&b; }
__device__ __forceinline__ float bf2f(short s) { __hip_bfloat16 b; *(short*)&b = s; return __bfloat162float(b); }

// async global->LDS, 16B per lane; lds base wave-uniform (HW adds lane*16)
__device__ __forceinline__ void async_cp16(void* lds, const void* g) {
    __builtin_amdgcn_global_load_lds((const __attribute__((address_space(1))) u32*)g,
                                     (__attribute__((address_space(3))) u32*)lds, 16, 0, 0);
}

// raw workgroup barrier with compiler memory fences (no vmcnt/lgkmcnt drain)
__device__ __forceinline__ void block_bar() {
    asm volatile("" ::: "memory");
    __builtin_amdgcn_s_barrier();
    asm volatile("" ::: "memory");
}

// coherent (agent-scope, cache-bypassing) 8B load / 2B store — NO cache maintenance
__device__ __forceinline__ u64 coh_ld64(const short* p) {
    return __hip_atomic_load((const u64*)p, __ATOMIC_RELAXED, __HIP_MEMORY_SCOPE_AGENT);
}
__device__ __forceinline__ void coh_st16(short* p, short v) {
    __hip_atomic_store(p, v, __ATOMIC_RELAXED, __HIP_MEMORY_SCOPE_AGENT);
}

// Lean grid barrier: relaxed agent atomics only (no L2 invalidate). All blocks
// must be co-resident (guaranteed by cooperative launch). One wave spins.
__device__ __forceinline__ void grid_bar(u32* cnt, u32* gen, u32 want) {
    __syncthreads();                 // drains vmcnt(0): h stores are at the coherence point
    if (threadIdx.x == 0) {
        u32 a = __hip_atomic_fetch_add(cnt, 1u, __ATOMIC_RELAXED, __HIP_MEMORY_SCOPE_AGENT);
        if (a == 255u) {             // last arriver of 256 blocks
            __hip_atomic_store(cnt, 0u, __ATOMIC_RELAXED, __HIP_MEMORY_SCOPE_AGENT);
            asm volatile("s_waitcnt vmcnt(0)" ::: "memory");   // reset visible before gen bump
            __hip_atomic_store(gen, want, __ATOMIC_RELAXED, __HIP_MEMORY_SCOPE_AGENT);
        } else {
            while (__hip_atomic_load(gen, __ATOMIC_RELAXED, __HIP_MEMORY_SCOPE_AGENT) < want)
                __builtin_amdgcn_s_sleep(2);
        }
    }
    __syncthreads();
}

// ---------------------------------------------------------------------------
// Merged prep (one launch): blocks [0,3584) elementwise setup; blocks
// [3584, 3584+9216) the four tiled weight transposes out[n][k] = bf16(in[k][map(n)]).
__global__ void prep_k(const float* __restrict__ images, short* __restrict__ imgs_c,
                       const float* __restrict__ embed,  short* __restrict__ embed_c,
                       float* __restrict__ c, short* __restrict__ h0,
                       float* __restrict__ o0, float* __restrict__ o1,
                       const float* __restrict__ bimg, const float* __restrict__ bhid,
                       const float* __restrict__ Wc_h, short* __restrict__ Wh_t,
                       const float* __restrict__ Wc_x, short* __restrict__ Wx_t,
                       const float* __restrict__ Wimg, short* __restrict__ Wimg_t,
                       const float* __restrict__ Whid, short* __restrict__ Whid_t) {
    if (blockIdx.x < 3584) {
        int i = blockIdx.x * 256 + threadIdx.x;
        if (i < 262144) {                       // images: 512*2048/4
            float4 v = ((const float4*)images)[i];
            short4 o; o.x = f2bf(v.x); o.y = f2bf(v.y); o.z = f2bf(v.z); o.w = f2bf(v.w);
            ((short4*)imgs_c)[i] = o;
        } else if (i < 393216) {                // embed: 1024*512/4
            int k = i - 262144;
            float4 v = ((const float4*)embed)[k];
            short4 o; o.x = f2bf(v.x); o.y = f2bf(v.y); o.z = f2bf(v.z); o.w = f2bf(v.w);
            ((short4*)embed_c)[k] = o;
        } else {                                // state/out init: 512*1024
            int k = i - 393216;
            int n = k & (OUTN - 1);
            c[k] = 0.0f; h0[k] = 0;
            o0[k] = bimg[n]; o1[k] = bhid[n];
        }
        return;
    }
    int id = blockIdx.x - 3584;
    const float* in; short* out; int K, N_in, bx, by, mapmode;
    if (id < 4096)      { in = Wc_h; out = Wh_t;   K = 1024; N_in = 4096; mapmode = 1; bx = id & 127;  by = id >> 7; }
    else if (id < 6144) { id -= 4096;              in = Wc_x; out = Wx_t; K = 512;  N_in = 4096; mapmode = 2; bx = id & 127;  by = id >> 7; }
    else if (id < 8192) { id -= 6144; in = Wimg; out = Wimg_t; K = 2048; N_in = 1024; mapmode = 0; bx = id & 31; by = id >> 5; }
    else                { id -= 8192; in = Whid; out = Whid_t; K = 1024; N_in = 1024; mapmode = 0; bx = id & 31; by = id >> 5; }

    __shared__ short tile[32][33];
    int n0 = bx * 32, k0 = by * 32;
    int tx = threadIdx.x & 31, ty = threadIdx.x >> 5;   // 32 x 8
    int nn = n0 + tx;
    int nsrc = (mapmode == 1) ? hmap(nn) : (mapmode == 2) ? xmap(nn) : nn;
#pragma unroll
    for (int j = 0; j < 4; j++) {
        int kw = ty + j * 8;
        tile[kw][tx] = f2bf(in[(size_t)(k0 + kw) * N_in + nsrc]);
    }
    __syncthreads();
#pragma unroll
    for (int j = 0; j < 4; j++) {
        int nw = ty + j * 8;
        out[(size_t)(n0 + nw) * K + k0 + tx] = tile[tx][nw];
    }
}

// ---------------------------------------------------------------------------
// Double-buffered MFMA core, tile 64x128, BK=64, 4 waves 2x2 (one-shot GEMMs).
template<typename OutT, bool ATOMIC, bool MAPB>
__global__ __launch_bounds__(256) void gemm_bt_k(
    const short* __restrict__ A, const short* __restrict__ Bt,
    const float* __restrict__ bias, OutT* __restrict__ out,
    int Kf, int niter, int N)
{
    __shared__ __align__(16) short As[2][2][64 * 32];
    __shared__ __align__(16) short Bs[2][2][128 * 32];
    const int tid  = threadIdx.x;
    const int lane = tid & 63, wid = tid >> 6;
    const int wm = wid >> 1, wn = wid & 1;
    const int col16 = lane & 15, quad = lane >> 4;
    const int m0 = blockIdx.y * 64;
    const int n0 = blockIdx.x * 128;
    const int kbeg = blockIdx.z * niter * 64;

    const short* agp = A  + (size_t)(m0 + wid * 16 + (lane >> 2)) * Kf + kbeg + (lane & 3) * 8;
    const short* bgp = Bt + (size_t)(n0 + wid * 32 + (lane >> 2)) * Kf + kbeg + (lane & 3) * 8;

    f32x4 acc[2][4];
#pragma unroll
    for (int i = 0; i < 2; i++)
#pragma unroll
        for (int jj = 0; jj < 4; jj++) acc[i][jj] = (f32x4)0.0f;

    async_cp16(&As[0][0][wid * 512], agp);
    async_cp16(&As[0][1][wid * 512], agp + 32);
    async_cp16(&Bs[0][0][wid * 1024],       bgp);
    async_cp16(&Bs[0][0][wid * 1024 + 512], bgp + (size_t)16 * Kf);
    async_cp16(&Bs[0][1][wid * 1024],       bgp + 32);
    async_cp16(&Bs[0][1][wid * 1024 + 512], bgp + (size_t)16 * Kf + 32);
    __syncthreads();

    int buf = 0;
#pragma unroll 1
    for (int it = 0; it < niter; ++it) {
        if (it + 1 < niter) {
            int k0 = (it + 1) * 64;
            async_cp16(&As[buf ^ 1][0][wid * 512], agp + k0);
            async_cp16(&As[buf ^ 1][1][wid * 512], agp + k0 + 32);
            async_cp16(&Bs[buf ^ 1][0][wid * 1024],       bgp + k0);
            async_cp16(&Bs[buf ^ 1][0][wid * 1024 + 512], bgp + (size_t)16 * Kf + k0);
            async_cp16(&Bs[buf ^ 1][1][wid * 1024],       bgp + k0 + 32);
            async_cp16(&Bs[buf ^ 1][1][wid * 1024 + 512], bgp + (size_t)16 * Kf + k0 + 32);
        }
        short8 af[2][2], bf[4][2];
#pragma unroll
        for (int tr = 0; tr < 2; tr++)
#pragma unroll
            for (int p = 0; p < 2; p++)
                af[tr][p] = *(const short8*)&As[buf][p][(wm * 32 + tr * 16 + col16) * 32 + quad * 8];
#pragma unroll
        for (int tc = 0; tc < 4; tc++)
#pragma unroll
            for (int p = 0; p < 2; p++)
                bf[tc][p] = *(const short8*)&Bs[buf][p][(wn * 64 + tc * 16 + col16) * 32 + quad * 8];
#pragma unroll
        for (int p = 0; p < 2; p++)
#pragma unroll
            for (int tr = 0; tr < 2; tr++)
#pragma unroll
                for (int tc = 0; tc < 4; tc++)
                    acc[tr][tc] = __builtin_amdgcn_mfma_f32_16x16x32_bf16(af[tr][p], bf[tc][p], acc[tr][tc], 0, 0, 0);
        __syncthreads();
        buf ^= 1;
    }

#pragma unroll
    for (int tr = 0; tr < 2; tr++)
#pragma unroll
        for (int tc = 0; tc < 4; tc++) {
            int colg = n0 + wn * 64 + tc * 16 + col16;
            float bv = 0.0f;
            if constexpr (!ATOMIC) bv = bias[MAPB ? xmap(colg) : colg];
#pragma unroll
            for (int r = 0; r < 4; r++) {
                int rowg = m0 + wm * 32 + tr * 16 + quad * 4 + r;
                float v = acc[tr][tc][r] + bv;
                if constexpr (ATOMIC) atomicAdd((float*)&out[(size_t)rowg * N + colg], v);
                else                  out[(size_t)rowg * N + colg] = f2bf(v);
            }
        }
}

// ---------------------------------------------------------------------------
// Persistent LSTM, lean-barrier edition. Grid 32x8 = 256 blocks (coop launch,
// 1 block/CU via 160KB LDS). Key points vs the failed grid.sync version:
//  * NO cache maintenance per step: Wh_t/eproj stay L2-resident the whole run.
//  * h exchange is the only coherent path: h stores = relaxed agent atomics
//    (write through to coherence point); h reads = relaxed agent u64 loads
//    (bypass L1/L2) reg-staged into the same swizzled LDS layout (T14 split,
//    prefetch distance 2, counted vmcnt).
//  * c lives in registers all 128 steps; B tiles 0,1 persistent in LDS.
// LDS (shorts): As dbuf 2x8192 | Bs dbuf 2x16384 | Bp 2x16384 = 160 KB.
__global__ __launch_bounds__(256, 1) void lstm_all_k(
    const short* __restrict__ Wh_t, const short* __restrict__ eproj,
    const int* __restrict__ msg,
    short* __restrict__ h_a, short* __restrict__ h_b,
    u32* __restrict__ bar_cnt, u32* __restrict__ bar_gen)
{
    constexpr int Kf = HID;
    extern __shared__ __align__(16) short smem[];
    short* As = smem;            // [2][8192]
    short* Bs = smem + 16384;    // [2][16384]
    short* Bp = smem + 49152;    // [2][16384] persistent B tiles 0,1

    const int tid  = threadIdx.x;
    const int lane = tid & 63, wid = tid >> 6;
    const int wm = wid >> 1, wn = wid & 1;
    const int col16 = lane & 15, quad = lane >> 4;
    const int m0 = blockIdx.y * 64;
    const int n0 = blockIdx.x * 128;

    const int swz_st = (((lane & 3) - ((lane >> 3) & 3)) & 3) * 8;
    const size_t aoff = (size_t)(m0 + wid * 16 + (lane >> 2)) * Kf + swz_st;
    const short* agpA = h_a + aoff;
    const short* agpB = h_b + aoff;
    const short* bgp0 = Wh_t + (size_t)(n0 + wid * 32 + (lane >> 2)) * Kf + swz_st;
    const short* bgp1 = bgp0 + (size_t)16 * Kf;

    const int G = (n0 + wn * 64) >> 6;
    const int j = G * 16 + col16;
    const short* egbase = eproj + G * 64 + col16 * 4;   // + v*FOURH -> short4 of 4 gates

    int moff[2][4], hoff[2][4];
#pragma unroll
    for (int tr = 0; tr < 2; tr++)
#pragma unroll
        for (int r = 0; r < 4; r++) {
            int b = m0 + wm * 32 + tr * 16 + quad * 4 + r;
            moff[tr][r] = b * TT;
            hoff[tr][r] = b * HID + j;
        }

    const int swz_rd = ((quad + (col16 >> 1)) & 3) * 8;
    const int arow = (wm * 32 + col16) * 32 + swz_rd;   // + tr*512
    const int brow = (wn * 64 + col16) * 32 + swz_rd;   // + tc*512
    const int adst = wid * 512 + lane * 8;              // LDS A stripe (shorts)

    float creg[2][4];
#pragma unroll
    for (int tr = 0; tr < 2; tr++)
#pragma unroll
        for (int r = 0; r < 4; r++) creg[tr][r] = 0.0f;

    // persistent B tiles 0,1 -> Bp (drained by the first grid_bar's syncthreads)
#pragma unroll
    for (int p = 0; p < 4; p++) {
        async_cp16(&Bp[p * 4096 + wid * 1024],       bgp0 + p * 32);
        async_cp16(&Bp[p * 4096 + wid * 1024 + 512], bgp1 + p * 32);
        async_cp16(&Bp[16384 + p * 4096 + wid * 1024],       bgp0 + 128 + p * 32);
        async_cp16(&Bp[16384 + p * 4096 + wid * 1024 + 512], bgp1 + 128 + p * 32);
    }

#pragma unroll 1
    for (int t = 0; t < TT; ++t) {
        const short* agp = (t & 1) ? agpB : agpA;
        short* hw        = (t & 1) ? h_a : h_b;

        // gate preactivation gather (h-independent, cached loads; latency hides
        // under the barrier spin)
        float gi[2][4][4];
#pragma unroll
        for (int tr = 0; tr < 2; tr++)
#pragma unroll
            for (int r = 0; r < 4; r++) {
                int v = msg[moff[tr][r] + t];
                short4 s4 = *(const short4*)(egbase + (size_t)v * FOURH);
                gi[tr][0][r] = bf2f(s4.x);
                gi[tr][1][r] = bf2f(s4.y);
                gi[tr][2][r] = bf2f(s4.z);
                gi[tr][3][r] = bf2f(s4.w);
            }

        grid_bar(bar_cnt, bar_gen, (u32)(t + 1));   // h_{t-1} visible at coherence point

        // ---- prologue: coherent A loads t0,t1 -> regs; write A0 to LDS
        u64 areg[2][8];
#pragma unroll
        for (int p = 0; p < 4; p++) {
            areg[0][2 * p]     = coh_ld64(agp + p * 32);
            areg[0][2 * p + 1] = coh_ld64(agp + p * 32 + 4);
        }
#pragma unroll
        for (int p = 0; p < 4; p++) {
            areg[1][2 * p]     = coh_ld64(agp + 128 + p * 32);
            areg[1][2 * p + 1] = coh_ld64(agp + 128 + p * 32 + 4);
        }
        asm volatile("s_waitcnt vmcnt(8)" ::: "memory");    // A0 landed (A1 in flight)
#pragma unroll
        for (int p = 0; p < 4; p++)
            *(u64x2*)&As[p * 2048 + adst] = (u64x2){areg[0][2 * p], areg[0][2 * p + 1]};
        asm volatile("s_waitcnt lgkmcnt(0)" ::: "memory");
        block_bar();

        f32x4 acc[2][4];
#pragma unroll
        for (int i = 0; i < 2; i++)
#pragma unroll
            for (int jj = 0; jj < 4; jj++) acc[i][jj] = (f32x4)0.0f;

#pragma unroll
        for (int it = 0; it < 8; ++it) {
            const int buf = it & 1;
            const short* Ab = &As[buf * 8192];
            const short* Bb = (it < 2) ? &Bp[it * 16384] : &Bs[buf * 16384];
            __builtin_amdgcn_s_setprio(1);
#pragma unroll
            for (int p = 0; p < 4; p++) {
                short8 af0 = *(const short8*)&Ab[p * 2048 + arow];
                short8 af1 = *(const short8*)&Ab[p * 2048 + arow + 512];
                short8 bf0 = *(const short8*)&Bb[p * 4096 + brow];
                short8 bf1 = *(const short8*)&Bb[p * 4096 + brow + 512];
                short8 bf2 = *(const short8*)&Bb[p * 4096 + brow + 1024];
                short8 bf3 = *(const short8*)&Bb[p * 4096 + brow + 1536];
                acc[0][0] = __builtin_amdgcn_mfma_f32_16x16x32_bf16(af0, bf0, acc[0][0], 0, 0, 0);
                acc[0][1] = __builtin_amdgcn_mfma_f32_16x16x32_bf16(af0, bf1, acc[0][1], 0, 0, 0);
                acc[0][2] = __builtin_amdgcn_mfma_f32_16x16x32_bf16(af0, bf2, acc[0][2], 0, 0, 0);
                acc[0][3] = __builtin_amdgcn_mfma_f32_16x16x32_bf16(af0, bf3, acc[0][3], 0, 0, 0);
                acc[1][0] = __builtin_amdgcn_mfma_f32_16x16x32_bf16(af1, bf0, acc[1][0], 0, 0, 0);
                acc[1][1] = __builtin_amdgcn_mfma_f32_16x16x32_bf16(af1, bf1, acc[1][1], 0, 0, 0);
                acc[1][2] = __builtin_amdgcn_mfma_f32_16x16x32_bf16(af1, bf2, acc[1][2], 0, 0, 0);
                acc[1][3] = __builtin_amdgcn_mfma_f32_16x16x32_bf16(af1, bf3, acc[1][3], 0, 0, 0);
            }
            __builtin_amdgcn_s_setprio(0);

            block_bar();   // all waves done reading As[buf]/Bb

            if (it < 6) {
                const int k0 = (it + 2) * 128;
                // coherent A(it+2) -> areg[buf] (slot just freed)
#pragma unroll
                for (int p = 0; p < 4; p++) {
                    areg[buf][2 * p]     = coh_ld64(agp + k0 + p * 32);
                    areg[buf][2 * p + 1] = coh_ld64(agp + k0 + p * 32 + 4);
                }
                // B(it+2) -> Bs[buf] (cached, L2-hot)
#pragma unroll
                for (int p = 0; p < 4; p++) {
                    async_cp16(&Bs[buf * 16384 + p * 4096 + wid * 1024],       bgp0 + k0 + p * 32);
                    async_cp16(&Bs[buf * 16384 + p * 4096 + wid * 1024 + 512], bgp1 + k0 + p * 32);
                }
                // newest 16 = A(it+2)+B(it+2); everything older (A/B it+1) landed
                asm volatile("s_waitcnt vmcnt(16)" ::: "memory");
                // ds_write A(it+1) from regs into As[buf^1]
#pragma unroll
                for (int p = 0; p < 4; p++)
                    *(u64x2*)&As[(buf ^ 1) * 8192 + p * 2048 + adst] =
                        (u64x2){areg[buf ^ 1][2 * p], areg[buf ^ 1][2 * p + 1]};
                asm volatile("s_waitcnt lgkmcnt(0)" ::: "memory");
                block_bar();
            } else if (it == 6) {
                asm volatile("s_waitcnt vmcnt(0)" ::: "memory");   // A7/B7 landed
#pragma unroll
                for (int p = 0; p < 4; p++)
                    *(u64x2*)&As[8192 + p * 2048 + adst] =
                        (u64x2){areg[1][2 * p], areg[1][2 * p + 1]};
                asm volatile("s_waitcnt lgkmcnt(0)" ::: "memory");
                block_bar();
            }
        }

        // fused cell update; c in regs; h written coherently (agent scope)
#pragma unroll
        for (int tr = 0; tr < 2; tr++)
#pragma unroll
            for (int r = 0; r < 4; r++) {
                float i_ = acc[tr][0][r] + gi[tr][0][r];
                float g_ = acc[tr][1][r] + gi[tr][1][r];
                float f_ = acc[tr][2][r] + gi[tr][2][r];
                float o_ = acc[tr][3][r] + gi[tr][3][r];
                float cn = sigmoidf_(f_ + 1.0f) * creg[tr][r] + sigmoidf_(i_) * tanhf(g_);
                creg[tr][r] = cn;
                coh_st16(&hw[hoff[tr][r]], f2bf(sigmoidf_(o_) * tanhf(cn)));
            }
    }
}

// ---------------------------------------------------------------------------
// Fallback per-step kernel (proven; used only if cooperative launch fails).
__global__ __launch_bounds__(256) void lstm_step_k(
    const short* __restrict__ h_prev, const short* __restrict__ Wh_t,
    const short* __restrict__ eproj, const int* __restrict__ msg, int t,
    float* __restrict__ c, short* __restrict__ h_next)
{
    constexpr int Kf = HID;
    extern __shared__ __align__(16) short smem[];
    short* As = smem;           // [2][4][2048] shorts
    short* Bs = smem + 16384;   // [2][4][4096] shorts

    const int tid  = threadIdx.x;
    const int lane = tid & 63, wid = tid >> 6;
    const int wm = wid >> 1, wn = wid & 1;
    const int col16 = lane & 15, quad = lane >> 4;
    const int m0 = blockIdx.y * 64;
    const int n0 = blockIdx.x * 128;

    const int swz_st = (((lane & 3) - ((lane >> 3) & 3)) & 3) * 8;
    const short* agp  = h_prev + (size_t)(m0 + wid * 16 + (lane >> 2)) * Kf + swz_st;
    const short* bgp0 = Wh_t   + (size_t)(n0 + wid * 32 + (lane >> 2)) * Kf + swz_st;
    const short* bgp1 = bgp0 + (size_t)16 * Kf;

    const int G = (n0 + wn * 64) >> 6;
    const int j = G * 16 + col16;
    float gi[2][4][4], cold[2][4];
#pragma unroll
    for (int tr = 0; tr < 2; tr++)
#pragma unroll
        for (int r = 0; r < 4; r++) {
            int b = m0 + wm * 32 + tr * 16 + quad * 4 + r;
            int v = msg[b * TT + t];
            short4 s4 = *(const short4*)(eproj + (size_t)v * FOURH + G * 64 + col16 * 4);
            gi[tr][0][r] = bf2f(s4.x);
            gi[tr][1][r] = bf2f(s4.y);
            gi[tr][2][r] = bf2f(s4.z);
            gi[tr][3][r] = bf2f(s4.w);
            cold[tr][r] = c[(size_t)b * HID + j];
        }

#pragma unroll
    for (int p = 0; p < 4; p++) {
        async_cp16(&As[p * 2048 + wid * 512], agp + p * 32);
        async_cp16(&Bs[p * 4096 + wid * 1024],       bgp0 + p * 32);
        async_cp16(&Bs[p * 4096 + wid * 1024 + 512], bgp1 + p * 32);
    }
#pragma unroll
    for (int p = 0; p < 4; p++) {
        async_cp16(&As[8192 + p * 2048 + wid * 512], agp + 128 + p * 32);
        async_cp16(&Bs[16384 + p * 4096 + wid * 1024],       bgp0 + 128 + p * 32);
        async_cp16(&Bs[16384 + p * 4096 + wid * 1024 + 512], bgp1 + 128 + p * 32);
    }

    f32x4 acc[2][4];
#pragma unroll
    for (int i = 0; i < 2; i++)
#pragma unroll
        for (int jj = 0; jj < 4; jj++) acc[i][jj] = (f32x4)0.0f;

    const int swz_rd = ((quad + (col16 >> 1)) & 3) * 8;
    const int arow = (wm * 32 + col16) * 32 + swz_rd;
    const int brow = (wn * 64 + col16) * 32 + swz_rd;

    asm volatile("s_waitcnt vmcnt(12)" ::: "memory");
    block_bar();

    int buf = 0;
#pragma unroll 1
    for (int it = 0; it < 8; ++it) {
        const short* Ab = &As[buf * 8192];
        const short* Bb = &Bs[buf * 16384];
        __builtin_amdgcn_s_setprio(1);
#pragma unroll
        for (int p = 0; p < 4; p++) {
            short8 af0 = *(const short8*)&Ab[p * 2048 + arow];
            short8 af1 = *(const short8*)&Ab[p * 2048 + arow + 512];
            short8 bf0 = *(const short8*)&Bb[p * 4096 + brow];
            short8 bf1 = *(const short8*)&Bb[p * 4096 + brow + 512];
            short8 bf2 = *(const short8*)&Bb[p * 4096 + brow + 1024];
            short8 bf3 = *(const short8*)&Bb[p * 4096 + brow + 1536];
            acc[0][0] = __builtin_amdgcn_mfma_f32_16x16x32_bf16(af0, bf0, acc[0][0], 0, 0, 0);
            acc[0][1] = __builtin_amdgcn_mfma_f32_16x16x32_bf16(af0, bf1, acc[0][1], 0, 0, 0);
            acc[0][2] = __builtin_amdgcn_mfma_f32_16x16x32_bf16(af0, bf2, acc[0][2], 0, 0, 0);
            acc[0][3] = __builtin_amdgcn_mfma_f32_16x16x32_bf16(af0, bf3, acc[0][3], 0, 0, 0);
            acc[1][0] = __builtin_amdgcn_mfma_f32_16x16x32_bf16(af1, bf0, acc[1][0], 0, 0, 0);
            acc[1][1] = __builtin_amdgcn_mfma_f32_16x16x32_bf16(af1, bf1, acc[1][1], 0, 0, 0);
            acc[1][2] = __builtin_amdgcn_mfma_f32_16x16x32_bf16(af1, bf2, acc[1][2], 0, 0, 0);
            acc[1][3] = __builtin_amdgcn_mfma_f32_16x16x32_bf16(af1, bf3, acc[1][3], 0, 0, 0);
        }
        __builtin_amdgcn_s_setprio(0);
        block_bar();
        if (it < 6) {
            const int k0 = (it + 2) * 128;
#pragma unroll
            for (int p = 0; p < 4; p++) {
                async_cp16(&As[buf * 8192 + p * 2048 + wid * 512], agp + k0 + p * 32);
                async_cp16(&Bs[buf * 16384 + p * 4096 + wid * 1024],       bgp0 + k0 + p * 32);
                async_cp16(&Bs[buf * 16384 + p * 4096 + wid * 1024 + 512], bgp1 + k0 + p * 32);
            }
            asm volatile("s_waitcnt vmcnt(12)" ::: "memory");
        } else if (it == 6) {
            asm volatile("s_waitcnt vmcnt(0)" ::: "memory");
        }
        if (it < 7) block_bar();
        buf ^= 1;
    }

#pragma unroll
    for (int tr = 0; tr < 2; tr++)
#pragma unroll
        for (int r = 0; r < 4; r++) {
            int b = m0 + wm * 32 + tr * 16 + quad * 4 + r;
            float i_ = acc[tr][0][r] + gi[tr][0][r];
            float g_ = acc[tr][1][r] + gi[tr][1][r];
            float f_ = acc[tr][2][r] + gi[tr][2][r];
            float o_ = acc[tr][3][r] + gi[tr][3][r];
            size_t idx = (size_t)b * HID + j;
            float cn = sigmoidf_(f_ + 1.0f) * cold[tr][r] + sigmoidf_(i_) * tanhf(g_);
            c[idx] = cn;
            h_next[idx] = f2bf(sigmoidf_(o_) * tanhf(cn));
        }
}

// ---------------------------------------------------------------------------
extern "C" void kernel_launch(void* const* d_in, const int* in_sizes, int n_in,
                              void* d_out, int out_size, void* d_ws, size_t ws_size,
                              hipStream_t stream) {
    const float* images = (const float*)d_in[0];
    const float* embed  = (const float*)d_in[1];
    const float* Wcell  = (const float*)d_in[2];
    const float* bcell  = (const float*)d_in[3];
    const float* Wimg   = (const float*)d_in[4];
    const float* bimg   = (const float*)d_in[5];
    const float* Whid   = (const float*)d_in[6];
    const float* bhid   = (const float*)d_in[7];
    const int*   msg    = (const int*)d_in[8];

    float* out0 = (float*)d_out;                   // images_encoded [512,1024] f32
    float* out1 = out0 + (size_t)BB * OUTN;        // hidden_encoded [512,1024] f32

    // Workspace layout (33 MB)
    char* ws = (char*)d_ws;
    const size_t MB = 1024 * 1024;
    short* Wh_t    = (short*)(ws);            //  8 MB [4096][1024] bf16, hmap
    short* Wx_t    = (short*)(ws + 8 * MB);   //  4 MB [4096][512]  bf16, xmap
    short* Wimg_t  = (short*)(ws + 12 * MB);  //  4 MB [1024][2048] bf16
    short* Whid_t  = (short*)(ws + 16 * MB);  //  2 MB [1024][1024] bf16
    short* eproj   = (short*)(ws + 18 * MB);  //  8 MB [1024][4096] bf16, bias folded, xmap layout
    short* h_a     = (short*)(ws + 26 * MB);  //  1 MB
    short* h_b     = (short*)(ws + 27 * MB);  //  1 MB
    float* cbuf    = (float*)(ws + 28 * MB);  //  2 MB (fallback c; coop barrier flags)
    short* imgs_c  = (short*)(ws + 30 * MB);  //  2 MB [512][2048] bf16
    short* embed_c = (short*)(ws + 32 * MB);  //  1 MB [1024][512] bf16

    u32* bar_cnt = (u32*)cbuf;        // zeroed by prep_k (c[k]=0)
    u32* bar_gen = (u32*)cbuf + 64;   // separate cacheline

    (void)hipFuncSetAttribute((const void*)lstm_all_k,  hipFuncAttributeMaxDynamicSharedMemorySize, 163840);
    (void)hipFuncSetAttribute((const void*)lstm_step_k, hipFuncAttributeMaxDynamicSharedMemorySize, 98304);

    // merged prep: elementwise setup + all four weight transposes (one launch)
    prep_k<<<dim3(3584 + 9216), dim3(256), 0, stream>>>(
        images, imgs_c, embed, embed_c, cbuf, h_a, out0, out1, bimg, bhid,
        Wcell + (size_t)EMBD * FOURH, Wh_t, Wcell, Wx_t, Wimg, Wimg_t, Whid, Whid_t);

    // eproj = bf16(embed @ W_x + b_cell), xmap gate-interleaved (single launch)
    gemm_bt_k<short, false, true><<<dim3(FOURH / 128, VOC / 64, 1), dim3(256), 0, stream>>>(
        embed_c, Wx_t, bcell, eproj, EMBD, EMBD / 64, FOURH);

    // images_encoded: split-K=4 in one launch (grid 8x8x4 = 256 blocks)
    gemm_bt_k<float, true, false><<<dim3(OUTN / 128, BB / 64, 4), dim3(256), 0, stream>>>(
        imgs_c, Wimg_t, nullptr, out0, DIMG, 8, OUTN);

    // all 128 LSTM steps: one persistent kernel, lean barrier (t=127 writes h_a)
    void* kargs[7] = {(void*)&Wh_t, (void*)&eproj, (void*)&msg,
                      (void*)&h_a, (void*)&h_b, (void*)&bar_cnt, (void*)&bar_gen};
    hipError_t ce = hipLaunchCooperativeKernel((const void*)lstm_all_k,
                                               dim3(FOURH / 128, BB / 64, 1), dim3(256, 1, 1),
                                               kargs, 163840, stream);
    if (ce != hipSuccess) {
        for (int t = 0; t < TT; t++) {
            const short* hp = (t & 1) ? h_b : h_a;
            short* hn       = (t & 1) ? h_a : h_b;
            lstm_step_k<<<dim3(FOURH / 128, BB / 64), dim3(256), 98304, stream>>>(
                hp, Wh_t, eproj, msg, t, cbuf, hn);
        }
    }

    // hidden_encoded: split-K=4 in one launch
    gemm_bt_k<float, true, false><<<dim3(OUTN / 128, BB / 64, 4), dim3(256), 0, stream>>>(
        h_a, Whid_t, nullptr, out1, HID, 4, OUTN);
}

// Round 5
// 2068.751 us; speedup vs baseline: 2.6277x; 1.1265x over previous
//
#include <hip/hip_runtime.h>
#include <hip/hip_bf16.h>

// Problem constants (from reference)
#define BB    512
#define TT    128
#define HID   1024
#define EMBD  512
#define VOC   1024
#define OUTN  1024
#define DIMG  2048
#define FOURH 4096

typedef __attribute__((ext_vector_type(8))) short  short8;   // 8 bf16 (MFMA A/B frag)
typedef __attribute__((ext_vector_type(4))) float  f32x4;    // MFMA C/D frag
typedef unsigned int u32;
typedef unsigned long long u64;
typedef __attribute__((ext_vector_type(2))) unsigned long long u64x2;  // 16B LDS write

// Wh_t interleave (gate in bits 4-5 of n): n = G*64 + gate*16 + u  -> orig gate*1024 + G*16 + u
__device__ __forceinline__ int hmap(int n) {
    return ((n >> 4) & 3) * HID + ((n >> 6) << 4) + (n & 15);
}
// eproj interleave (gate in bits 0-1 of n): n = G*64 + u*4 + gate -> orig gate*1024 + G*16 + u
__device__ __forceinline__ int xmap(int n) {
    return (n & 3) * HID + ((n >> 6) << 4) + ((n >> 2) & 15);
}
__device__ __forceinline__ float sigmoidf_(float x) { return 1.0f / (1.0f + expf(-x)); }
__device__ __forceinline__ short f2bf(float x) { __hip_bfloat16 b = __float2bfloat16(x); return *(short*)&b; }
__device__ __forceinline__ float bf2f(short s) { __hip_bfloat16 b; *(short*)&b = s; return __bfloat162float(b); }

// async global->LDS, 16B per lane; lds base wave-uniform (HW adds lane*16)
__device__ __forceinline__ void async_cp16(void* lds, const void* g) {
    __builtin_amdgcn_global_load_lds((const __attribute__((address_space(1))) u32*)g,
                                     (__attribute__((address_space(3))) u32*)lds, 16, 0, 0);
}

// raw workgroup barrier with compiler memory fences (no vmcnt/lgkmcnt drain)
__device__ __forceinline__ void block_bar() {
    asm volatile("" ::: "memory");
    __builtin_amdgcn_s_barrier();
    asm volatile("" ::: "memory");
}

// coherent (agent-scope, cache-bypassing) 8B load / 2B store — NO cache maintenance
__device__ __forceinline__ u64 coh_ld64(const short* p) {
    return __hip_atomic_load((const u64*)p, __ATOMIC_RELAXED, __HIP_MEMORY_SCOPE_AGENT);
}
__device__ __forceinline__ void coh_st16(short* p, short v) {
    __hip_atomic_store(p, v, __ATOMIC_RELAXED, __HIP_MEMORY_SCOPE_AGENT);
}

// Two-level grid barrier (256 blocks = 8 groups x 32). Avoids 256 serialized
// same-line atomics: 32 adds/group line (8 lines in parallel) + 8 root adds +
// one gen publish. bar layout (u32 idx): cnt[g]=g*64, root=1024, gen=2048.
// Spin is BOUNDED: if a barrier ever wedges (should be impossible), we proceed
// after ~128k polls -> visible numeric failure instead of a dead container.
__device__ __forceinline__ void grid_bar2(u32* bar, u32 want, int gid) {
    asm volatile("s_waitcnt vmcnt(0)" ::: "memory");   // own stores at coherence point
    block_bar();                                       // whole block drained
    if (threadIdx.x == 0) {
        u32 a = __hip_atomic_fetch_add(bar + gid * 64, 1u, __ATOMIC_RELAXED, __HIP_MEMORY_SCOPE_AGENT);
        if (a == 31u) {                                // group complete
            u32 r = __hip_atomic_fetch_add(bar + 1024, 1u, __ATOMIC_RELAXED, __HIP_MEMORY_SCOPE_AGENT);
            if (r == 7u) {                             // all groups complete
#pragma unroll
                for (int g2 = 0; g2 < 8; g2++)
                    __hip_atomic_store(bar + g2 * 64, 0u, __ATOMIC_RELAXED, __HIP_MEMORY_SCOPE_AGENT);
                __hip_atomic_store(bar + 1024, 0u, __ATOMIC_RELAXED, __HIP_MEMORY_SCOPE_AGENT);
                asm volatile("s_waitcnt vmcnt(0)" ::: "memory");   // resets visible first
                __hip_atomic_store(bar + 2048, want, __ATOMIC_RELAXED, __HIP_MEMORY_SCOPE_AGENT);
            }
        }
        u32 guard = 0;
        while (__hip_atomic_load(bar + 2048, __ATOMIC_RELAXED, __HIP_MEMORY_SCOPE_AGENT) < want) {
            __builtin_amdgcn_s_sleep(1);
            if (++guard > (1u << 17)) break;           // safety valve (never hit in practice)
        }
    }
    block_bar();
}

// ---------------------------------------------------------------------------
// Merged prep (one launch): blocks [0,3584) elementwise setup; blocks
// [3584, 3584+9216) the four tiled weight transposes out[n][k] = bf16(in[k][map(n)]).
__global__ void prep_k(const float* __restrict__ images, short* __restrict__ imgs_c,
                       const float* __restrict__ embed,  short* __restrict__ embed_c,
                       float* __restrict__ c, short* __restrict__ h0,
                       float* __restrict__ o0, float* __restrict__ o1,
                       const float* __restrict__ bimg, const float* __restrict__ bhid,
                       const float* __restrict__ Wc_h, short* __restrict__ Wh_t,
                       const float* __restrict__ Wc_x, short* __restrict__ Wx_t,
                       const float* __restrict__ Wimg, short* __restrict__ Wimg_t,
                       const float* __restrict__ Whid, short* __restrict__ Whid_t) {
    if (blockIdx.x < 3584) {
        int i = blockIdx.x * 256 + threadIdx.x;
        if (i < 262144) {                       // images: 512*2048/4
            float4 v = ((const float4*)images)[i];
            short4 o; o.x = f2bf(v.x); o.y = f2bf(v.y); o.z = f2bf(v.z); o.w = f2bf(v.w);
            ((short4*)imgs_c)[i] = o;
        } else if (i < 393216) {                // embed: 1024*512/4
            int k = i - 262144;
            float4 v = ((const float4*)embed)[k];
            short4 o; o.x = f2bf(v.x); o.y = f2bf(v.y); o.z = f2bf(v.z); o.w = f2bf(v.w);
            ((short4*)embed_c)[k] = o;
        } else {                                // state/out init: 512*1024
            int k = i - 393216;
            int n = k & (OUTN - 1);
            c[k] = 0.0f; h0[k] = 0;
            o0[k] = bimg[n]; o1[k] = bhid[n];
        }
        return;
    }
    int id = blockIdx.x - 3584;
    const float* in; short* out; int K, N_in, bx, by, mapmode;
    if (id < 4096)      { in = Wc_h; out = Wh_t;   K = 1024; N_in = 4096; mapmode = 1; bx = id & 127;  by = id >> 7; }
    else if (id < 6144) { id -= 4096;              in = Wc_x; out = Wx_t; K = 512;  N_in = 4096; mapmode = 2; bx = id & 127;  by = id >> 7; }
    else if (id < 8192) { id -= 6144; in = Wimg; out = Wimg_t; K = 2048; N_in = 1024; mapmode = 0; bx = id & 31; by = id >> 5; }
    else                { id -= 8192; in = Whid; out = Whid_t; K = 1024; N_in = 1024; mapmode = 0; bx = id & 31; by = id >> 5; }

    __shared__ short tile[32][33];
    int n0 = bx * 32, k0 = by * 32;
    int tx = threadIdx.x & 31, ty = threadIdx.x >> 5;   // 32 x 8
    int nn = n0 + tx;
    int nsrc = (mapmode == 1) ? hmap(nn) : (mapmode == 2) ? xmap(nn) : nn;
#pragma unroll
    for (int j = 0; j < 4; j++) {
        int kw = ty + j * 8;
        tile[kw][tx] = f2bf(in[(size_t)(k0 + kw) * N_in + nsrc]);
    }
    __syncthreads();
#pragma unroll
    for (int j = 0; j < 4; j++) {
        int nw = ty + j * 8;
        out[(size_t)(n0 + nw) * K + k0 + tx] = tile[tx][nw];
    }
}

// ---------------------------------------------------------------------------
// Double-buffered MFMA core, tile 64x128, BK=64, 4 waves 2x2 (one-shot GEMMs).
template<typename OutT, bool ATOMIC, bool MAPB>
__global__ __launch_bounds__(256) void gemm_bt_k(
    const short* __restrict__ A, const short* __restrict__ Bt,
    const float* __restrict__ bias, OutT* __restrict__ out,
    int Kf, int niter, int N)
{
    __shared__ __align__(16) short As[2][2][64 * 32];
    __shared__ __align__(16) short Bs[2][2][128 * 32];
    const int tid  = threadIdx.x;
    const int lane = tid & 63, wid = tid >> 6;
    const int wm = wid >> 1, wn = wid & 1;
    const int col16 = lane & 15, quad = lane >> 4;
    const int m0 = blockIdx.y * 64;
    const int n0 = blockIdx.x * 128;
    const int kbeg = blockIdx.z * niter * 64;

    const short* agp = A  + (size_t)(m0 + wid * 16 + (lane >> 2)) * Kf + kbeg + (lane & 3) * 8;
    const short* bgp = Bt + (size_t)(n0 + wid * 32 + (lane >> 2)) * Kf + kbeg + (lane & 3) * 8;

    f32x4 acc[2][4];
#pragma unroll
    for (int i = 0; i < 2; i++)
#pragma unroll
        for (int jj = 0; jj < 4; jj++) acc[i][jj] = (f32x4)0.0f;

    async_cp16(&As[0][0][wid * 512], agp);
    async_cp16(&As[0][1][wid * 512], agp + 32);
    async_cp16(&Bs[0][0][wid * 1024],       bgp);
    async_cp16(&Bs[0][0][wid * 1024 + 512], bgp + (size_t)16 * Kf);
    async_cp16(&Bs[0][1][wid * 1024],       bgp + 32);
    async_cp16(&Bs[0][1][wid * 1024 + 512], bgp + (size_t)16 * Kf + 32);
    __syncthreads();

    int buf = 0;
#pragma unroll 1
    for (int it = 0; it < niter; ++it) {
        if (it + 1 < niter) {
            int k0 = (it + 1) * 64;
            async_cp16(&As[buf ^ 1][0][wid * 512], agp + k0);
            async_cp16(&As[buf ^ 1][1][wid * 512], agp + k0 + 32);
            async_cp16(&Bs[buf ^ 1][0][wid * 1024],       bgp + k0);
            async_cp16(&Bs[buf ^ 1][0][wid * 1024 + 512], bgp + (size_t)16 * Kf + k0);
            async_cp16(&Bs[buf ^ 1][1][wid * 1024],       bgp + k0 + 32);
            async_cp16(&Bs[buf ^ 1][1][wid * 1024 + 512], bgp + (size_t)16 * Kf + k0 + 32);
        }
        short8 af[2][2], bf[4][2];
#pragma unroll
        for (int tr = 0; tr < 2; tr++)
#pragma unroll
            for (int p = 0; p < 2; p++)
                af[tr][p] = *(const short8*)&As[buf][p][(wm * 32 + tr * 16 + col16) * 32 + quad * 8];
#pragma unroll
        for (int tc = 0; tc < 4; tc++)
#pragma unroll
            for (int p = 0; p < 2; p++)
                bf[tc][p] = *(const short8*)&Bs[buf][p][(wn * 64 + tc * 16 + col16) * 32 + quad * 8];
#pragma unroll
        for (int p = 0; p < 2; p++)
#pragma unroll
            for (int tr = 0; tr < 2; tr++)
#pragma unroll
                for (int tc = 0; tc < 4; tc++)
                    acc[tr][tc] = __builtin_amdgcn_mfma_f32_16x16x32_bf16(af[tr][p], bf[tc][p], acc[tr][tc], 0, 0, 0);
        __syncthreads();
        buf ^= 1;
    }

#pragma unroll
    for (int tr = 0; tr < 2; tr++)
#pragma unroll
        for (int tc = 0; tc < 4; tc++) {
            int colg = n0 + wn * 64 + tc * 16 + col16;
            float bv = 0.0f;
            if constexpr (!ATOMIC) bv = bias[MAPB ? xmap(colg) : colg];
#pragma unroll
            for (int r = 0; r < 4; r++) {
                int rowg = m0 + wm * 32 + tr * 16 + quad * 4 + r;
                float v = acc[tr][tc][r] + bv;
                if constexpr (ATOMIC) atomicAdd((float*)&out[(size_t)rowg * N + colg], v);
                else                  out[(size_t)rowg * N + colg] = f2bf(v);
            }
        }
}

// ---------------------------------------------------------------------------
// Persistent LSTM, two-level-barrier edition (R4 resubmit, hardened spin).
//  * grid_bar2: 8x32 two-level arrive (kills the 256-deep same-line atomic
//    serialization modeled as the ~11 us/step residual).
//  * gather software pipeline: msg indices for t+1 load during K-loop it==6
//    (covered by 2 MFMA phases); eproj short4 loads issued right after the
//    K-loop (covered by the cell-update VALU).
// Everything else (staging, swizzle, Bp persistence, c-in-regs) identical to R3.
__global__ __launch_bounds__(256, 1) void lstm_all_k(
    const short* __restrict__ Wh_t, const short* __restrict__ eproj,
    const int* __restrict__ msg,
    short* __restrict__ h_a, short* __restrict__ h_b,
    u32* __restrict__ bar)
{
    constexpr int Kf = HID;
    extern __shared__ __align__(16) short smem[];
    short* As = smem;            // [2][8192]
    short* Bs = smem + 16384;    // [2][16384]
    short* Bp = smem + 49152;    // [2][16384] persistent B tiles 0,1

    const int tid  = threadIdx.x;
    const int lane = tid & 63, wid = tid >> 6;
    const int wm = wid >> 1, wn = wid & 1;
    const int col16 = lane & 15, quad = lane >> 4;
    const int m0 = blockIdx.y * 64;
    const int n0 = blockIdx.x * 128;
    const int gid = blockIdx.x & 7;    // 8 groups x 32 blocks

    const int swz_st = (((lane & 3) - ((lane >> 3) & 3)) & 3) * 8;
    const size_t aoff = (size_t)(m0 + wid * 16 + (lane >> 2)) * Kf + swz_st;
    const short* agpA = h_a + aoff;
    const short* agpB = h_b + aoff;
    const short* bgp0 = Wh_t + (size_t)(n0 + wid * 32 + (lane >> 2)) * Kf + swz_st;
    const short* bgp1 = bgp0 + (size_t)16 * Kf;

    const int G = (n0 + wn * 64) >> 6;
    const int j = G * 16 + col16;
    const short* egbase = eproj + G * 64 + col16 * 4;   // + v*FOURH -> short4 of 4 gates

    int moff[2][4], hoff[2][4];
#pragma unroll
    for (int tr = 0; tr < 2; tr++)
#pragma unroll
        for (int r = 0; r < 4; r++) {
            int b = m0 + wm * 32 + tr * 16 + quad * 4 + r;
            moff[tr][r] = b * TT;
            hoff[tr][r] = b * HID + j;
        }

    const int swz_rd = ((quad + (col16 >> 1)) & 3) * 8;
    const int arow = (wm * 32 + col16) * 32 + swz_rd;   // + tr*512
    const int brow = (wn * 64 + col16) * 32 + swz_rd;   // + tc*512
    const int adst = wid * 512 + lane * 8;              // LDS A stripe (shorts)

    float creg[2][4];
#pragma unroll
    for (int tr = 0; tr < 2; tr++)
#pragma unroll
        for (int r = 0; r < 4; r++) creg[tr][r] = 0.0f;

    // persistent B tiles 0,1 -> Bp (drained by the first grid_bar2)
#pragma unroll
    for (int p = 0; p < 4; p++) {
        async_cp16(&Bp[p * 4096 + wid * 1024],       bgp0 + p * 32);
        async_cp16(&Bp[p * 4096 + wid * 1024 + 512], bgp1 + p * 32);
        async_cp16(&Bp[16384 + p * 4096 + wid * 1024],       bgp0 + 128 + p * 32);
        async_cp16(&Bp[16384 + p * 4096 + wid * 1024 + 512], bgp1 + 128 + p * 32);
    }

    // cold gather prefetch for t=0 (pre-barrier; eproj ready in-stream)
    int vbuf[2][4];
    short4 s4buf[2][4];
#pragma unroll
    for (int tr = 0; tr < 2; tr++)
#pragma unroll
        for (int r = 0; r < 4; r++)
            vbuf[tr][r] = msg[moff[tr][r]];
#pragma unroll
    for (int tr = 0; tr < 2; tr++)
#pragma unroll
        for (int r = 0; r < 4; r++)
            s4buf[tr][r] = *(const short4*)(egbase + (size_t)vbuf[tr][r] * FOURH);

#pragma unroll 1
    for (int t = 0; t < TT; ++t) {
        const short* agp = (t & 1) ? agpB : agpA;
        short* hw        = (t & 1) ? h_a : h_b;

        // convert the prefetched gather (s4buf loaded last step / cold path)
        float gi[2][4][4];
#pragma unroll
        for (int tr = 0; tr < 2; tr++)
#pragma unroll
            for (int r = 0; r < 4; r++) {
                short4 s4 = s4buf[tr][r];
                gi[tr][0][r] = bf2f(s4.x);
                gi[tr][1][r] = bf2f(s4.y);
                gi[tr][2][r] = bf2f(s4.z);
                gi[tr][3][r] = bf2f(s4.w);
            }

        grid_bar2(bar, (u32)(t + 1), gid);   // h_{t-1} visible at coherence point

        // ---- prologue: coherent A loads t0,t1 -> regs; write A0 to LDS
        u64 areg[2][8];
#pragma unroll
        for (int p = 0; p < 4; p++) {
            areg[0][2 * p]     = coh_ld64(agp + p * 32);
            areg[0][2 * p + 1] = coh_ld64(agp + p * 32 + 4);
        }
#pragma unroll
        for (int p = 0; p < 4; p++) {
            areg[1][2 * p]     = coh_ld64(agp + 128 + p * 32);
            areg[1][2 * p + 1] = coh_ld64(agp + 128 + p * 32 + 4);
        }
        asm volatile("s_waitcnt vmcnt(8)" ::: "memory");    // A0 landed (A1 in flight)
#pragma unroll
        for (int p = 0; p < 4; p++)
            *(u64x2*)&As[p * 2048 + adst] = (u64x2){areg[0][2 * p], areg[0][2 * p + 1]};
        asm volatile("s_waitcnt lgkmcnt(0)" ::: "memory");
        block_bar();

        f32x4 acc[2][4];
#pragma unroll
        for (int i = 0; i < 2; i++)
#pragma unroll
            for (int jj = 0; jj < 4; jj++) acc[i][jj] = (f32x4)0.0f;

#pragma unroll
        for (int it = 0; it < 8; ++it) {
            const int buf = it & 1;
            const short* Ab = &As[buf * 8192];
            const short* Bb = (it < 2) ? &Bp[it * 16384] : &Bs[buf * 16384];
            __builtin_amdgcn_s_setprio(1);
#pragma unroll
            for (int p = 0; p < 4; p++) {
                short8 af0 = *(const short8*)&Ab[p * 2048 + arow];
                short8 af1 = *(const short8*)&Ab[p * 2048 + arow + 512];
                short8 bf0 = *(const short8*)&Bb[p * 4096 + brow];
                short8 bf1 = *(const short8*)&Bb[p * 4096 + brow + 512];
                short8 bf2 = *(const short8*)&Bb[p * 4096 + brow + 1024];
                short8 bf3 = *(const short8*)&Bb[p * 4096 + brow + 1536];
                acc[0][0] = __builtin_amdgcn_mfma_f32_16x16x32_bf16(af0, bf0, acc[0][0], 0, 0, 0);
                acc[0][1] = __builtin_amdgcn_mfma_f32_16x16x32_bf16(af0, bf1, acc[0][1], 0, 0, 0);
                acc[0][2] = __builtin_amdgcn_mfma_f32_16x16x32_bf16(af0, bf2, acc[0][2], 0, 0, 0);
                acc[0][3] = __builtin_amdgcn_mfma_f32_16x16x32_bf16(af0, bf3, acc[0][3], 0, 0, 0);
                acc[1][0] = __builtin_amdgcn_mfma_f32_16x16x32_bf16(af1, bf0, acc[1][0], 0, 0, 0);
                acc[1][1] = __builtin_amdgcn_mfma_f32_16x16x32_bf16(af1, bf1, acc[1][1], 0, 0, 0);
                acc[1][2] = __builtin_amdgcn_mfma_f32_16x16x32_bf16(af1, bf2, acc[1][2], 0, 0, 0);
                acc[1][3] = __builtin_amdgcn_mfma_f32_16x16x32_bf16(af1, bf3, acc[1][3], 0, 0, 0);
            }
            __builtin_amdgcn_s_setprio(0);

            block_bar();   // all waves done reading As[buf]/Bb

            if (it < 6) {
                const int k0 = (it + 2) * 128;
                // coherent A(it+2) -> areg[buf] (slot just freed)
#pragma unroll
                for (int p = 0; p < 4; p++) {
                    areg[buf][2 * p]     = coh_ld64(agp + k0 + p * 32);
                    areg[buf][2 * p + 1] = coh_ld64(agp + k0 + p * 32 + 4);
                }
                // B(it+2) -> Bs[buf] (cached, L2-hot)
#pragma unroll
                for (int p = 0; p < 4; p++) {
                    async_cp16(&Bs[buf * 16384 + p * 4096 + wid * 1024],       bgp0 + k0 + p * 32);
                    async_cp16(&Bs[buf * 16384 + p * 4096 + wid * 1024 + 512], bgp1 + k0 + p * 32);
                }
                // newest 16 = A(it+2)+B(it+2); everything older (A/B it+1) landed
                asm volatile("s_waitcnt vmcnt(16)" ::: "memory");
                // ds_write A(it+1) from regs into As[buf^1]
#pragma unroll
                for (int p = 0; p < 4; p++)
                    *(u64x2*)&As[(buf ^ 1) * 8192 + p * 2048 + adst] =
                        (u64x2){areg[buf ^ 1][2 * p], areg[buf ^ 1][2 * p + 1]};
                asm volatile("s_waitcnt lgkmcnt(0)" ::: "memory");
                block_bar();
            } else if (it == 6) {
                asm volatile("s_waitcnt vmcnt(0)" ::: "memory");   // A7/B7 landed
#pragma unroll
                for (int p = 0; p < 4; p++)
                    *(u64x2*)&As[8192 + p * 2048 + adst] =
                        (u64x2){areg[1][2 * p], areg[1][2 * p + 1]};
                asm volatile("s_waitcnt lgkmcnt(0)" ::: "memory");
                block_bar();
                // gather pipeline stage 1: msg indices for t+1 (fly over it==7)
                if (t + 1 < TT) {
#pragma unroll
                    for (int tr = 0; tr < 2; tr++)
#pragma unroll
                        for (int r = 0; r < 4; r++)
                            vbuf[tr][r] = msg[moff[tr][r] + t + 1];
                }
            }
        }

        // gather pipeline stage 2: eproj rows for t+1 (latency covered by cell VALU)
        if (t + 1 < TT) {
            asm volatile("s_waitcnt vmcnt(0)" ::: "memory");   // msg indices landed
#pragma unroll
            for (int tr = 0; tr < 2; tr++)
#pragma unroll
                for (int r = 0; r < 4; r++)
                    s4buf[tr][r] = *(const short4*)(egbase + (size_t)vbuf[tr][r] * FOURH);
        }

        // fused cell update; c in regs; h written coherently (agent scope)
#pragma unroll
        for (int tr = 0; tr < 2; tr++)
#pragma unroll
            for (int r = 0; r < 4; r++) {
                float i_ = acc[tr][0][r] + gi[tr][0][r];
                float g_ = acc[tr][1][r] + gi[tr][1][r];
                float f_ = acc[tr][2][r] + gi[tr][2][r];
                float o_ = acc[tr][3][r] + gi[tr][3][r];
                float cn = sigmoidf_(f_ + 1.0f) * creg[tr][r] + sigmoidf_(i_) * tanhf(g_);
                creg[tr][r] = cn;
                coh_st16(&hw[hoff[tr][r]], f2bf(sigmoidf_(o_) * tanhf(cn)));
            }
    }
}

// ---------------------------------------------------------------------------
// Fallback per-step kernel (proven; used only if cooperative launch fails).
__global__ __launch_bounds__(256) void lstm_step_k(
    const short* __restrict__ h_prev, const short* __restrict__ Wh_t,
    const short* __restrict__ eproj, const int* __restrict__ msg, int t,
    float* __restrict__ c, short* __restrict__ h_next)
{
    constexpr int Kf = HID;
    extern __shared__ __align__(16) short smem[];
    short* As = smem;           // [2][4][2048] shorts
    short* Bs = smem + 16384;   // [2][4][4096] shorts

    const int tid  = threadIdx.x;
    const int lane = tid & 63, wid = tid >> 6;
    const int wm = wid >> 1, wn = wid & 1;
    const int col16 = lane & 15, quad = lane >> 4;
    const int m0 = blockIdx.y * 64;
    const int n0 = blockIdx.x * 128;

    const int swz_st = (((lane & 3) - ((lane >> 3) & 3)) & 3) * 8;
    const short* agp  = h_prev + (size_t)(m0 + wid * 16 + (lane >> 2)) * Kf + swz_st;
    const short* bgp0 = Wh_t   + (size_t)(n0 + wid * 32 + (lane >> 2)) * Kf + swz_st;
    const short* bgp1 = bgp0 + (size_t)16 * Kf;

    const int G = (n0 + wn * 64) >> 6;
    const int j = G * 16 + col16;
    float gi[2][4][4], cold[2][4];
#pragma unroll
    for (int tr = 0; tr < 2; tr++)
#pragma unroll
        for (int r = 0; r < 4; r++) {
            int b = m0 + wm * 32 + tr * 16 + quad * 4 + r;
            int v = msg[b * TT + t];
            short4 s4 = *(const short4*)(eproj + (size_t)v * FOURH + G * 64 + col16 * 4);
            gi[tr][0][r] = bf2f(s4.x);
            gi[tr][1][r] = bf2f(s4.y);
            gi[tr][2][r] = bf2f(s4.z);
            gi[tr][3][r] = bf2f(s4.w);
            cold[tr][r] = c[(size_t)b * HID + j];
        }

#pragma unroll
    for (int p = 0; p < 4; p++) {
        async_cp16(&As[p * 2048 + wid * 512], agp + p * 32);
        async_cp16(&Bs[p * 4096 + wid * 1024],       bgp0 + p * 32);
        async_cp16(&Bs[p * 4096 + wid * 1024 + 512], bgp1 + p * 32);
    }
#pragma unroll
    for (int p = 0; p < 4; p++) {
        async_cp16(&As[8192 + p * 2048 + wid * 512], agp + 128 + p * 32);
        async_cp16(&Bs[16384 + p * 4096 + wid * 1024],       bgp0 + 128 + p * 32);
        async_cp16(&Bs[16384 + p * 4096 + wid * 1024 + 512], bgp1 + 128 + p * 32);
    }

    f32x4 acc[2][4];
#pragma unroll
    for (int i = 0; i < 2; i++)
#pragma unroll
        for (int jj = 0; jj < 4; jj++) acc[i][jj] = (f32x4)0.0f;

    const int swz_rd = ((quad + (col16 >> 1)) & 3) * 8;
    const int arow = (wm * 32 + col16) * 32 + swz_rd;
    const int brow = (wn * 64 + col16) * 32 + swz_rd;

    asm volatile("s_waitcnt vmcnt(12)" ::: "memory");
    block_bar();

    int buf = 0;
#pragma unroll 1
    for (int it = 0; it < 8; ++it) {
        const short* Ab = &As[buf * 8192];
        const short* Bb = &Bs[buf * 16384];
        __builtin_amdgcn_s_setprio(1);
#pragma unroll
        for (int p = 0; p < 4; p++) {
            short8 af0 = *(const short8*)&Ab[p * 2048 + arow];
            short8 af1 = *(const short8*)&Ab[p * 2048 + arow + 512];
            short8 bf0 = *(const short8*)&Bb[p * 4096 + brow];
            short8 bf1 = *(const short8*)&Bb[p * 4096 + brow + 512];
            short8 bf2 = *(const short8*)&Bb[p * 4096 + brow + 1024];
            short8 bf3 = *(const short8*)&Bb[p * 4096 + brow + 1536];
            acc[0][0] = __builtin_amdgcn_mfma_f32_16x16x32_bf16(af0, bf0, acc[0][0], 0, 0, 0);
            acc[0][1] = __builtin_amdgcn_mfma_f32_16x16x32_bf16(af0, bf1, acc[0][1], 0, 0, 0);
            acc[0][2] = __builtin_amdgcn_mfma_f32_16x16x32_bf16(af0, bf2, acc[0][2], 0, 0, 0);
            acc[0][3] = __builtin_amdgcn_mfma_f32_16x16x32_bf16(af0, bf3, acc[0][3], 0, 0, 0);
            acc[1][0] = __builtin_amdgcn_mfma_f32_16x16x32_bf16(af1, bf0, acc[1][0], 0, 0, 0);
            acc[1][1] = __builtin_amdgcn_mfma_f32_16x16x32_bf16(af1, bf1, acc[1][1], 0, 0, 0);
            acc[1][2] = __builtin_amdgcn_mfma_f32_16x16x32_bf16(af1, bf2, acc[1][2], 0, 0, 0);
            acc[1][3] = __builtin_amdgcn_mfma_f32_16x16x32_bf16(af1, bf3, acc[1][3], 0, 0, 0);
        }
        __builtin_amdgcn_s_setprio(0);
        block_bar();
        if (it < 6) {
            const int k0 = (it + 2) * 128;
#pragma unroll
            for (int p = 0; p < 4; p++) {
                async_cp16(&As[buf * 8192 + p * 2048 + wid * 512], agp + k0 + p * 32);
                async_cp16(&Bs[buf * 16384 + p * 4096 + wid * 1024],       bgp0 + k0 + p * 32);
                async_cp16(&Bs[buf * 16384 + p * 4096 + wid * 1024 + 512], bgp1 + k0 + p * 32);
            }
            asm volatile("s_waitcnt vmcnt(12)" ::: "memory");
        } else if (it == 6) {
            asm volatile("s_waitcnt vmcnt(0)" ::: "memory");
        }
        if (it < 7) block_bar();
        buf ^= 1;
    }

#pragma unroll
    for (int tr = 0; tr < 2; tr++)
#pragma unroll
        for (int r = 0; r < 4; r++) {
            int b = m0 + wm * 32 + tr * 16 + quad * 4 + r;
            float i_ = acc[tr][0][r] + gi[tr][0][r];
            float g_ = acc[tr][1][r] + gi[tr][1][r];
            float f_ = acc[tr][2][r] + gi[tr][2][r];
            float o_ = acc[tr][3][r] + gi[tr][3][r];
            size_t idx = (size_t)b * HID + j;
            float cn = sigmoidf_(f_ + 1.0f) * cold[tr][r] + sigmoidf_(i_) * tanhf(g_);
            c[idx] = cn;
            h_next[idx] = f2bf(sigmoidf_(o_) * tanhf(cn));
        }
}

// ---------------------------------------------------------------------------
extern "C" void kernel_launch(void* const* d_in, const int* in_sizes, int n_in,
                              void* d_out, int out_size, void* d_ws, size_t ws_size,
                              hipStream_t stream) {
    const float* images = (const float*)d_in[0];
    const float* embed  = (const float*)d_in[1];
    const float* Wcell  = (const float*)d_in[2];
    const float* bcell  = (const float*)d_in[3];
    const float* Wimg   = (const float*)d_in[4];
    const float* bimg   = (const float*)d_in[5];
    const float* Whid   = (const float*)d_in[6];
    const float* bhid   = (const float*)d_in[7];
    const int*   msg    = (const int*)d_in[8];

    float* out0 = (float*)d_out;                   // images_encoded [512,1024] f32
    float* out1 = out0 + (size_t)BB * OUTN;        // hidden_encoded [512,1024] f32

    // Workspace layout (33 MB)
    char* ws = (char*)d_ws;
    const size_t MB = 1024 * 1024;
    short* Wh_t    = (short*)(ws);            //  8 MB [4096][1024] bf16, hmap
    short* Wx_t    = (short*)(ws + 8 * MB);   //  4 MB [4096][512]  bf16, xmap
    short* Wimg_t  = (short*)(ws + 12 * MB);  //  4 MB [1024][2048] bf16
    short* Whid_t  = (short*)(ws + 16 * MB);  //  2 MB [1024][1024] bf16
    short* eproj   = (short*)(ws + 18 * MB);  //  8 MB [1024][4096] bf16, bias folded, xmap layout
    short* h_a     = (short*)(ws + 26 * MB);  //  1 MB
    short* h_b     = (short*)(ws + 27 * MB);  //  1 MB
    float* cbuf    = (float*)(ws + 28 * MB);  //  2 MB (fallback c; coop barrier flags)
    short* imgs_c  = (short*)(ws + 30 * MB);  //  2 MB [512][2048] bf16
    short* embed_c = (short*)(ws + 32 * MB);  //  1 MB [1024][512] bf16

    u32* bar = (u32*)cbuf;            // zeroed by prep_k every replay (c[k]=0)

    (void)hipFuncSetAttribute((const void*)lstm_all_k,  hipFuncAttributeMaxDynamicSharedMemorySize, 163840);
    (void)hipFuncSetAttribute((const void*)lstm_step_k, hipFuncAttributeMaxDynamicSharedMemorySize, 98304);

    // merged prep: elementwise setup + all four weight transposes (one launch)
    prep_k<<<dim3(3584 + 9216), dim3(256), 0, stream>>>(
        images, imgs_c, embed, embed_c, cbuf, h_a, out0, out1, bimg, bhid,
        Wcell + (size_t)EMBD * FOURH, Wh_t, Wcell, Wx_t, Wimg, Wimg_t, Whid, Whid_t);

    // eproj = bf16(embed @ W_x + b_cell), xmap gate-interleaved (single launch)
    gemm_bt_k<short, false, true><<<dim3(FOURH / 128, VOC / 64, 1), dim3(256), 0, stream>>>(
        embed_c, Wx_t, bcell, eproj, EMBD, EMBD / 64, FOURH);

    // images_encoded: split-K=4 in one launch (grid 8x8x4 = 256 blocks)
    gemm_bt_k<float, true, false><<<dim3(OUTN / 128, BB / 64, 4), dim3(256), 0, stream>>>(
        imgs_c, Wimg_t, nullptr, out0, DIMG, 8, OUTN);

    // all 128 LSTM steps: one persistent kernel, 2-level barrier (t=127 writes h_a)
    void* kargs[6] = {(void*)&Wh_t, (void*)&eproj, (void*)&msg,
                      (void*)&h_a, (void*)&h_b, (void*)&bar};
    hipError_t ce = hipLaunchCooperativeKernel((const void*)lstm_all_k,
                                               dim3(FOURH / 128, BB / 64, 1), dim3(256, 1, 1),
                                               kargs, 163840, stream);
    if (ce != hipSuccess) {
        for (int t = 0; t < TT; t++) {
            const short* hp = (t & 1) ? h_b : h_a;
            short* hn       = (t & 1) ? h_a : h_b;
            lstm_step_k<<<dim3(FOURH / 128, BB / 64), dim3(256), 98304, stream>>>(
                hp, Wh_t, eproj, msg, t, cbuf, hn);
        }
    }

    // hidden_encoded: split-K=4 in one launch
    gemm_bt_k<float, true, false><<<dim3(OUTN / 128, BB / 64, 4), dim3(256), 0, stream>>>(
        h_a, Whid_t, nullptr, out1, HID, 4, OUTN);
}

// Round 6
// 1816.220 us; speedup vs baseline: 2.9931x; 1.1390x over previous
//
#include <hip/hip_runtime.h>
#include <hip/hip_bf16.h>

// Problem constants (from reference)
#define BB    512
#define TT    128
#define HID   1024
#define EMBD  512
#define VOC   1024
#define OUTN  1024
#define DIMG  2048
#define FOURH 4096

typedef __attribute__((ext_vector_type(8))) short  short8;   // 8 bf16 (MFMA A/B frag)
typedef __attribute__((ext_vector_type(4))) float  f32x4;    // MFMA C/D frag
typedef unsigned int u32;
typedef unsigned long long u64;
typedef __attribute__((ext_vector_type(2))) unsigned long long u64x2;  // 16B chunk

// Wh_t interleave (gate in bits 4-5 of n): n = G*64 + gate*16 + u  -> orig gate*1024 + G*16 + u
__device__ __forceinline__ int hmap(int n) {
    return ((n >> 4) & 3) * HID + ((n >> 6) << 4) + (n & 15);
}
// eproj interleave (gate in bits 0-1 of n): n = G*64 + u*4 + gate -> orig gate*1024 + G*16 + u
__device__ __forceinline__ int xmap(int n) {
    return (n & 3) * HID + ((n >> 6) << 4) + ((n >> 2) & 15);
}
__device__ __forceinline__ float sigmoidf_(float x) { return 1.0f / (1.0f + expf(-x)); }
__device__ __forceinline__ short f2bf(float x) { __hip_bfloat16 b = __float2bfloat16(x); return *(short*)&b; }
__device__ __forceinline__ float bf2f(short s) { __hip_bfloat16 b; *(short*)&b = s; return __bfloat162float(b); }

// async global->LDS, 16B per lane; lds base wave-uniform (HW adds lane*16)
__device__ __forceinline__ void async_cp16(void* lds, const void* g) {
    __builtin_amdgcn_global_load_lds((const __attribute__((address_space(1))) u32*)g,
                                     (__attribute__((address_space(3))) u32*)lds, 16, 0, 0);
}

// raw workgroup barrier with compiler memory fences (no vmcnt/lgkmcnt drain)
__device__ __forceinline__ void block_bar() {
    asm volatile("" ::: "memory");
    __builtin_amdgcn_s_barrier();
    asm volatile("" ::: "memory");
}

// coherent 16B load/store: sc0 sc1 = bypass L1 and L2, read/write coherence point.
// NOTE: compiler does NOT track these as async loads — every consumer is guarded
// by a manual s_waitcnt vmcnt(N) + sched_barrier(0) (ledger in lstm_all_k).
__device__ __forceinline__ u64x2 coh_ld128(const short* p) {
    u64x2 r;
    asm volatile("global_load_dwordx4 %0, %1, off sc0 sc1" : "=v"(r) : "v"(p) : "memory");
    return r;
}
__device__ __forceinline__ void coh_st128(short* p, u64x2 v) {
    asm volatile("global_store_dwordx4 %0, %1, off sc0 sc1" :: "v"(p), "v"(v) : "memory");
}

// Two-level grid barrier (256 blocks = 8 groups x 32). 32 adds/group line (8
// lines in parallel) + 8 root adds + one gen publish. bar layout (u32 idx):
// cnt[g]=g*64, root=1024, gen=2048. Spin bounded (safety valve).
__device__ __forceinline__ void grid_bar2(u32* bar, u32 want, int gid) {
    asm volatile("s_waitcnt vmcnt(0)" ::: "memory");   // own stores at coherence point
    block_bar();                                       // whole block drained
    if (threadIdx.x == 0) {
        u32 a = __hip_atomic_fetch_add(bar + gid * 64, 1u, __ATOMIC_RELAXED, __HIP_MEMORY_SCOPE_AGENT);
        if (a == 31u) {                                // group complete
            u32 r = __hip_atomic_fetch_add(bar + 1024, 1u, __ATOMIC_RELAXED, __HIP_MEMORY_SCOPE_AGENT);
            if (r == 7u) {                             // all groups complete
#pragma unroll
                for (int g2 = 0; g2 < 8; g2++)
                    __hip_atomic_store(bar + g2 * 64, 0u, __ATOMIC_RELAXED, __HIP_MEMORY_SCOPE_AGENT);
                __hip_atomic_store(bar + 1024, 0u, __ATOMIC_RELAXED, __HIP_MEMORY_SCOPE_AGENT);
                asm volatile("s_waitcnt vmcnt(0)" ::: "memory");   // resets visible first
                __hip_atomic_store(bar + 2048, want, __ATOMIC_RELAXED, __HIP_MEMORY_SCOPE_AGENT);
            }
        }
        u32 guard = 0;
        while (__hip_atomic_load(bar + 2048, __ATOMIC_RELAXED, __HIP_MEMORY_SCOPE_AGENT) < want) {
            __builtin_amdgcn_s_sleep(1);
            if (++guard > (1u << 17)) break;           // safety valve (never hit in practice)
        }
    }
    block_bar();
}

// ---------------------------------------------------------------------------
// Merged prep (one launch): blocks [0,3584) elementwise setup; blocks
// [3584, 3584+9216) the four tiled weight transposes out[n][k] = bf16(in[k][map(n)]).
__global__ void prep_k(const float* __restrict__ images, short* __restrict__ imgs_c,
                       const float* __restrict__ embed,  short* __restrict__ embed_c,
                       float* __restrict__ c, short* __restrict__ h0,
                       float* __restrict__ o0, float* __restrict__ o1,
                       const float* __restrict__ bimg, const float* __restrict__ bhid,
                       const float* __restrict__ Wc_h, short* __restrict__ Wh_t,
                       const float* __restrict__ Wc_x, short* __restrict__ Wx_t,
                       const float* __restrict__ Wimg, short* __restrict__ Wimg_t,
                       const float* __restrict__ Whid, short* __restrict__ Whid_t) {
    if (blockIdx.x < 3584) {
        int i = blockIdx.x * 256 + threadIdx.x;
        if (i < 262144) {                       // images: 512*2048/4
            float4 v = ((const float4*)images)[i];
            short4 o; o.x = f2bf(v.x); o.y = f2bf(v.y); o.z = f2bf(v.z); o.w = f2bf(v.w);
            ((short4*)imgs_c)[i] = o;
        } else if (i < 393216) {                // embed: 1024*512/4
            int k = i - 262144;
            float4 v = ((const float4*)embed)[k];
            short4 o; o.x = f2bf(v.x); o.y = f2bf(v.y); o.z = f2bf(v.z); o.w = f2bf(v.w);
            ((short4*)embed_c)[k] = o;
        } else {                                // state/out init: 512*1024
            int k = i - 393216;
            int n = k & (OUTN - 1);
            c[k] = 0.0f; h0[k] = 0;
            o0[k] = bimg[n]; o1[k] = bhid[n];
        }
        return;
    }
    int id = blockIdx.x - 3584;
    const float* in; short* out; int K, N_in, bx, by, mapmode;
    if (id < 4096)      { in = Wc_h; out = Wh_t;   K = 1024; N_in = 4096; mapmode = 1; bx = id & 127;  by = id >> 7; }
    else if (id < 6144) { id -= 4096;              in = Wc_x; out = Wx_t; K = 512;  N_in = 4096; mapmode = 2; bx = id & 127;  by = id >> 7; }
    else if (id < 8192) { id -= 6144; in = Wimg; out = Wimg_t; K = 2048; N_in = 1024; mapmode = 0; bx = id & 31; by = id >> 5; }
    else                { id -= 8192; in = Whid; out = Whid_t; K = 1024; N_in = 1024; mapmode = 0; bx = id & 31; by = id >> 5; }

    __shared__ short tile[32][33];
    int n0 = bx * 32, k0 = by * 32;
    int tx = threadIdx.x & 31, ty = threadIdx.x >> 5;   // 32 x 8
    int nn = n0 + tx;
    int nsrc = (mapmode == 1) ? hmap(nn) : (mapmode == 2) ? xmap(nn) : nn;
#pragma unroll
    for (int j = 0; j < 4; j++) {
        int kw = ty + j * 8;
        tile[kw][tx] = f2bf(in[(size_t)(k0 + kw) * N_in + nsrc]);
    }
    __syncthreads();
#pragma unroll
    for (int j = 0; j < 4; j++) {
        int nw = ty + j * 8;
        out[(size_t)(n0 + nw) * K + k0 + tx] = tile[tx][nw];
    }
}

// ---------------------------------------------------------------------------
// Double-buffered MFMA core, tile 64x128, BK=64, 4 waves 2x2 (one-shot GEMMs).
template<typename OutT, bool ATOMIC, bool MAPB>
__global__ __launch_bounds__(256) void gemm_bt_k(
    const short* __restrict__ A, const short* __restrict__ Bt,
    const float* __restrict__ bias, OutT* __restrict__ out,
    int Kf, int niter, int N)
{
    __shared__ __align__(16) short As[2][2][64 * 32];
    __shared__ __align__(16) short Bs[2][2][128 * 32];
    const int tid  = threadIdx.x;
    const int lane = tid & 63, wid = tid >> 6;
    const int wm = wid >> 1, wn = wid & 1;
    const int col16 = lane & 15, quad = lane >> 4;
    const int m0 = blockIdx.y * 64;
    const int n0 = blockIdx.x * 128;
    const int kbeg = blockIdx.z * niter * 64;

    const short* agp = A  + (size_t)(m0 + wid * 16 + (lane >> 2)) * Kf + kbeg + (lane & 3) * 8;
    const short* bgp = Bt + (size_t)(n0 + wid * 32 + (lane >> 2)) * Kf + kbeg + (lane & 3) * 8;

    f32x4 acc[2][4];
#pragma unroll
    for (int i = 0; i < 2; i++)
#pragma unroll
        for (int jj = 0; jj < 4; jj++) acc[i][jj] = (f32x4)0.0f;

    async_cp16(&As[0][0][wid * 512], agp);
    async_cp16(&As[0][1][wid * 512], agp + 32);
    async_cp16(&Bs[0][0][wid * 1024],       bgp);
    async_cp16(&Bs[0][0][wid * 1024 + 512], bgp + (size_t)16 * Kf);
    async_cp16(&Bs[0][1][wid * 1024],       bgp + 32);
    async_cp16(&Bs[0][1][wid * 1024 + 512], bgp + (size_t)16 * Kf + 32);
    __syncthreads();

    int buf = 0;
#pragma unroll 1
    for (int it = 0; it < niter; ++it) {
        if (it + 1 < niter) {
            int k0 = (it + 1) * 64;
            async_cp16(&As[buf ^ 1][0][wid * 512], agp + k0);
            async_cp16(&As[buf ^ 1][1][wid * 512], agp + k0 + 32);
            async_cp16(&Bs[buf ^ 1][0][wid * 1024],       bgp + k0);
            async_cp16(&Bs[buf ^ 1][0][wid * 1024 + 512], bgp + (size_t)16 * Kf + k0);
            async_cp16(&Bs[buf ^ 1][1][wid * 1024],       bgp + k0 + 32);
            async_cp16(&Bs[buf ^ 1][1][wid * 1024 + 512], bgp + (size_t)16 * Kf + k0 + 32);
        }
        short8 af[2][2], bf[4][2];
#pragma unroll
        for (int tr = 0; tr < 2; tr++)
#pragma unroll
            for (int p = 0; p < 2; p++)
                af[tr][p] = *(const short8*)&As[buf][p][(wm * 32 + tr * 16 + col16) * 32 + quad * 8];
#pragma unroll
        for (int tc = 0; tc < 4; tc++)
#pragma unroll
            for (int p = 0; p < 2; p++)
                bf[tc][p] = *(const short8*)&Bs[buf][p][(wn * 64 + tc * 16 + col16) * 32 + quad * 8];
#pragma unroll
        for (int p = 0; p < 2; p++)
#pragma unroll
            for (int tr = 0; tr < 2; tr++)
#pragma unroll
                for (int tc = 0; tc < 4; tc++)
                    acc[tr][tc] = __builtin_amdgcn_mfma_f32_16x16x32_bf16(af[tr][p], bf[tc][p], acc[tr][tc], 0, 0, 0);
        __syncthreads();
        buf ^= 1;
    }

#pragma unroll
    for (int tr = 0; tr < 2; tr++)
#pragma unroll
        for (int tc = 0; tc < 4; tc++) {
            int colg = n0 + wn * 64 + tc * 16 + col16;
            float bv = 0.0f;
            if constexpr (!ATOMIC) bv = bias[MAPB ? xmap(colg) : colg];
#pragma unroll
            for (int r = 0; r < 4; r++) {
                int rowg = m0 + wm * 32 + tr * 16 + quad * 4 + r;
                float v = acc[tr][tc][r] + bv;
                if constexpr (ATOMIC) atomicAdd((float*)&out[(size_t)rowg * N + colg], v);
                else                  out[(size_t)rowg * N + colg] = f2bf(v);
            }
        }
}

// ---------------------------------------------------------------------------
// Persistent LSTM, coalesced-coherent-traffic edition. Changes vs R5 (isolated):
//  * h STORES: cell output repacked through LDS (dead As[0] region) then ONE
//    global_store_dwordx4 sc0 sc1 per thread -> 16B full-width transactions
//    (65K/step) instead of 8 scattered 2B agent stores per thread (524K/step).
//    The pre-barrier vmcnt(0) drain shrinks accordingly.
//  * h LOADS: single 16B sc0 sc1 inline-asm loads (half the transactions).
//    Manual ledger: per K-tile = 4 A-ld128 + 8 B-cp16; steady-state wait
//    vmcnt(12); prologue vmcnt(4). sched_barrier(0) after each manual wait
//    (compiler can't track inline-asm loads - rule #18).
// Barrier (grid_bar2), Bp persistence, c-in-regs, gather pipeline: unchanged.
__global__ __launch_bounds__(256, 1) void lstm_all_k(
    const short* __restrict__ Wh_t, const short* __restrict__ eproj,
    const int* __restrict__ msg,
    short* __restrict__ h_a, short* __restrict__ h_b,
    u32* __restrict__ bar)
{
    constexpr int Kf = HID;
    extern __shared__ __align__(16) short smem[];
    short* As = smem;            // [2][8192]; As[0..2048) doubles as h repack buf
    short* Bs = smem + 16384;    // [2][16384]
    short* Bp = smem + 49152;    // [2][16384] persistent B tiles 0,1

    const int tid  = threadIdx.x;
    const int lane = tid & 63, wid = tid >> 6;
    const int wm = wid >> 1, wn = wid & 1;
    const int col16 = lane & 15, quad = lane >> 4;
    const int m0 = blockIdx.y * 64;
    const int n0 = blockIdx.x * 128;
    const int gid = blockIdx.x & 7;    // 8 groups x 32 blocks

    const int swz_st = (((lane & 3) - ((lane >> 3) & 3)) & 3) * 8;
    const size_t aoff = (size_t)(m0 + wid * 16 + (lane >> 2)) * Kf + swz_st;
    const short* agpA = h_a + aoff;
    const short* agpB = h_b + aoff;
    const short* bgp0 = Wh_t + (size_t)(n0 + wid * 32 + (lane >> 2)) * Kf + swz_st;
    const short* bgp1 = bgp0 + (size_t)16 * Kf;

    const int G = (n0 + wn * 64) >> 6;
    const int j = G * 16 + col16;
    const short* egbase = eproj + G * 64 + col16 * 4;   // + v*FOURH -> short4 of 4 gates

    int moff[2][4];
#pragma unroll
    for (int tr = 0; tr < 2; tr++)
#pragma unroll
        for (int r = 0; r < 4; r++)
            moff[tr][r] = (m0 + wm * 32 + tr * 16 + quad * 4 + r) * TT;

    const int swz_rd = ((quad + (col16 >> 1)) & 3) * 8;
    const int arow = (wm * 32 + col16) * 32 + swz_rd;   // + tr*512
    const int brow = (wn * 64 + col16) * 32 + swz_rd;   // + tc*512
    const int adst = wid * 512 + lane * 8;              // LDS A stripe (shorts)

    // h repack geometry: block owns rows m0..m0+63, cols cbase..cbase+31
    const int cbase   = blockIdx.x * 32;
    const int reprow  = tid >> 2;            // 0..63
    const int repchk  = tid & 3;             // 0..3 (16B chunk)
    const int repdst  = (wm * 32 + quad * 4) * 32 + wn * 16 + col16;  // + (tr*16+r)*32

    float creg[2][4];
#pragma unroll
    for (int tr = 0; tr < 2; tr++)
#pragma unroll
        for (int r = 0; r < 4; r++) creg[tr][r] = 0.0f;

    // persistent B tiles 0,1 -> Bp (drained by the first grid_bar2)
#pragma unroll
    for (int p = 0; p < 4; p++) {
        async_cp16(&Bp[p * 4096 + wid * 1024],       bgp0 + p * 32);
        async_cp16(&Bp[p * 4096 + wid * 1024 + 512], bgp1 + p * 32);
        async_cp16(&Bp[16384 + p * 4096 + wid * 1024],       bgp0 + 128 + p * 32);
        async_cp16(&Bp[16384 + p * 4096 + wid * 1024 + 512], bgp1 + 128 + p * 32);
    }

    // cold gather prefetch for t=0
    int vbuf[2][4];
    short4 s4buf[2][4];
#pragma unroll
    for (int tr = 0; tr < 2; tr++)
#pragma unroll
        for (int r = 0; r < 4; r++)
            vbuf[tr][r] = msg[moff[tr][r]];
#pragma unroll
    for (int tr = 0; tr < 2; tr++)
#pragma unroll
        for (int r = 0; r < 4; r++)
            s4buf[tr][r] = *(const short4*)(egbase + (size_t)vbuf[tr][r] * FOURH);

#pragma unroll 1
    for (int t = 0; t < TT; ++t) {
        const short* agp = (t & 1) ? agpB : agpA;
        short* hw        = (t & 1) ? h_a : h_b;

        // convert the prefetched gather
        float gi[2][4][4];
#pragma unroll
        for (int tr = 0; tr < 2; tr++)
#pragma unroll
            for (int r = 0; r < 4; r++) {
                short4 s4 = s4buf[tr][r];
                gi[tr][0][r] = bf2f(s4.x);
                gi[tr][1][r] = bf2f(s4.y);
                gi[tr][2][r] = bf2f(s4.z);
                gi[tr][3][r] = bf2f(s4.w);
            }

        grid_bar2(bar, (u32)(t + 1), gid);   // h_{t-1} visible at coherence point

        // ---- prologue: coherent 16B A loads t0,t1 -> regs; write A0 to LDS
        u64x2 areg[2][4];
#pragma unroll
        for (int p = 0; p < 4; p++) areg[0][p] = coh_ld128(agp + p * 32);
#pragma unroll
        for (int p = 0; p < 4; p++) areg[1][p] = coh_ld128(agp + 128 + p * 32);
        asm volatile("s_waitcnt vmcnt(4)" ::: "memory");    // A0 landed (A1 in flight)
        __builtin_amdgcn_sched_barrier(0);
#pragma unroll
        for (int p = 0; p < 4; p++)
            *(u64x2*)&As[p * 2048 + adst] = areg[0][p];
        asm volatile("s_waitcnt lgkmcnt(0)" ::: "memory");
        block_bar();

        f32x4 acc[2][4];
#pragma unroll
        for (int i = 0; i < 2; i++)
#pragma unroll
            for (int jj = 0; jj < 4; jj++) acc[i][jj] = (f32x4)0.0f;

#pragma unroll
        for (int it = 0; it < 8; ++it) {
            const int buf = it & 1;
            const short* Ab = &As[buf * 8192];
            const short* Bb = (it < 2) ? &Bp[it * 16384] : &Bs[buf * 16384];
            __builtin_amdgcn_s_setprio(1);
#pragma unroll
            for (int p = 0; p < 4; p++) {
                short8 af0 = *(const short8*)&Ab[p * 2048 + arow];
                short8 af1 = *(const short8*)&Ab[p * 2048 + arow + 512];
                short8 bf0 = *(const short8*)&Bb[p * 4096 + brow];
                short8 bf1 = *(const short8*)&Bb[p * 4096 + brow + 512];
                short8 bf2 = *(const short8*)&Bb[p * 4096 + brow + 1024];
                short8 bf3 = *(const short8*)&Bb[p * 4096 + brow + 1536];
                acc[0][0] = __builtin_amdgcn_mfma_f32_16x16x32_bf16(af0, bf0, acc[0][0], 0, 0, 0);
                acc[0][1] = __builtin_amdgcn_mfma_f32_16x16x32_bf16(af0, bf1, acc[0][1], 0, 0, 0);
                acc[0][2] = __builtin_amdgcn_mfma_f32_16x16x32_bf16(af0, bf2, acc[0][2], 0, 0, 0);
                acc[0][3] = __builtin_amdgcn_mfma_f32_16x16x32_bf16(af0, bf3, acc[0][3], 0, 0, 0);
                acc[1][0] = __builtin_amdgcn_mfma_f32_16x16x32_bf16(af1, bf0, acc[1][0], 0, 0, 0);
                acc[1][1] = __builtin_amdgcn_mfma_f32_16x16x32_bf16(af1, bf1, acc[1][1], 0, 0, 0);
                acc[1][2] = __builtin_amdgcn_mfma_f32_16x16x32_bf16(af1, bf2, acc[1][2], 0, 0, 0);
                acc[1][3] = __builtin_amdgcn_mfma_f32_16x16x32_bf16(af1, bf3, acc[1][3], 0, 0, 0);
            }
            __builtin_amdgcn_s_setprio(0);

            block_bar();   // all waves done reading As[buf]/Bb

            if (it < 6) {
                const int k0 = (it + 2) * 128;
                // coherent A(it+2) -> areg[buf] (slot just freed): 4 x 16B
#pragma unroll
                for (int p = 0; p < 4; p++)
                    areg[buf][p] = coh_ld128(agp + k0 + p * 32);
                // B(it+2) -> Bs[buf] (cached, L2-hot): 8 x cp16
#pragma unroll
                for (int p = 0; p < 4; p++) {
                    async_cp16(&Bs[buf * 16384 + p * 4096 + wid * 1024],       bgp0 + k0 + p * 32);
                    async_cp16(&Bs[buf * 16384 + p * 4096 + wid * 1024 + 512], bgp1 + k0 + p * 32);
                }
                // newest 12 = A(it+2)+B(it+2); A/B(it+1) (the older 12) landed
                asm volatile("s_waitcnt vmcnt(12)" ::: "memory");
                __builtin_amdgcn_sched_barrier(0);
#pragma unroll
                for (int p = 0; p < 4; p++)
                    *(u64x2*)&As[(buf ^ 1) * 8192 + p * 2048 + adst] = areg[buf ^ 1][p];
                asm volatile("s_waitcnt lgkmcnt(0)" ::: "memory");
                block_bar();
            } else if (it == 6) {
                asm volatile("s_waitcnt vmcnt(0)" ::: "memory");   // A7/B7 landed
                __builtin_amdgcn_sched_barrier(0);
#pragma unroll
                for (int p = 0; p < 4; p++)
                    *(u64x2*)&As[8192 + p * 2048 + adst] = areg[1][p];
                asm volatile("s_waitcnt lgkmcnt(0)" ::: "memory");
                block_bar();
                // gather pipeline stage 1: msg indices for t+1 (fly over it==7)
                if (t + 1 < TT) {
#pragma unroll
                    for (int tr = 0; tr < 2; tr++)
#pragma unroll
                        for (int r = 0; r < 4; r++)
                            vbuf[tr][r] = msg[moff[tr][r] + t + 1];
                }
            }
        }

        // gather pipeline stage 2: eproj rows for t+1 (covered by cell VALU)
        if (t + 1 < TT) {
#pragma unroll
            for (int tr = 0; tr < 2; tr++)
#pragma unroll
                for (int r = 0; r < 4; r++)
                    s4buf[tr][r] = *(const short4*)(egbase + (size_t)vbuf[tr][r] * FOURH);
        }

        // fused cell update; c in regs; h repacked into LDS (As[0..2048), dead now)
#pragma unroll
        for (int tr = 0; tr < 2; tr++)
#pragma unroll
            for (int r = 0; r < 4; r++) {
                float i_ = acc[tr][0][r] + gi[tr][0][r];
                float g_ = acc[tr][1][r] + gi[tr][1][r];
                float f_ = acc[tr][2][r] + gi[tr][2][r];
                float o_ = acc[tr][3][r] + gi[tr][3][r];
                float cn = sigmoidf_(f_ + 1.0f) * creg[tr][r] + sigmoidf_(i_) * tanhf(g_);
                creg[tr][r] = cn;
                As[repdst + (tr * 16 + r) * 32] = f2bf(sigmoidf_(o_) * tanhf(cn));
            }
        block_bar();                         // repack complete
        {
            u64x2 v = *(const u64x2*)&As[reprow * 32 + repchk * 8];
            coh_st128(hw + (size_t)(m0 + reprow) * HID + cbase + repchk * 8, v);
        }
        // store drained by next grid_bar2's vmcnt(0); its block_bar also orders
        // the LDS repack read vs next step's prologue As writes.
    }
}

// ---------------------------------------------------------------------------
// Fallback per-step kernel (proven; used only if cooperative launch fails).
__global__ __launch_bounds__(256) void lstm_step_k(
    const short* __restrict__ h_prev, const short* __restrict__ Wh_t,
    const short* __restrict__ eproj, const int* __restrict__ msg, int t,
    float* __restrict__ c, short* __restrict__ h_next)
{
    constexpr int Kf = HID;
    extern __shared__ __align__(16) short smem[];
    short* As = smem;           // [2][4][2048] shorts
    short* Bs = smem + 16384;   // [2][4][4096] shorts

    const int tid  = threadIdx.x;
    const int lane = tid & 63, wid = tid >> 6;
    const int wm = wid >> 1, wn = wid & 1;
    const int col16 = lane & 15, quad = lane >> 4;
    const int m0 = blockIdx.y * 64;
    const int n0 = blockIdx.x * 128;

    const int swz_st = (((lane & 3) - ((lane >> 3) & 3)) & 3) * 8;
    const short* agp  = h_prev + (size_t)(m0 + wid * 16 + (lane >> 2)) * Kf + swz_st;
    const short* bgp0 = Wh_t   + (size_t)(n0 + wid * 32 + (lane >> 2)) * Kf + swz_st;
    const short* bgp1 = bgp0 + (size_t)16 * Kf;

    const int G = (n0 + wn * 64) >> 6;
    const int j = G * 16 + col16;
    float gi[2][4][4], cold[2][4];
#pragma unroll
    for (int tr = 0; tr < 2; tr++)
#pragma unroll
        for (int r = 0; r < 4; r++) {
            int b = m0 + wm * 32 + tr * 16 + quad * 4 + r;
            int v = msg[b * TT + t];
            short4 s4 = *(const short4*)(eproj + (size_t)v * FOURH + G * 64 + col16 * 4);
            gi[tr][0][r] = bf2f(s4.x);
            gi[tr][1][r] = bf2f(s4.y);
            gi[tr][2][r] = bf2f(s4.z);
            gi[tr][3][r] = bf2f(s4.w);
            cold[tr][r] = c[(size_t)b * HID + j];
        }

#pragma unroll
    for (int p = 0; p < 4; p++) {
        async_cp16(&As[p * 2048 + wid * 512], agp + p * 32);
        async_cp16(&Bs[p * 4096 + wid * 1024],       bgp0 + p * 32);
        async_cp16(&Bs[p * 4096 + wid * 1024 + 512], bgp1 + p * 32);
    }
#pragma unroll
    for (int p = 0; p < 4; p++) {
        async_cp16(&As[8192 + p * 2048 + wid * 512], agp + 128 + p * 32);
        async_cp16(&Bs[16384 + p * 4096 + wid * 1024],       bgp0 + 128 + p * 32);
        async_cp16(&Bs[16384 + p * 4096 + wid * 1024 + 512], bgp1 + 128 + p * 32);
    }

    f32x4 acc[2][4];
#pragma unroll
    for (int i = 0; i < 2; i++)
#pragma unroll
        for (int jj = 0; jj < 4; jj++) acc[i][jj] = (f32x4)0.0f;

    const int swz_rd = ((quad + (col16 >> 1)) & 3) * 8;
    const int arow = (wm * 32 + col16) * 32 + swz_rd;
    const int brow = (wn * 64 + col16) * 32 + swz_rd;

    asm volatile("s_waitcnt vmcnt(12)" ::: "memory");
    block_bar();

    int buf = 0;
#pragma unroll 1
    for (int it = 0; it < 8; ++it) {
        const short* Ab = &As[buf * 8192];
        const short* Bb = &Bs[buf * 16384];
        __builtin_amdgcn_s_setprio(1);
#pragma unroll
        for (int p = 0; p < 4; p++) {
            short8 af0 = *(const short8*)&Ab[p * 2048 + arow];
            short8 af1 = *(const short8*)&Ab[p * 2048 + arow + 512];
            short8 bf0 = *(const short8*)&Bb[p * 4096 + brow];
            short8 bf1 = *(const short8*)&Bb[p * 4096 + brow + 512];
            short8 bf2 = *(const short8*)&Bb[p * 4096 + brow + 1024];
            short8 bf3 = *(const short8*)&Bb[p * 4096 + brow + 1536];
            acc[0][0] = __builtin_amdgcn_mfma_f32_16x16x32_bf16(af0, bf0, acc[0][0], 0, 0, 0);
            acc[0][1] = __builtin_amdgcn_mfma_f32_16x16x32_bf16(af0, bf1, acc[0][1], 0, 0, 0);
            acc[0][2] = __builtin_amdgcn_mfma_f32_16x16x32_bf16(af0, bf2, acc[0][2], 0, 0, 0);
            acc[0][3] = __builtin_amdgcn_mfma_f32_16x16x32_bf16(af0, bf3, acc[0][3], 0, 0, 0);
            acc[1][0] = __builtin_amdgcn_mfma_f32_16x16x32_bf16(af1, bf0, acc[1][0], 0, 0, 0);
            acc[1][1] = __builtin_amdgcn_mfma_f32_16x16x32_bf16(af1, bf1, acc[1][1], 0, 0, 0);
            acc[1][2] = __builtin_amdgcn_mfma_f32_16x16x32_bf16(af1, bf2, acc[1][2], 0, 0, 0);
            acc[1][3] = __builtin_amdgcn_mfma_f32_16x16x32_bf16(af1, bf3, acc[1][3], 0, 0, 0);
        }
        __builtin_amdgcn_s_setprio(0);
        block_bar();
        if (it < 6) {
            const int k0 = (it + 2) * 128;
#pragma unroll
            for (int p = 0; p < 4; p++) {
                async_cp16(&As[buf * 8192 + p * 2048 + wid * 512], agp + k0 + p * 32);
                async_cp16(&Bs[buf * 16384 + p * 4096 + wid * 1024],       bgp0 + k0 + p * 32);
                async_cp16(&Bs[buf * 16384 + p * 4096 + wid * 1024 + 512], bgp1 + k0 + p * 32);
            }
            asm volatile("s_waitcnt vmcnt(12)" ::: "memory");
        } else if (it == 6) {
            asm volatile("s_waitcnt vmcnt(0)" ::: "memory");
        }
        if (it < 7) block_bar();
        buf ^= 1;
    }

#pragma unroll
    for (int tr = 0; tr < 2; tr++)
#pragma unroll
        for (int r = 0; r < 4; r++) {
            int b = m0 + wm * 32 + tr * 16 + quad * 4 + r;
            float i_ = acc[tr][0][r] + gi[tr][0][r];
            float g_ = acc[tr][1][r] + gi[tr][1][r];
            float f_ = acc[tr][2][r] + gi[tr][2][r];
            float o_ = acc[tr][3][r] + gi[tr][3][r];
            size_t idx = (size_t)b * HID + j;
            float cn = sigmoidf_(f_ + 1.0f) * cold[tr][r] + sigmoidf_(i_) * tanhf(g_);
            c[idx] = cn;
            h_next[idx] = f2bf(sigmoidf_(o_) * tanhf(cn));
        }
}

// ---------------------------------------------------------------------------
extern "C" void kernel_launch(void* const* d_in, const int* in_sizes, int n_in,
                              void* d_out, int out_size, void* d_ws, size_t ws_size,
                              hipStream_t stream) {
    const float* images = (const float*)d_in[0];
    const float* embed  = (const float*)d_in[1];
    const float* Wcell  = (const float*)d_in[2];
    const float* bcell  = (const float*)d_in[3];
    const float* Wimg   = (const float*)d_in[4];
    const float* bimg   = (const float*)d_in[5];
    const float* Whid   = (const float*)d_in[6];
    const float* bhid   = (const float*)d_in[7];
    const int*   msg    = (const int*)d_in[8];

    float* out0 = (float*)d_out;                   // images_encoded [512,1024] f32
    float* out1 = out0 + (size_t)BB * OUTN;        // hidden_encoded [512,1024] f32

    // Workspace layout (33 MB)
    char* ws = (char*)d_ws;
    const size_t MB = 1024 * 1024;
    short* Wh_t    = (short*)(ws);            //  8 MB [4096][1024] bf16, hmap
    short* Wx_t    = (short*)(ws + 8 * MB);   //  4 MB [4096][512]  bf16, xmap
    short* Wimg_t  = (short*)(ws + 12 * MB);  //  4 MB [1024][2048] bf16
    short* Whid_t  = (short*)(ws + 16 * MB);  //  2 MB [1024][1024] bf16
    short* eproj   = (short*)(ws + 18 * MB);  //  8 MB [1024][4096] bf16, bias folded, xmap layout
    short* h_a     = (short*)(ws + 26 * MB);  //  1 MB
    short* h_b     = (short*)(ws + 27 * MB);  //  1 MB
    float* cbuf    = (float*)(ws + 28 * MB);  //  2 MB (fallback c; coop barrier flags)
    short* imgs_c  = (short*)(ws + 30 * MB);  //  2 MB [512][2048] bf16
    short* embed_c = (short*)(ws + 32 * MB);  //  1 MB [1024][512] bf16

    u32* bar = (u32*)cbuf;            // zeroed by prep_k every replay (c[k]=0)

    (void)hipFuncSetAttribute((const void*)lstm_all_k,  hipFuncAttributeMaxDynamicSharedMemorySize, 163840);
    (void)hipFuncSetAttribute((const void*)lstm_step_k, hipFuncAttributeMaxDynamicSharedMemorySize, 98304);

    // merged prep: elementwise setup + all four weight transposes (one launch)
    prep_k<<<dim3(3584 + 9216), dim3(256), 0, stream>>>(
        images, imgs_c, embed, embed_c, cbuf, h_a, out0, out1, bimg, bhid,
        Wcell + (size_t)EMBD * FOURH, Wh_t, Wcell, Wx_t, Wimg, Wimg_t, Whid, Whid_t);

    // eproj = bf16(embed @ W_x + b_cell), xmap gate-interleaved (single launch)
    gemm_bt_k<short, false, true><<<dim3(FOURH / 128, VOC / 64, 1), dim3(256), 0, stream>>>(
        embed_c, Wx_t, bcell, eproj, EMBD, EMBD / 64, FOURH);

    // images_encoded: split-K=4 in one launch (grid 8x8x4 = 256 blocks)
    gemm_bt_k<float, true, false><<<dim3(OUTN / 128, BB / 64, 4), dim3(256), 0, stream>>>(
        imgs_c, Wimg_t, nullptr, out0, DIMG, 8, OUTN);

    // all 128 LSTM steps: one persistent kernel (t=127 writes h_a)
    void* kargs[6] = {(void*)&Wh_t, (void*)&eproj, (void*)&msg,
                      (void*)&h_a, (void*)&h_b, (void*)&bar};
    hipError_t ce = hipLaunchCooperativeKernel((const void*)lstm_all_k,
                                               dim3(FOURH / 128, BB / 64, 1), dim3(256, 1, 1),
                                               kargs, 163840, stream);
    if (ce != hipSuccess) {
        for (int t = 0; t < TT; t++) {
            const short* hp = (t & 1) ? h_b : h_a;
            short* hn       = (t & 1) ? h_a : h_b;
            lstm_step_k<<<dim3(FOURH / 128, BB / 64), dim3(256), 98304, stream>>>(
                hp, Wh_t, eproj, msg, t, cbuf, hn);
        }
    }

    // hidden_encoded: split-K=4 in one launch
    gemm_bt_k<float, true, false><<<dim3(OUTN / 128, BB / 64, 4), dim3(256), 0, stream>>>(
        h_a, Whid_t, nullptr, out1, HID, 4, OUTN);
}

// Round 8
// 1720.489 us; speedup vs baseline: 3.1596x; 1.0556x over previous
//
#include <hip/hip_runtime.h>
#include <hip/hip_bf16.h>

// Problem constants (from reference)
#define BB    512
#define TT    128
#define HID   1024
#define EMBD  512
#define VOC   1024
#define OUTN  1024
#define DIMG  2048
#define FOURH 4096

typedef __attribute__((ext_vector_type(8))) short  short8;   // 8 bf16 (MFMA A/B frag)
typedef __attribute__((ext_vector_type(4))) float  f32x4;    // MFMA C/D frag
typedef unsigned int u32;
typedef unsigned long long u64;
typedef __attribute__((ext_vector_type(2))) unsigned long long u64x2;  // 16B chunk

// Wh_t interleave (gate in bits 4-5 of n): n = G*64 + gate*16 + u  -> orig gate*1024 + G*16 + u
__device__ __forceinline__ int hmap(int n) {
    return ((n >> 4) & 3) * HID + ((n >> 6) << 4) + (n & 15);
}
// eproj interleave (gate in bits 0-1 of n): n = G*64 + u*4 + gate -> orig gate*1024 + G*16 + u
__device__ __forceinline__ int xmap(int n) {
    return (n & 3) * HID + ((n >> 6) << 4) + ((n >> 2) & 15);
}
__device__ __forceinline__ float sigmoidf_(float x) { return 1.0f / (1.0f + expf(-x)); }
__device__ __forceinline__ short f2bf(float x) { __hip_bfloat16 b = __float2bfloat16(x); return *(short*)&b; }
__device__ __forceinline__ float bf2f(short s) { __hip_bfloat16 b; *(short*)&b = s; return __bfloat162float(b); }

// async global->LDS, 16B per lane; lds base wave-uniform (HW adds lane*16)
__device__ __forceinline__ void async_cp16(void* lds, const void* g) {
    __builtin_amdgcn_global_load_lds((const __attribute__((address_space(1))) u32*)g,
                                     (__attribute__((address_space(3))) u32*)lds, 16, 0, 0);
}

// raw workgroup barrier with compiler memory fences (no vmcnt/lgkmcnt drain)
__device__ __forceinline__ void block_bar() {
    asm volatile("" ::: "memory");
    __builtin_amdgcn_s_barrier();
    asm volatile("" ::: "memory");
}

// coherent 16B load/store: sc0 sc1 = bypass L1 and L2, read/write coherence point.
// NOTE: compiler does NOT track these as async loads — every consumer is guarded
// by a manual s_waitcnt vmcnt(N) + sched_barrier(0) (ledger in lstm_all_k).
__device__ __forceinline__ u64x2 coh_ld128(const short* p) {
    u64x2 r;
    asm volatile("global_load_dwordx4 %0, %1, off sc0 sc1" : "=v"(r) : "v"(p) : "memory");
    return r;
}
__device__ __forceinline__ void coh_st128(short* p, u64x2 v) {
    asm volatile("global_store_dwordx4 %0, %1, off sc0 sc1" :: "v"(p), "v"(v) : "memory");
}

// Per-group generation barrier (32 blocks sharing blockIdx.y = one independent
// recurrence chain). Store-arrive (NO atomic RMW): block stores its generation
// into slots[x]; wave 0's 64 lanes poll the 32 slots (coalesced coherent load +
// __all vote). Groups never wait on each other. Monotonic generations -> no
// reset. Caller ordering: vmcnt(0) drains h stores BEFORE the slot store;
// consumers' sc0 sc1 h loads read the coherence point after the vote passes.
// Guard = 2^14: a wedged barrier exits in ~8 ms -> visible numeric failure
// WITH counters instead of a container-killing hang (R7 lesson).
__device__ __forceinline__ void group_bar(u32* slots, u32 want, int x) {
    asm volatile("s_waitcnt vmcnt(0)" ::: "memory");   // own h stores at coherence point
    block_bar();                                       // whole block drained
    if (threadIdx.x < 64) {
        if (threadIdx.x == 0)
            __hip_atomic_store(slots + x, want, __ATOMIC_RELAXED, __HIP_MEMORY_SCOPE_AGENT);
        const int sl = threadIdx.x & 31;
        u32 guard = 0;
        for (;;) {
            u32 v = __hip_atomic_load(slots + sl, __ATOMIC_RELAXED, __HIP_MEMORY_SCOPE_AGENT);
            if (__all((int)(v >= want))) break;
            __builtin_amdgcn_s_sleep(1);
            if (++guard > (1u << 14)) break;           // safety valve
        }
    }
    block_bar();
}

// ---------------------------------------------------------------------------
// Merged prep (one launch): blocks [0,3584) elementwise setup; blocks
// [3584, 3584+9216) the four tiled weight transposes out[n][k] = bf16(in[k][map(n)]).
__global__ void prep_k(const float* __restrict__ images, short* __restrict__ imgs_c,
                       const float* __restrict__ embed,  short* __restrict__ embed_c,
                       float* __restrict__ c, short* __restrict__ h0,
                       float* __restrict__ o0, float* __restrict__ o1,
                       const float* __restrict__ bimg, const float* __restrict__ bhid,
                       const float* __restrict__ Wc_h, short* __restrict__ Wh_t,
                       const float* __restrict__ Wc_x, short* __restrict__ Wx_t,
                       const float* __restrict__ Wimg, short* __restrict__ Wimg_t,
                       const float* __restrict__ Whid, short* __restrict__ Whid_t) {
    if (blockIdx.x < 3584) {
        int i = blockIdx.x * 256 + threadIdx.x;
        if (i < 262144) {                       // images: 512*2048/4
            float4 v = ((const float4*)images)[i];
            short4 o; o.x = f2bf(v.x); o.y = f2bf(v.y); o.z = f2bf(v.z); o.w = f2bf(v.w);
            ((short4*)imgs_c)[i] = o;
        } else if (i < 393216) {                // embed: 1024*512/4
            int k = i - 262144;
            float4 v = ((const float4*)embed)[k];
            short4 o; o.x = f2bf(v.x); o.y = f2bf(v.y); o.z = f2bf(v.z); o.w = f2bf(v.w);
            ((short4*)embed_c)[k] = o;
        } else {                                // state/out init: 512*1024
            int k = i - 393216;
            int n = k & (OUTN - 1);
            c[k] = 0.0f; h0[k] = 0;
            o0[k] = bimg[n]; o1[k] = bhid[n];
        }
        return;
    }
    int id = blockIdx.x - 3584;
    const float* in; short* out; int K, N_in, bx, by, mapmode;
    if (id < 4096)      { in = Wc_h; out = Wh_t;   K = 1024; N_in = 4096; mapmode = 1; bx = id & 127;  by = id >> 7; }
    else if (id < 6144) { id -= 4096;              in = Wc_x; out = Wx_t; K = 512;  N_in = 4096; mapmode = 2; bx = id & 127;  by = id >> 7; }
    else if (id < 8192) { id -= 6144; in = Wimg; out = Wimg_t; K = 2048; N_in = 1024; mapmode = 0; bx = id & 31; by = id >> 5; }
    else                { id -= 8192; in = Whid; out = Whid_t; K = 1024; N_in = 1024; mapmode = 0; bx = id & 31; by = id >> 5; }

    __shared__ short tile[32][33];
    int n0 = bx * 32, k0 = by * 32;
    int tx = threadIdx.x & 31, ty = threadIdx.x >> 5;   // 32 x 8
    int nn = n0 + tx;
    int nsrc = (mapmode == 1) ? hmap(nn) : (mapmode == 2) ? xmap(nn) : nn;
#pragma unroll
    for (int j = 0; j < 4; j++) {
        int kw = ty + j * 8;
        tile[kw][tx] = f2bf(in[(size_t)(k0 + kw) * N_in + nsrc]);
    }
    __syncthreads();
#pragma unroll
    for (int j = 0; j < 4; j++) {
        int nw = ty + j * 8;
        out[(size_t)(n0 + nw) * K + k0 + tx] = tile[tx][nw];
    }
}

// ---------------------------------------------------------------------------
// Double-buffered MFMA core, tile 64x128, BK=64, 4 waves 2x2 (one-shot GEMMs).
template<typename OutT, bool ATOMIC, bool MAPB>
__global__ __launch_bounds__(256) void gemm_bt_k(
    const short* __restrict__ A, const short* __restrict__ Bt,
    const float* __restrict__ bias, OutT* __restrict__ out,
    int Kf, int niter, int N)
{
    __shared__ __align__(16) short As[2][2][64 * 32];
    __shared__ __align__(16) short Bs[2][2][128 * 32];
    const int tid  = threadIdx.x;
    const int lane = tid & 63, wid = tid >> 6;
    const int wm = wid >> 1, wn = wid & 1;
    const int col16 = lane & 15, quad = lane >> 4;
    const int m0 = blockIdx.y * 64;
    const int n0 = blockIdx.x * 128;
    const int kbeg = blockIdx.z * niter * 64;

    const short* agp = A  + (size_t)(m0 + wid * 16 + (lane >> 2)) * Kf + kbeg + (lane & 3) * 8;
    const short* bgp = Bt + (size_t)(n0 + wid * 32 + (lane >> 2)) * Kf + kbeg + (lane & 3) * 8;

    f32x4 acc[2][4];
#pragma unroll
    for (int i = 0; i < 2; i++)
#pragma unroll
        for (int jj = 0; jj < 4; jj++) acc[i][jj] = (f32x4)0.0f;

    async_cp16(&As[0][0][wid * 512], agp);
    async_cp16(&As[0][1][wid * 512], agp + 32);
    async_cp16(&Bs[0][0][wid * 1024],       bgp);
    async_cp16(&Bs[0][0][wid * 1024 + 512], bgp + (size_t)16 * Kf);
    async_cp16(&Bs[0][1][wid * 1024],       bgp + 32);
    async_cp16(&Bs[0][1][wid * 1024 + 512], bgp + (size_t)16 * Kf + 32);
    __syncthreads();

    int buf = 0;
#pragma unroll 1
    for (int it = 0; it < niter; ++it) {
        if (it + 1 < niter) {
            int k0 = (it + 1) * 64;
            async_cp16(&As[buf ^ 1][0][wid * 512], agp + k0);
            async_cp16(&As[buf ^ 1][1][wid * 512], agp + k0 + 32);
            async_cp16(&Bs[buf ^ 1][0][wid * 1024],       bgp + k0);
            async_cp16(&Bs[buf ^ 1][0][wid * 1024 + 512], bgp + (size_t)16 * Kf + k0);
            async_cp16(&Bs[buf ^ 1][1][wid * 1024],       bgp + k0 + 32);
            async_cp16(&Bs[buf ^ 1][1][wid * 1024 + 512], bgp + (size_t)16 * Kf + k0 + 32);
        }
        short8 af[2][2], bf[4][2];
#pragma unroll
        for (int tr = 0; tr < 2; tr++)
#pragma unroll
            for (int p = 0; p < 2; p++)
                af[tr][p] = *(const short8*)&As[buf][p][(wm * 32 + tr * 16 + col16) * 32 + quad * 8];
#pragma unroll
        for (int tc = 0; tc < 4; tc++)
#pragma unroll
            for (int p = 0; p < 2; p++)
                bf[tc][p] = *(const short8*)&Bs[buf][p][(wn * 64 + tc * 16 + col16) * 32 + quad * 8];
#pragma unroll
        for (int p = 0; p < 2; p++)
#pragma unroll
            for (int tr = 0; tr < 2; tr++)
#pragma unroll
                for (int tc = 0; tc < 4; tc++)
                    acc[tr][tc] = __builtin_amdgcn_mfma_f32_16x16x32_bf16(af[tr][p], bf[tc][p], acc[tr][tc], 0, 0, 0);
        __syncthreads();
        buf ^= 1;
    }

#pragma unroll
    for (int tr = 0; tr < 2; tr++)
#pragma unroll
        for (int tc = 0; tc < 4; tc++) {
            int colg = n0 + wn * 64 + tc * 16 + col16;
            float bv = 0.0f;
            if constexpr (!ATOMIC) bv = bias[MAPB ? xmap(colg) : colg];
#pragma unroll
            for (int r = 0; r < 4; r++) {
                int rowg = m0 + wm * 32 + tr * 16 + quad * 4 + r;
                float v = acc[tr][tc][r] + bv;
                if constexpr (ATOMIC) atomicAdd((float*)&out[(size_t)rowg * N + colg], v);
                else                  out[(size_t)rowg * N + colg] = f2bf(v);
            }
        }
}

// ---------------------------------------------------------------------------
// Persistent LSTM, decoupled-group-barrier edition (R7 resubmit, tighter guard).
//  * group_bar replaces the global two-level barrier. The 8 row-groups
//    (same blockIdx.y) are independent recurrence chains — block (x,y) reads
//    h rows [64y,64y+64) written only by blocks (*,y). Each group syncs among
//    its own 32 blocks via store-arrive + all-poll (no RMW serialization, no
//    root chain, no global wake, no cross-group lockstep).
// Everything else (coalesced h exchange, staging ledger, Bp persistence,
// c-in-regs, gather pipeline) byte-identical to R6 (proven 1745 us kernel).
__global__ __launch_bounds__(256, 1) void lstm_all_k(
    const short* __restrict__ Wh_t, const short* __restrict__ eproj,
    const int* __restrict__ msg,
    short* __restrict__ h_a, short* __restrict__ h_b,
    u32* __restrict__ bar)
{
    constexpr int Kf = HID;
    extern __shared__ __align__(16) short smem[];
    short* As = smem;            // [2][8192]; As[0..2048) doubles as h repack buf
    short* Bs = smem + 16384;    // [2][16384]
    short* Bp = smem + 49152;    // [2][16384] persistent B tiles 0,1

    const int tid  = threadIdx.x;
    const int lane = tid & 63, wid = tid >> 6;
    const int wm = wid >> 1, wn = wid & 1;
    const int col16 = lane & 15, quad = lane >> 4;
    const int m0 = blockIdx.y * 64;
    const int n0 = blockIdx.x * 128;
    u32* slots = bar + blockIdx.y * 64;   // group slot array (32 u32, own 256B region)

    const int swz_st = (((lane & 3) - ((lane >> 3) & 3)) & 3) * 8;
    const size_t aoff = (size_t)(m0 + wid * 16 + (lane >> 2)) * Kf + swz_st;
    const short* agpA = h_a + aoff;
    const short* agpB = h_b + aoff;
    const short* bgp0 = Wh_t + (size_t)(n0 + wid * 32 + (lane >> 2)) * Kf + swz_st;
    const short* bgp1 = bgp0 + (size_t)16 * Kf;

    const int G = (n0 + wn * 64) >> 6;
    const int j = G * 16 + col16;
    const short* egbase = eproj + G * 64 + col16 * 4;   // + v*FOURH -> short4 of 4 gates

    int moff[2][4];
#pragma unroll
    for (int tr = 0; tr < 2; tr++)
#pragma unroll
        for (int r = 0; r < 4; r++)
            moff[tr][r] = (m0 + wm * 32 + tr * 16 + quad * 4 + r) * TT;

    const int swz_rd = ((quad + (col16 >> 1)) & 3) * 8;
    const int arow = (wm * 32 + col16) * 32 + swz_rd;   // + tr*512
    const int brow = (wn * 64 + col16) * 32 + swz_rd;   // + tc*512
    const int adst = wid * 512 + lane * 8;              // LDS A stripe (shorts)

    // h repack geometry: block owns rows m0..m0+63, cols cbase..cbase+31
    const int cbase   = blockIdx.x * 32;
    const int reprow  = tid >> 2;            // 0..63
    const int repchk  = tid & 3;             // 0..3 (16B chunk)
    const int repdst  = (wm * 32 + quad * 4) * 32 + wn * 16 + col16;  // + (tr*16+r)*32

    float creg[2][4];
#pragma unroll
    for (int tr = 0; tr < 2; tr++)
#pragma unroll
        for (int r = 0; r < 4; r++) creg[tr][r] = 0.0f;

    // persistent B tiles 0,1 -> Bp (drained by the first group_bar)
#pragma unroll
    for (int p = 0; p < 4; p++) {
        async_cp16(&Bp[p * 4096 + wid * 1024],       bgp0 + p * 32);
        async_cp16(&Bp[p * 4096 + wid * 1024 + 512], bgp1 + p * 32);
        async_cp16(&Bp[16384 + p * 4096 + wid * 1024],       bgp0 + 128 + p * 32);
        async_cp16(&Bp[16384 + p * 4096 + wid * 1024 + 512], bgp1 + 128 + p * 32);
    }

    // cold gather prefetch for t=0
    int vbuf[2][4];
    short4 s4buf[2][4];
#pragma unroll
    for (int tr = 0; tr < 2; tr++)
#pragma unroll
        for (int r = 0; r < 4; r++)
            vbuf[tr][r] = msg[moff[tr][r]];
#pragma unroll
    for (int tr = 0; tr < 2; tr++)
#pragma unroll
        for (int r = 0; r < 4; r++)
            s4buf[tr][r] = *(const short4*)(egbase + (size_t)vbuf[tr][r] * FOURH);

#pragma unroll 1
    for (int t = 0; t < TT; ++t) {
        const short* agp = (t & 1) ? agpB : agpA;
        short* hw        = (t & 1) ? h_a : h_b;

        // convert the prefetched gather
        float gi[2][4][4];
#pragma unroll
        for (int tr = 0; tr < 2; tr++)
#pragma unroll
            for (int r = 0; r < 4; r++) {
                short4 s4 = s4buf[tr][r];
                gi[tr][0][r] = bf2f(s4.x);
                gi[tr][1][r] = bf2f(s4.y);
                gi[tr][2][r] = bf2f(s4.z);
                gi[tr][3][r] = bf2f(s4.w);
            }

        group_bar(slots, (u32)(t + 1), blockIdx.x);   // group's h_{t-1} at coherence point

        // ---- prologue: coherent 16B A loads t0,t1 -> regs; write A0 to LDS
        u64x2 areg[2][4];
#pragma unroll
        for (int p = 0; p < 4; p++) areg[0][p] = coh_ld128(agp + p * 32);
#pragma unroll
        for (int p = 0; p < 4; p++) areg[1][p] = coh_ld128(agp + 128 + p * 32);
        asm volatile("s_waitcnt vmcnt(4)" ::: "memory");    // A0 landed (A1 in flight)
        __builtin_amdgcn_sched_barrier(0);
#pragma unroll
        for (int p = 0; p < 4; p++)
            *(u64x2*)&As[p * 2048 + adst] = areg[0][p];
        asm volatile("s_waitcnt lgkmcnt(0)" ::: "memory");
        block_bar();

        f32x4 acc[2][4];
#pragma unroll
        for (int i = 0; i < 2; i++)
#pragma unroll
            for (int jj = 0; jj < 4; jj++) acc[i][jj] = (f32x4)0.0f;

#pragma unroll
        for (int it = 0; it < 8; ++it) {
            const int buf = it & 1;
            const short* Ab = &As[buf * 8192];
            const short* Bb = (it < 2) ? &Bp[it * 16384] : &Bs[buf * 16384];
            __builtin_amdgcn_s_setprio(1);
#pragma unroll
            for (int p = 0; p < 4; p++) {
                short8 af0 = *(const short8*)&Ab[p * 2048 + arow];
                short8 af1 = *(const short8*)&Ab[p * 2048 + arow + 512];
                short8 bf0 = *(const short8*)&Bb[p * 4096 + brow];
                short8 bf1 = *(const short8*)&Bb[p * 4096 + brow + 512];
                short8 bf2 = *(const short8*)&Bb[p * 4096 + brow + 1024];
                short8 bf3 = *(const short8*)&Bb[p * 4096 + brow + 1536];
                acc[0][0] = __builtin_amdgcn_mfma_f32_16x16x32_bf16(af0, bf0, acc[0][0], 0, 0, 0);
                acc[0][1] = __builtin_amdgcn_mfma_f32_16x16x32_bf16(af0, bf1, acc[0][1], 0, 0, 0);
                acc[0][2] = __builtin_amdgcn_mfma_f32_16x16x32_bf16(af0, bf2, acc[0][2], 0, 0, 0);
                acc[0][3] = __builtin_amdgcn_mfma_f32_16x16x32_bf16(af0, bf3, acc[0][3], 0, 0, 0);
                acc[1][0] = __builtin_amdgcn_mfma_f32_16x16x32_bf16(af1, bf0, acc[1][0], 0, 0, 0);
                acc[1][1] = __builtin_amdgcn_mfma_f32_16x16x32_bf16(af1, bf1, acc[1][1], 0, 0, 0);
                acc[1][2] = __builtin_amdgcn_mfma_f32_16x16x32_bf16(af1, bf2, acc[1][2], 0, 0, 0);
                acc[1][3] = __builtin_amdgcn_mfma_f32_16x16x32_bf16(af1, bf3, acc[1][3], 0, 0, 0);
            }
            __builtin_amdgcn_s_setprio(0);

            block_bar();   // all waves done reading As[buf]/Bb

            if (it < 6) {
                const int k0 = (it + 2) * 128;
                // coherent A(it+2) -> areg[buf] (slot just freed): 4 x 16B
#pragma unroll
                for (int p = 0; p < 4; p++)
                    areg[buf][p] = coh_ld128(agp + k0 + p * 32);
                // B(it+2) -> Bs[buf] (cached, L2-hot): 8 x cp16
#pragma unroll
                for (int p = 0; p < 4; p++) {
                    async_cp16(&Bs[buf * 16384 + p * 4096 + wid * 1024],       bgp0 + k0 + p * 32);
                    async_cp16(&Bs[buf * 16384 + p * 4096 + wid * 1024 + 512], bgp1 + k0 + p * 32);
                }
                // newest 12 = A(it+2)+B(it+2); A/B(it+1) (the older 12) landed
                asm volatile("s_waitcnt vmcnt(12)" ::: "memory");
                __builtin_amdgcn_sched_barrier(0);
#pragma unroll
                for (int p = 0; p < 4; p++)
                    *(u64x2*)&As[(buf ^ 1) * 8192 + p * 2048 + adst] = areg[buf ^ 1][p];
                asm volatile("s_waitcnt lgkmcnt(0)" ::: "memory");
                block_bar();
            } else if (it == 6) {
                asm volatile("s_waitcnt vmcnt(0)" ::: "memory");   // A7/B7 landed
                __builtin_amdgcn_sched_barrier(0);
#pragma unroll
                for (int p = 0; p < 4; p++)
                    *(u64x2*)&As[8192 + p * 2048 + adst] = areg[1][p];
                asm volatile("s_waitcnt lgkmcnt(0)" ::: "memory");
                block_bar();
                // gather pipeline stage 1: msg indices for t+1 (fly over it==7)
                if (t + 1 < TT) {
#pragma unroll
                    for (int tr = 0; tr < 2; tr++)
#pragma unroll
                        for (int r = 0; r < 4; r++)
                            vbuf[tr][r] = msg[moff[tr][r] + t + 1];
                }
            }
        }

        // gather pipeline stage 2: eproj rows for t+1 (covered by cell VALU)
        if (t + 1 < TT) {
#pragma unroll
            for (int tr = 0; tr < 2; tr++)
#pragma unroll
                for (int r = 0; r < 4; r++)
                    s4buf[tr][r] = *(const short4*)(egbase + (size_t)vbuf[tr][r] * FOURH);
        }

        // fused cell update; c in regs; h repacked into LDS (As[0..2048), dead now)
#pragma unroll
        for (int tr = 0; tr < 2; tr++)
#pragma unroll
            for (int r = 0; r < 4; r++) {
                float i_ = acc[tr][0][r] + gi[tr][0][r];
                float g_ = acc[tr][1][r] + gi[tr][1][r];
                float f_ = acc[tr][2][r] + gi[tr][2][r];
                float o_ = acc[tr][3][r] + gi[tr][3][r];
                float cn = sigmoidf_(f_ + 1.0f) * creg[tr][r] + sigmoidf_(i_) * tanhf(g_);
                creg[tr][r] = cn;
                As[repdst + (tr * 16 + r) * 32] = f2bf(sigmoidf_(o_) * tanhf(cn));
            }
        block_bar();                         // repack complete
        {
            u64x2 v = *(const u64x2*)&As[reprow * 32 + repchk * 8];
            coh_st128(hw + (size_t)(m0 + reprow) * HID + cbase + repchk * 8, v);
        }
        // store drained by next group_bar's vmcnt(0); its block_bar also orders
        // the LDS repack read vs next step's prologue As writes.
    }
}

// ---------------------------------------------------------------------------
// Fallback per-step kernel (proven; used only if cooperative launch fails).
__global__ __launch_bounds__(256) void lstm_step_k(
    const short* __restrict__ h_prev, const short* __restrict__ Wh_t,
    const short* __restrict__ eproj, const int* __restrict__ msg, int t,
    float* __restrict__ c, short* __restrict__ h_next)
{
    constexpr int Kf = HID;
    extern __shared__ __align__(16) short smem[];
    short* As = smem;           // [2][4][2048] shorts
    short* Bs = smem + 16384;   // [2][4][4096] shorts

    const int tid  = threadIdx.x;
    const int lane = tid & 63, wid = tid >> 6;
    const int wm = wid >> 1, wn = wid & 1;
    const int col16 = lane & 15, quad = lane >> 4;
    const int m0 = blockIdx.y * 64;
    const int n0 = blockIdx.x * 128;

    const int swz_st = (((lane & 3) - ((lane >> 3) & 3)) & 3) * 8;
    const short* agp  = h_prev + (size_t)(m0 + wid * 16 + (lane >> 2)) * Kf + swz_st;
    const short* bgp0 = Wh_t   + (size_t)(n0 + wid * 32 + (lane >> 2)) * Kf + swz_st;
    const short* bgp1 = bgp0 + (size_t)16 * Kf;

    const int G = (n0 + wn * 64) >> 6;
    const int j = G * 16 + col16;
    float gi[2][4][4], cold[2][4];
#pragma unroll
    for (int tr = 0; tr < 2; tr++)
#pragma unroll
        for (int r = 0; r < 4; r++) {
            int b = m0 + wm * 32 + tr * 16 + quad * 4 + r;
            int v = msg[b * TT + t];
            short4 s4 = *(const short4*)(eproj + (size_t)v * FOURH + G * 64 + col16 * 4);
            gi[tr][0][r] = bf2f(s4.x);
            gi[tr][1][r] = bf2f(s4.y);
            gi[tr][2][r] = bf2f(s4.z);
            gi[tr][3][r] = bf2f(s4.w);
            cold[tr][r] = c[(size_t)b * HID + j];
        }

#pragma unroll
    for (int p = 0; p < 4; p++) {
        async_cp16(&As[p * 2048 + wid * 512], agp + p * 32);
        async_cp16(&Bs[p * 4096 + wid * 1024],       bgp0 + p * 32);
        async_cp16(&Bs[p * 4096 + wid * 1024 + 512], bgp1 + p * 32);
    }
#pragma unroll
    for (int p = 0; p < 4; p++) {
        async_cp16(&As[8192 + p * 2048 + wid * 512], agp + 128 + p * 32);
        async_cp16(&Bs[16384 + p * 4096 + wid * 1024],       bgp0 + 128 + p * 32);
        async_cp16(&Bs[16384 + p * 4096 + wid * 1024 + 512], bgp1 + 128 + p * 32);
    }

    f32x4 acc[2][4];
#pragma unroll
    for (int i = 0; i < 2; i++)
#pragma unroll
        for (int jj = 0; jj < 4; jj++) acc[i][jj] = (f32x4)0.0f;

    const int swz_rd = ((quad + (col16 >> 1)) & 3) * 8;
    const int arow = (wm * 32 + col16) * 32 + swz_rd;
    const int brow = (wn * 64 + col16) * 32 + swz_rd;

    asm volatile("s_waitcnt vmcnt(12)" ::: "memory");
    block_bar();

    int buf = 0;
#pragma unroll 1
    for (int it = 0; it < 8; ++it) {
        const short* Ab = &As[buf * 8192];
        const short* Bb = &Bs[buf * 16384];
        __builtin_amdgcn_s_setprio(1);
#pragma unroll
        for (int p = 0; p < 4; p++) {
            short8 af0 = *(const short8*)&Ab[p * 2048 + arow];
            short8 af1 = *(const short8*)&Ab[p * 2048 + arow + 512];
            short8 bf0 = *(const short8*)&Bb[p * 4096 + brow];
            short8 bf1 = *(const short8*)&Bb[p * 4096 + brow + 512];
            short8 bf2 = *(const short8*)&Bb[p * 4096 + brow + 1024];
            short8 bf3 = *(const short8*)&Bb[p * 4096 + brow + 1536];
            acc[0][0] = __builtin_amdgcn_mfma_f32_16x16x32_bf16(af0, bf0, acc[0][0], 0, 0, 0);
            acc[0][1] = __builtin_amdgcn_mfma_f32_16x16x32_bf16(af0, bf1, acc[0][1], 0, 0, 0);
            acc[0][2] = __builtin_amdgcn_mfma_f32_16x16x32_bf16(af0, bf2, acc[0][2], 0, 0, 0);
            acc[0][3] = __builtin_amdgcn_mfma_f32_16x16x32_bf16(af0, bf3, acc[0][3], 0, 0, 0);
            acc[1][0] = __builtin_amdgcn_mfma_f32_16x16x32_bf16(af1, bf0, acc[1][0], 0, 0, 0);
            acc[1][1] = __builtin_amdgcn_mfma_f32_16x16x32_bf16(af1, bf1, acc[1][1], 0, 0, 0);
            acc[1][2] = __builtin_amdgcn_mfma_f32_16x16x32_bf16(af1, bf2, acc[1][2], 0, 0, 0);
            acc[1][3] = __builtin_amdgcn_mfma_f32_16x16x32_bf16(af1, bf3, acc[1][3], 0, 0, 0);
        }
        __builtin_amdgcn_s_setprio(0);
        block_bar();
        if (it < 6) {
            const int k0 = (it + 2) * 128;
#pragma unroll
            for (int p = 0; p < 4; p++) {
                async_cp16(&As[buf * 8192 + p * 2048 + wid * 512], agp + k0 + p * 32);
                async_cp16(&Bs[buf * 16384 + p * 4096 + wid * 1024],       bgp0 + k0 + p * 32);
                async_cp16(&Bs[buf * 16384 + p * 4096 + wid * 1024 + 512], bgp1 + k0 + p * 32);
            }
            asm volatile("s_waitcnt vmcnt(12)" ::: "memory");
        } else if (it == 6) {
            asm volatile("s_waitcnt vmcnt(0)" ::: "memory");
        }
        if (it < 7) block_bar();
        buf ^= 1;
    }

#pragma unroll
    for (int tr = 0; tr < 2; tr++)
#pragma unroll
        for (int r = 0; r < 4; r++) {
            int b = m0 + wm * 32 + tr * 16 + quad * 4 + r;
            float i_ = acc[tr][0][r] + gi[tr][0][r];
            float g_ = acc[tr][1][r] + gi[tr][1][r];
            float f_ = acc[tr][2][r] + gi[tr][2][r];
            float o_ = acc[tr][3][r] + gi[tr][3][r];
            size_t idx = (size_t)b * HID + j;
            float cn = sigmoidf_(f_ + 1.0f) * cold[tr][r] + sigmoidf_(i_) * tanhf(g_);
            c[idx] = cn;
            h_next[idx] = f2bf(sigmoidf_(o_) * tanhf(cn));
        }
}

// ---------------------------------------------------------------------------
extern "C" void kernel_launch(void* const* d_in, const int* in_sizes, int n_in,
                              void* d_out, int out_size, void* d_ws, size_t ws_size,
                              hipStream_t stream) {
    const float* images = (const float*)d_in[0];
    const float* embed  = (const float*)d_in[1];
    const float* Wcell  = (const float*)d_in[2];
    const float* bcell  = (const float*)d_in[3];
    const float* Wimg   = (const float*)d_in[4];
    const float* bimg   = (const float*)d_in[5];
    const float* Whid   = (const float*)d_in[6];
    const float* bhid   = (const float*)d_in[7];
    const int*   msg    = (const int*)d_in[8];

    float* out0 = (float*)d_out;                   // images_encoded [512,1024] f32
    float* out1 = out0 + (size_t)BB * OUTN;        // hidden_encoded [512,1024] f32

    // Workspace layout (33 MB)
    char* ws = (char*)d_ws;
    const size_t MB = 1024 * 1024;
    short* Wh_t    = (short*)(ws);            //  8 MB [4096][1024] bf16, hmap
    short* Wx_t    = (short*)(ws + 8 * MB);   //  4 MB [4096][512]  bf16, xmap
    short* Wimg_t  = (short*)(ws + 12 * MB);  //  4 MB [1024][2048] bf16
    short* Whid_t  = (short*)(ws + 16 * MB);  //  2 MB [1024][1024] bf16
    short* eproj   = (short*)(ws + 18 * MB);  //  8 MB [1024][4096] bf16, bias folded, xmap layout
    short* h_a     = (short*)(ws + 26 * MB);  //  1 MB
    short* h_b     = (short*)(ws + 27 * MB);  //  1 MB
    float* cbuf    = (float*)(ws + 28 * MB);  //  2 MB (fallback c; barrier slots)
    short* imgs_c  = (short*)(ws + 30 * MB);  //  2 MB [512][2048] bf16
    short* embed_c = (short*)(ws + 32 * MB);  //  1 MB [1024][512] bf16

    u32* bar = (u32*)cbuf;            // zeroed by prep_k every replay (c[k]=0)

    (void)hipFuncSetAttribute((const void*)lstm_all_k,  hipFuncAttributeMaxDynamicSharedMemorySize, 163840);
    (void)hipFuncSetAttribute((const void*)lstm_step_k, hipFuncAttributeMaxDynamicSharedMemorySize, 98304);

    // merged prep: elementwise setup + all four weight transposes (one launch)
    prep_k<<<dim3(3584 + 9216), dim3(256), 0, stream>>>(
        images, imgs_c, embed, embed_c, cbuf, h_a, out0, out1, bimg, bhid,
        Wcell + (size_t)EMBD * FOURH, Wh_t, Wcell, Wx_t, Wimg, Wimg_t, Whid, Whid_t);

    // eproj = bf16(embed @ W_x + b_cell), xmap gate-interleaved (single launch)
    gemm_bt_k<short, false, true><<<dim3(FOURH / 128, VOC / 64, 1), dim3(256), 0, stream>>>(
        embed_c, Wx_t, bcell, eproj, EMBD, EMBD / 64, FOURH);

    // images_encoded: split-K=4 in one launch (grid 8x8x4 = 256 blocks)
    gemm_bt_k<float, true, false><<<dim3(OUTN / 128, BB / 64, 4), dim3(256), 0, stream>>>(
        imgs_c, Wimg_t, nullptr, out0, DIMG, 8, OUTN);

    // all 128 LSTM steps: one persistent kernel (t=127 writes h_a)
    void* kargs[6] = {(void*)&Wh_t, (void*)&eproj, (void*)&msg,
                      (void*)&h_a, (void*)&h_b, (void*)&bar};
    hipError_t ce = hipLaunchCooperativeKernel((const void*)lstm_all_k,
                                               dim3(FOURH / 128, BB / 64, 1), dim3(256, 1, 1),
                                               kargs, 163840, stream);
    if (ce != hipSuccess) {
        for (int t = 0; t < TT; t++) {
            const short* hp = (t & 1) ? h_b : h_a;
            short* hn       = (t & 1) ? h_a : h_b;
            lstm_step_k<<<dim3(FOURH / 128, BB / 64), dim3(256), 98304, stream>>>(
                hp, Wh_t, eproj, msg, t, cbuf, hn);
        }
    }

    // hidden_encoded: split-K=4 in one launch
    gemm_bt_k<float, true, false><<<dim3(OUTN / 128, BB / 64, 4), dim3(256), 0, stream>>>(
        h_a, Whid_t, nullptr, out1, HID, 4, OUTN);
}

// Round 10
// 1542.265 us; speedup vs baseline: 3.5247x; 1.1156x over previous
//
#include <hip/hip_runtime.h>
#include <hip/hip_bf16.h>

// Problem constants (from reference)
#define BB    512
#define TT    128
#define HID   1024
#define EMBD  512
#define VOC   1024
#define OUTN  1024
#define DIMG  2048
#define FOURH 4096

typedef __attribute__((ext_vector_type(8))) short  short8;   // 8 bf16 (MFMA A/B frag)
typedef __attribute__((ext_vector_type(4))) float  f32x4;    // MFMA C/D frag
typedef unsigned int u32;
typedef unsigned long long u64;
typedef __attribute__((ext_vector_type(2))) unsigned long long u64x2;  // 16B chunk

// Wh_t interleave (gate in bits 4-5 of n): n = G*64 + gate*16 + u  -> orig gate*1024 + G*16 + u
__device__ __forceinline__ int hmap(int n) {
    return ((n >> 4) & 3) * HID + ((n >> 6) << 4) + (n & 15);
}
// eproj interleave (gate in bits 0-1 of n): n = G*64 + u*4 + gate -> orig gate*1024 + G*16 + u
__device__ __forceinline__ int xmap(int n) {
    return (n & 3) * HID + ((n >> 6) << 4) + ((n >> 2) & 15);
}
// Fast transcendentals: v_exp_f32 + v_rcp_f32 (~1e-5 rel err, far below the
// bf16 quantization already present in h; saturation at +-inf is exact).
__device__ __forceinline__ float sigmoidf_(float x) {
    return __builtin_amdgcn_rcpf(1.0f + __expf(-x));
}
__device__ __forceinline__ float tanhf_(float x) {
    return 1.0f - 2.0f * __builtin_amdgcn_rcpf(1.0f + __expf(2.0f * x));
}
__device__ __forceinline__ short f2bf(float x) { __hip_bfloat16 b = __float2bfloat16(x); return *(short*)&b; }
__device__ __forceinline__ float bf2f(short s) { __hip_bfloat16 b; *(short*)&b = s; return __bfloat162float(b); }

// async global->LDS, 16B per lane; lds base wave-uniform (HW adds lane*16)
__device__ __forceinline__ void async_cp16(void* lds, const void* g) {
    __builtin_amdgcn_global_load_lds((const __attribute__((address_space(1))) u32*)g,
                                     (__attribute__((address_space(3))) u32*)lds, 16, 0, 0);
}

// raw workgroup barrier with compiler memory fences (no vmcnt/lgkmcnt drain)
__device__ __forceinline__ void block_bar() {
    asm volatile("" ::: "memory");
    __builtin_amdgcn_s_barrier();
    asm volatile("" ::: "memory");
}

// coherent 16B load/store: sc0 sc1 = bypass L1 and L2, read/write coherence point.
// NOTE: compiler does NOT track these as async loads — every consumer is guarded
// by a manual s_waitcnt vmcnt(N) + sched_barrier(0) (ledger in lstm_all_k).
__device__ __forceinline__ u64x2 coh_ld128(const short* p) {
    u64x2 r;
    asm volatile("global_load_dwordx4 %0, %1, off sc0 sc1" : "=v"(r) : "v"(p) : "memory");
    return r;
}
__device__ __forceinline__ void coh_st128(short* p, u64x2 v) {
    asm volatile("global_store_dwordx4 %0, %1, off sc0 sc1" :: "v"(p), "v"(v) : "memory");
}

// Per-group generation barrier (32 blocks sharing blockIdx.y = one independent
// recurrence chain). Store-arrive (NO atomic RMW): block stores its generation
// into slots[x]; wave 0's 64 lanes poll the 32 slots (coalesced coherent load +
// __all vote). Groups never wait on each other. Monotonic generations -> no
// reset, self-healing against stray replay memsets (R8 evidence). Guard 2^14:
// a wedged barrier exits in ms with a visible numeric failure, not a dead
// container (R7 lesson). Proven at 1720 us (R8).
__device__ __forceinline__ void group_bar(u32* slots, u32 want, int x) {
    asm volatile("s_waitcnt vmcnt(0)" ::: "memory");   // own h stores at coherence point
    block_bar();                                       // whole block drained
    if (threadIdx.x < 64) {
        if (threadIdx.x == 0)
            __hip_atomic_store(slots + x, want, __ATOMIC_RELAXED, __HIP_MEMORY_SCOPE_AGENT);
        const int sl = threadIdx.x & 31;
        u32 guard = 0;
        for (;;) {
            u32 v = __hip_atomic_load(slots + sl, __ATOMIC_RELAXED, __HIP_MEMORY_SCOPE_AGENT);
            if (__all((int)(v >= want))) break;
            __builtin_amdgcn_s_sleep(1);
            if (++guard > (1u << 14)) break;           // safety valve
        }
    }
    block_bar();
}

// ---------------------------------------------------------------------------
// Merged prep (one launch): blocks [0,3584) elementwise setup; blocks
// [3584, 3584+9216) the four tiled weight transposes out[n][k] = bf16(in[k][map(n)]).
__global__ void prep_k(const float* __restrict__ images, short* __restrict__ imgs_c,
                       const float* __restrict__ embed,  short* __restrict__ embed_c,
                       float* __restrict__ c, short* __restrict__ h0,
                       float* __restrict__ o0, float* __restrict__ o1,
                       const float* __restrict__ bimg, const float* __restrict__ bhid,
                       const float* __restrict__ Wc_h, short* __restrict__ Wh_t,
                       const float* __restrict__ Wc_x, short* __restrict__ Wx_t,
                       const float* __restrict__ Wimg, short* __restrict__ Wimg_t,
                       const float* __restrict__ Whid, short* __restrict__ Whid_t) {
    if (blockIdx.x < 3584) {
        int i = blockIdx.x * 256 + threadIdx.x;
        if (i < 262144) {                       // images: 512*2048/4
            float4 v = ((const float4*)images)[i];
            short4 o; o.x = f2bf(v.x); o.y = f2bf(v.y); o.z = f2bf(v.z); o.w = f2bf(v.w);
            ((short4*)imgs_c)[i] = o;
        } else if (i < 393216) {                // embed: 1024*512/4
            int k = i - 262144;
            float4 v = ((const float4*)embed)[k];
            short4 o; o.x = f2bf(v.x); o.y = f2bf(v.y); o.z = f2bf(v.z); o.w = f2bf(v.w);
            ((short4*)embed_c)[k] = o;
        } else {                                // state/out init: 512*1024
            int k = i - 393216;
            int n = k & (OUTN - 1);
            c[k] = 0.0f; h0[k] = 0;
            o0[k] = bimg[n]; o1[k] = bhid[n];
        }
        return;
    }
    int id = blockIdx.x - 3584;
    const float* in; short* out; int K, N_in, bx, by, mapmode;
    if (id < 4096)      { in = Wc_h; out = Wh_t;   K = 1024; N_in = 4096; mapmode = 1; bx = id & 127;  by = id >> 7; }
    else if (id < 6144) { id -= 4096;              in = Wc_x; out = Wx_t; K = 512;  N_in = 4096; mapmode = 2; bx = id & 127;  by = id >> 7; }
    else if (id < 8192) { id -= 6144; in = Wimg; out = Wimg_t; K = 2048; N_in = 1024; mapmode = 0; bx = id & 31; by = id >> 5; }
    else                { id -= 8192; in = Whid; out = Whid_t; K = 1024; N_in = 1024; mapmode = 0; bx = id & 31; by = id >> 5; }

    __shared__ short tile[32][33];
    int n0 = bx * 32, k0 = by * 32;
    int tx = threadIdx.x & 31, ty = threadIdx.x >> 5;   // 32 x 8
    int nn = n0 + tx;
    int nsrc = (mapmode == 1) ? hmap(nn) : (mapmode == 2) ? xmap(nn) : nn;
#pragma unroll
    for (int j = 0; j < 4; j++) {
        int kw = ty + j * 8;
        tile[kw][tx] = f2bf(in[(size_t)(k0 + kw) * N_in + nsrc]);
    }
    __syncthreads();
#pragma unroll
    for (int j = 0; j < 4; j++) {
        int nw = ty + j * 8;
        out[(size_t)(n0 + nw) * K + k0 + tx] = tile[tx][nw];
    }
}

// ---------------------------------------------------------------------------
// Double-buffered MFMA core, tile 64x128, BK=64, 4 waves 2x2 (one-shot GEMMs).
template<typename OutT, bool ATOMIC, bool MAPB>
__global__ __launch_bounds__(256) void gemm_bt_k(
    const short* __restrict__ A, const short* __restrict__ Bt,
    const float* __restrict__ bias, OutT* __restrict__ out,
    int Kf, int niter, int N)
{
    __shared__ __align__(16) short As[2][2][64 * 32];
    __shared__ __align__(16) short Bs[2][2][128 * 32];
    const int tid  = threadIdx.x;
    const int lane = tid & 63, wid = tid >> 6;
    const int wm = wid >> 1, wn = wid & 1;
    const int col16 = lane & 15, quad = lane >> 4;
    const int m0 = blockIdx.y * 64;
    const int n0 = blockIdx.x * 128;
    const int kbeg = blockIdx.z * niter * 64;

    const short* agp = A  + (size_t)(m0 + wid * 16 + (lane >> 2)) * Kf + kbeg + (lane & 3) * 8;
    const short* bgp = Bt + (size_t)(n0 + wid * 32 + (lane >> 2)) * Kf + kbeg + (lane & 3) * 8;

    f32x4 acc[2][4];
#pragma unroll
    for (int i = 0; i < 2; i++)
#pragma unroll
        for (int jj = 0; jj < 4; jj++) acc[i][jj] = (f32x4)0.0f;

    async_cp16(&As[0][0][wid * 512], agp);
    async_cp16(&As[0][1][wid * 512], agp + 32);
    async_cp16(&Bs[0][0][wid * 1024],       bgp);
    async_cp16(&Bs[0][0][wid * 1024 + 512], bgp + (size_t)16 * Kf);
    async_cp16(&Bs[0][1][wid * 1024],       bgp + 32);
    async_cp16(&Bs[0][1][wid * 1024 + 512], bgp + (size_t)16 * Kf + 32);
    __syncthreads();

    int buf = 0;
#pragma unroll 1
    for (int it = 0; it < niter; ++it) {
        if (it + 1 < niter) {
            int k0 = (it + 1) * 64;
            async_cp16(&As[buf ^ 1][0][wid * 512], agp + k0);
            async_cp16(&As[buf ^ 1][1][wid * 512], agp + k0 + 32);
            async_cp16(&Bs[buf ^ 1][0][wid * 1024],       bgp + k0);
            async_cp16(&Bs[buf ^ 1][0][wid * 1024 + 512], bgp + (size_t)16 * Kf + k0);
            async_cp16(&Bs[buf ^ 1][1][wid * 1024],       bgp + k0 + 32);
            async_cp16(&Bs[buf ^ 1][1][wid * 1024 + 512], bgp + (size_t)16 * Kf + k0 + 32);
        }
        short8 af[2][2], bf[4][2];
#pragma unroll
        for (int tr = 0; tr < 2; tr++)
#pragma unroll
            for (int p = 0; p < 2; p++)
                af[tr][p] = *(const short8*)&As[buf][p][(wm * 32 + tr * 16 + col16) * 32 + quad * 8];
#pragma unroll
        for (int tc = 0; tc < 4; tc++)
#pragma unroll
            for (int p = 0; p < 2; p++)
                bf[tc][p] = *(const short8*)&Bs[buf][p][(wn * 64 + tc * 16 + col16) * 32 + quad * 8];
#pragma unroll
        for (int p = 0; p < 2; p++)
#pragma unroll
            for (int tr = 0; tr < 2; tr++)
#pragma unroll
                for (int tc = 0; tc < 4; tc++)
                    acc[tr][tc] = __builtin_amdgcn_mfma_f32_16x16x32_bf16(af[tr][p], bf[tc][p], acc[tr][tc], 0, 0, 0);
        __syncthreads();
        buf ^= 1;
    }

#pragma unroll
    for (int tr = 0; tr < 2; tr++)
#pragma unroll
        for (int tc = 0; tc < 4; tc++) {
            int colg = n0 + wn * 64 + tc * 16 + col16;
            float bv = 0.0f;
            if constexpr (!ATOMIC) bv = bias[MAPB ? xmap(colg) : colg];
#pragma unroll
            for (int r = 0; r < 4; r++) {
                int rowg = m0 + wm * 32 + tr * 16 + quad * 4 + r;
                float v = acc[tr][tc][r] + bv;
                if constexpr (ATOMIC) atomicAdd((float*)&out[(size_t)rowg * N + colg], v);
                else                  out[(size_t)rowg * N + colg] = f2bf(v);
            }
        }
}

// ---------------------------------------------------------------------------
// Persistent LSTM — R8 structure (proven 1720 us) with two safe micro-opts:
//  * fast sigmoid/tanh via v_exp_f32 + v_rcp_f32 (libm expf/tanhf were ~5
//    transcendental calls x 16 outputs/thread/step of the VALUBusy budget)
//  * gather bf16->f32 conversion moved AFTER group_bar, under the prologue
//    A-load shadow (was delaying every block's barrier arrival)
// Everything else (group barrier, coalesced h exchange, staging ledger, Bp
// persistence, c-in-regs, gather pipeline, LDS repack) byte-identical to R8.
__global__ __launch_bounds__(256, 1) void lstm_all_k(
    const short* __restrict__ Wh_t, const short* __restrict__ eproj,
    const int* __restrict__ msg,
    short* __restrict__ h_a, short* __restrict__ h_b,
    u32* __restrict__ bar)
{
    constexpr int Kf = HID;
    extern __shared__ __align__(16) short smem[];
    short* As = smem;            // [2][8192]; As[0..2048) doubles as h repack buf
    short* Bs = smem + 16384;    // [2][16384]
    short* Bp = smem + 49152;    // [2][16384] persistent B tiles 0,1

    const int tid  = threadIdx.x;
    const int lane = tid & 63, wid = tid >> 6;
    const int wm = wid >> 1, wn = wid & 1;
    const int col16 = lane & 15, quad = lane >> 4;
    const int m0 = blockIdx.y * 64;
    const int n0 = blockIdx.x * 128;
    u32* slots = bar + blockIdx.y * 64;   // group slot array (32 u32, own 256B region)

    const int swz_st = (((lane & 3) - ((lane >> 3) & 3)) & 3) * 8;
    const size_t aoff = (size_t)(m0 + wid * 16 + (lane >> 2)) * Kf + swz_st;
    const short* agpA = h_a + aoff;
    const short* agpB = h_b + aoff;
    const short* bgp0 = Wh_t + (size_t)(n0 + wid * 32 + (lane >> 2)) * Kf + swz_st;
    const short* bgp1 = bgp0 + (size_t)16 * Kf;

    const int G = (n0 + wn * 64) >> 6;
    const int j = G * 16 + col16;
    const short* egbase = eproj + G * 64 + col16 * 4;   // + v*FOURH -> short4 of 4 gates

    int moff[2][4];
#pragma unroll
    for (int tr = 0; tr < 2; tr++)
#pragma unroll
        for (int r = 0; r < 4; r++)
            moff[tr][r] = (m0 + wm * 32 + tr * 16 + quad * 4 + r) * TT;

    const int swz_rd = ((quad + (col16 >> 1)) & 3) * 8;
    const int arow = (wm * 32 + col16) * 32 + swz_rd;   // + tr*512
    const int brow = (wn * 64 + col16) * 32 + swz_rd;   // + tc*512
    const int adst = wid * 512 + lane * 8;              // LDS A stripe (shorts)

    // h repack geometry: block owns rows m0..m0+63, cols cbase..cbase+31
    const int cbase   = blockIdx.x * 32;
    const int reprow  = tid >> 2;            // 0..63
    const int repchk  = tid & 3;             // 0..3 (16B chunk)
    const int repdst  = (wm * 32 + quad * 4) * 32 + wn * 16 + col16;  // + (tr*16+r)*32

    float creg[2][4];
#pragma unroll
    for (int tr = 0; tr < 2; tr++)
#pragma unroll
        for (int r = 0; r < 4; r++) creg[tr][r] = 0.0f;

    // persistent B tiles 0,1 -> Bp (drained by the first group_bar)
#pragma unroll
    for (int p = 0; p < 4; p++) {
        async_cp16(&Bp[p * 4096 + wid * 1024],       bgp0 + p * 32);
        async_cp16(&Bp[p * 4096 + wid * 1024 + 512], bgp1 + p * 32);
        async_cp16(&Bp[16384 + p * 4096 + wid * 1024],       bgp0 + 128 + p * 32);
        async_cp16(&Bp[16384 + p * 4096 + wid * 1024 + 512], bgp1 + 128 + p * 32);
    }

    // cold gather prefetch for t=0
    int vbuf[2][4];
    short4 s4buf[2][4];
#pragma unroll
    for (int tr = 0; tr < 2; tr++)
#pragma unroll
        for (int r = 0; r < 4; r++)
            vbuf[tr][r] = msg[moff[tr][r]];
#pragma unroll
    for (int tr = 0; tr < 2; tr++)
#pragma unroll
        for (int r = 0; r < 4; r++)
            s4buf[tr][r] = *(const short4*)(egbase + (size_t)vbuf[tr][r] * FOURH);

#pragma unroll 1
    for (int t = 0; t < TT; ++t) {
        const short* agp = (t & 1) ? agpB : agpA;
        short* hw        = (t & 1) ? h_a : h_b;

        group_bar(slots, (u32)(t + 1), blockIdx.x);   // group's h_{t-1} at coherence point

        // ---- prologue: coherent 16B A loads t0,t1 -> regs (issue FIRST) ...
        u64x2 areg[2][4];
#pragma unroll
        for (int p = 0; p < 4; p++) areg[0][p] = coh_ld128(agp + p * 32);
#pragma unroll
        for (int p = 0; p < 4; p++) areg[1][p] = coh_ld128(agp + 128 + p * 32);

        // ... then convert the prefetched gather UNDER the load shadow
        float gi[2][4][4];
#pragma unroll
        for (int tr = 0; tr < 2; tr++)
#pragma unroll
            for (int r = 0; r < 4; r++) {
                short4 s4 = s4buf[tr][r];
                gi[tr][0][r] = bf2f(s4.x);
                gi[tr][1][r] = bf2f(s4.y);
                gi[tr][2][r] = bf2f(s4.z);
                gi[tr][3][r] = bf2f(s4.w);
            }

        asm volatile("s_waitcnt vmcnt(4)" ::: "memory");    // A0 landed (A1 in flight)
        __builtin_amdgcn_sched_barrier(0);
#pragma unroll
        for (int p = 0; p < 4; p++)
            *(u64x2*)&As[p * 2048 + adst] = areg[0][p];
        asm volatile("s_waitcnt lgkmcnt(0)" ::: "memory");
        block_bar();

        f32x4 acc[2][4];
#pragma unroll
        for (int i = 0; i < 2; i++)
#pragma unroll
            for (int jj = 0; jj < 4; jj++) acc[i][jj] = (f32x4)0.0f;

#pragma unroll
        for (int it = 0; it < 8; ++it) {
            const int buf = it & 1;
            const short* Ab = &As[buf * 8192];
            const short* Bb = (it < 2) ? &Bp[it * 16384] : &Bs[buf * 16384];
            __builtin_amdgcn_s_setprio(1);
#pragma unroll
            for (int p = 0; p < 4; p++) {
                short8 af0 = *(const short8*)&Ab[p * 2048 + arow];
                short8 af1 = *(const short8*)&Ab[p * 2048 + arow + 512];
                short8 bf0 = *(const short8*)&Bb[p * 4096 + brow];
                short8 bf1 = *(const short8*)&Bb[p * 4096 + brow + 512];
                short8 bf2 = *(const short8*)&Bb[p * 4096 + brow + 1024];
                short8 bf3 = *(const short8*)&Bb[p * 4096 + brow + 1536];
                acc[0][0] = __builtin_amdgcn_mfma_f32_16x16x32_bf16(af0, bf0, acc[0][0], 0, 0, 0);
                acc[0][1] = __builtin_amdgcn_mfma_f32_16x16x32_bf16(af0, bf1, acc[0][1], 0, 0, 0);
                acc[0][2] = __builtin_amdgcn_mfma_f32_16x16x32_bf16(af0, bf2, acc[0][2], 0, 0, 0);
                acc[0][3] = __builtin_amdgcn_mfma_f32_16x16x32_bf16(af0, bf3, acc[0][3], 0, 0, 0);
                acc[1][0] = __builtin_amdgcn_mfma_f32_16x16x32_bf16(af1, bf0, acc[1][0], 0, 0, 0);
                acc[1][1] = __builtin_amdgcn_mfma_f32_16x16x32_bf16(af1, bf1, acc[1][1], 0, 0, 0);
                acc[1][2] = __builtin_amdgcn_mfma_f32_16x16x32_bf16(af1, bf2, acc[1][2], 0, 0, 0);
                acc[1][3] = __builtin_amdgcn_mfma_f32_16x16x32_bf16(af1, bf3, acc[1][3], 0, 0, 0);
            }
            __builtin_amdgcn_s_setprio(0);

            block_bar();   // all waves done reading As[buf]/Bb

            if (it < 6) {
                const int k0 = (it + 2) * 128;
                // coherent A(it+2) -> areg[buf] (slot just freed): 4 x 16B
#pragma unroll
                for (int p = 0; p < 4; p++)
                    areg[buf][p] = coh_ld128(agp + k0 + p * 32);
                // B(it+2) -> Bs[buf] (cached, L2-hot): 8 x cp16
#pragma unroll
                for (int p = 0; p < 4; p++) {
                    async_cp16(&Bs[buf * 16384 + p * 4096 + wid * 1024],       bgp0 + k0 + p * 32);
                    async_cp16(&Bs[buf * 16384 + p * 4096 + wid * 1024 + 512], bgp1 + k0 + p * 32);
                }
                // newest 12 = A(it+2)+B(it+2); A/B(it+1) (the older 12) landed
                asm volatile("s_waitcnt vmcnt(12)" ::: "memory");
                __builtin_amdgcn_sched_barrier(0);
#pragma unroll
                for (int p = 0; p < 4; p++)
                    *(u64x2*)&As[(buf ^ 1) * 8192 + p * 2048 + adst] = areg[buf ^ 1][p];
                asm volatile("s_waitcnt lgkmcnt(0)" ::: "memory");
                block_bar();
            } else if (it == 6) {
                asm volatile("s_waitcnt vmcnt(0)" ::: "memory");   // A7/B7 landed
                __builtin_amdgcn_sched_barrier(0);
#pragma unroll
                for (int p = 0; p < 4; p++)
                    *(u64x2*)&As[8192 + p * 2048 + adst] = areg[1][p];
                asm volatile("s_waitcnt lgkmcnt(0)" ::: "memory");
                block_bar();
                // gather pipeline stage 1: msg indices for t+1 (fly over it==7)
                if (t + 1 < TT) {
#pragma unroll
                    for (int tr = 0; tr < 2; tr++)
#pragma unroll
                        for (int r = 0; r < 4; r++)
                            vbuf[tr][r] = msg[moff[tr][r] + t + 1];
                }
            }
        }

        // gather pipeline stage 2: eproj rows for t+1 (covered by cell VALU)
        if (t + 1 < TT) {
#pragma unroll
            for (int tr = 0; tr < 2; tr++)
#pragma unroll
                for (int r = 0; r < 4; r++)
                    s4buf[tr][r] = *(const short4*)(egbase + (size_t)vbuf[tr][r] * FOURH);
        }

        // fused cell update; c in regs; h repacked into LDS (As[0..2048), dead now)
#pragma unroll
        for (int tr = 0; tr < 2; tr++)
#pragma unroll
            for (int r = 0; r < 4; r++) {
                float i_ = acc[tr][0][r] + gi[tr][0][r];
                float g_ = acc[tr][1][r] + gi[tr][1][r];
                float f_ = acc[tr][2][r] + gi[tr][2][r];
                float o_ = acc[tr][3][r] + gi[tr][3][r];
                float cn = sigmoidf_(f_ + 1.0f) * creg[tr][r] + sigmoidf_(i_) * tanhf_(g_);
                creg[tr][r] = cn;
                As[repdst + (tr * 16 + r) * 32] = f2bf(sigmoidf_(o_) * tanhf_(cn));
            }
        block_bar();                         // repack complete
        {
            u64x2 v = *(const u64x2*)&As[reprow * 32 + repchk * 8];
            coh_st128(hw + (size_t)(m0 + reprow) * HID + cbase + repchk * 8, v);
        }
        // store drained by next group_bar's vmcnt(0); its block_bar also orders
        // the LDS repack read vs next step's prologue As writes.
    }
}

// ---------------------------------------------------------------------------
// Fallback per-step kernel (proven; used only if cooperative launch fails).
__global__ __launch_bounds__(256) void lstm_step_k(
    const short* __restrict__ h_prev, const short* __restrict__ Wh_t,
    const short* __restrict__ eproj, const int* __restrict__ msg, int t,
    float* __restrict__ c, short* __restrict__ h_next)
{
    constexpr int Kf = HID;
    extern __shared__ __align__(16) short smem[];
    short* As = smem;           // [2][4][2048] shorts
    short* Bs = smem + 16384;   // [2][4][4096] shorts

    const int tid  = threadIdx.x;
    const int lane = tid & 63, wid = tid >> 6;
    const int wm = wid >> 1, wn = wid & 1;
    const int col16 = lane & 15, quad = lane >> 4;
    const int m0 = blockIdx.y * 64;
    const int n0 = blockIdx.x * 128;

    const int swz_st = (((lane & 3) - ((lane >> 3) & 3)) & 3) * 8;
    const short* agp  = h_prev + (size_t)(m0 + wid * 16 + (lane >> 2)) * Kf + swz_st;
    const short* bgp0 = Wh_t   + (size_t)(n0 + wid * 32 + (lane >> 2)) * Kf + swz_st;
    const short* bgp1 = bgp0 + (size_t)16 * Kf;

    const int G = (n0 + wn * 64) >> 6;
    const int j = G * 16 + col16;
    float gi[2][4][4], cold[2][4];
#pragma unroll
    for (int tr = 0; tr < 2; tr++)
#pragma unroll
        for (int r = 0; r < 4; r++) {
            int b = m0 + wm * 32 + tr * 16 + quad * 4 + r;
            int v = msg[b * TT + t];
            short4 s4 = *(const short4*)(eproj + (size_t)v * FOURH + G * 64 + col16 * 4);
            gi[tr][0][r] = bf2f(s4.x);
            gi[tr][1][r] = bf2f(s4.y);
            gi[tr][2][r] = bf2f(s4.z);
            gi[tr][3][r] = bf2f(s4.w);
            cold[tr][r] = c[(size_t)b * HID + j];
        }

#pragma unroll
    for (int p = 0; p < 4; p++) {
        async_cp16(&As[p * 2048 + wid * 512], agp + p * 32);
        async_cp16(&Bs[p * 4096 + wid * 1024],       bgp0 + p * 32);
        async_cp16(&Bs[p * 4096 + wid * 1024 + 512], bgp1 + p * 32);
    }
#pragma unroll
    for (int p = 0; p < 4; p++) {
        async_cp16(&As[8192 + p * 2048 + wid * 512], agp + 128 + p * 32);
        async_cp16(&Bs[16384 + p * 4096 + wid * 1024],       bgp0 + 128 + p * 32);
        async_cp16(&Bs[16384 + p * 4096 + wid * 1024 + 512], bgp1 + 128 + p * 32);
    }

    f32x4 acc[2][4];
#pragma unroll
    for (int i = 0; i < 2; i++)
#pragma unroll
        for (int jj = 0; jj < 4; jj++) acc[i][jj] = (f32x4)0.0f;

    const int swz_rd = ((quad + (col16 >> 1)) & 3) * 8;
    const int arow = (wm * 32 + col16) * 32 + swz_rd;
    const int brow = (wn * 64 + col16) * 32 + swz_rd;

    asm volatile("s_waitcnt vmcnt(12)" ::: "memory");
    block_bar();

    int buf = 0;
#pragma unroll 1
    for (int it = 0; it < 8; ++it) {
        const short* Ab = &As[buf * 8192];
        const short* Bb = &Bs[buf * 16384];
        __builtin_amdgcn_s_setprio(1);
#pragma unroll
        for (int p = 0; p < 4; p++) {
            short8 af0 = *(const short8*)&Ab[p * 2048 + arow];
            short8 af1 = *(const short8*)&Ab[p * 2048 + arow + 512];
            short8 bf0 = *(const short8*)&Bb[p * 4096 + brow];
            short8 bf1 = *(const short8*)&Bb[p * 4096 + brow + 512];
            short8 bf2 = *(const short8*)&Bb[p * 4096 + brow + 1024];
            short8 bf3 = *(const short8*)&Bb[p * 4096 + brow + 1536];
            acc[0][0] = __builtin_amdgcn_mfma_f32_16x16x32_bf16(af0, bf0, acc[0][0], 0, 0, 0);
            acc[0][1] = __builtin_amdgcn_mfma_f32_16x16x32_bf16(af0, bf1, acc[0][1], 0, 0, 0);
            acc[0][2] = __builtin_amdgcn_mfma_f32_16x16x32_bf16(af0, bf2, acc[0][2], 0, 0, 0);
            acc[0][3] = __builtin_amdgcn_mfma_f32_16x16x32_bf16(af0, bf3, acc[0][3], 0, 0, 0);
            acc[1][0] = __builtin_amdgcn_mfma_f32_16x16x32_bf16(af1, bf0, acc[1][0], 0, 0, 0);
            acc[1][1] = __builtin_amdgcn_mfma_f32_16x16x32_bf16(af1, bf1, acc[1][1], 0, 0, 0);
            acc[1][2] = __builtin_amdgcn_mfma_f32_16x16x32_bf16(af1, bf2, acc[1][2], 0, 0, 0);
            acc[1][3] = __builtin_amdgcn_mfma_f32_16x16x32_bf16(af1, bf3, acc[1][3], 0, 0, 0);
        }
        __builtin_amdgcn_s_setprio(0);
        block_bar();
        if (it < 6) {
            const int k0 = (it + 2) * 128;
#pragma unroll
            for (int p = 0; p < 4; p++) {
                async_cp16(&As[buf * 8192 + p * 2048 + wid * 512], agp + k0 + p * 32);
                async_cp16(&Bs[buf * 16384 + p * 4096 + wid * 1024],       bgp0 + k0 + p * 32);
                async_cp16(&Bs[buf * 16384 + p * 4096 + wid * 1024 + 512], bgp1 + k0 + p * 32);
            }
            asm volatile("s_waitcnt vmcnt(12)" ::: "memory");
        } else if (it == 6) {
            asm volatile("s_waitcnt vmcnt(0)" ::: "memory");
        }
        if (it < 7) block_bar();
        buf ^= 1;
    }

#pragma unroll
    for (int tr = 0; tr < 2; tr++)
#pragma unroll
        for (int r = 0; r < 4; r++) {
            int b = m0 + wm * 32 + tr * 16 + quad * 4 + r;
            float i_ = acc[tr][0][r] + gi[tr][0][r];
            float g_ = acc[tr][1][r] + gi[tr][1][r];
            float f_ = acc[tr][2][r] + gi[tr][2][r];
            float o_ = acc[tr][3][r] + gi[tr][3][r];
            size_t idx = (size_t)b * HID + j;
            float cn = sigmoidf_(f_ + 1.0f) * cold[tr][r] + sigmoidf_(i_) * tanhf_(g_);
            c[idx] = cn;
            h_next[idx] = f2bf(sigmoidf_(o_) * tanhf_(cn));
        }
}

// ---------------------------------------------------------------------------
extern "C" void kernel_launch(void* const* d_in, const int* in_sizes, int n_in,
                              void* d_out, int out_size, void* d_ws, size_t ws_size,
                              hipStream_t stream) {
    const float* images = (const float*)d_in[0];
    const float* embed  = (const float*)d_in[1];
    const float* Wcell  = (const float*)d_in[2];
    const float* bcell  = (const float*)d_in[3];
    const float* Wimg   = (const float*)d_in[4];
    const float* bimg   = (const float*)d_in[5];
    const float* Whid   = (const float*)d_in[6];
    const float* bhid   = (const float*)d_in[7];
    const int*   msg    = (const int*)d_in[8];

    float* out0 = (float*)d_out;                   // images_encoded [512,1024] f32
    float* out1 = out0 + (size_t)BB * OUTN;        // hidden_encoded [512,1024] f32

    // Workspace layout (33 MB)
    char* ws = (char*)d_ws;
    const size_t MB = 1024 * 1024;
    short* Wh_t    = (short*)(ws);            //  8 MB [4096][1024] bf16, hmap
    short* Wx_t    = (short*)(ws + 8 * MB);   //  4 MB [4096][512]  bf16, xmap
    short* Wimg_t  = (short*)(ws + 12 * MB);  //  4 MB [1024][2048] bf16
    short* Whid_t  = (short*)(ws + 16 * MB);  //  2 MB [1024][1024] bf16
    short* eproj   = (short*)(ws + 18 * MB);  //  8 MB [1024][4096] bf16, bias folded, xmap layout
    short* h_a     = (short*)(ws + 26 * MB);  //  1 MB
    short* h_b     = (short*)(ws + 27 * MB);  //  1 MB
    float* cbuf    = (float*)(ws + 28 * MB);  //  2 MB (fallback c; barrier slots)
    short* imgs_c  = (short*)(ws + 30 * MB);  //  2 MB [512][2048] bf16
    short* embed_c = (short*)(ws + 32 * MB);  //  1 MB [1024][512] bf16

    u32* bar = (u32*)cbuf;            // zeroed by prep_k every replay (c[k]=0)

    (void)hipFuncSetAttribute((const void*)lstm_all_k,  hipFuncAttributeMaxDynamicSharedMemorySize, 163840);
    (void)hipFuncSetAttribute((const void*)lstm_step_k, hipFuncAttributeMaxDynamicSharedMemorySize, 98304);

    // merged prep: elementwise setup + all four weight transposes (one launch)
    prep_k<<<dim3(3584 + 9216), dim3(256), 0, stream>>>(
        images, imgs_c, embed, embed_c, cbuf, h_a, out0, out1, bimg, bhid,
        Wcell + (size_t)EMBD * FOURH, Wh_t, Wcell, Wx_t, Wimg, Wimg_t, Whid, Whid_t);

    // eproj = bf16(embed @ W_x + b_cell), xmap gate-interleaved (single launch)
    gemm_bt_k<short, false, true><<<dim3(FOURH / 128, VOC / 64, 1), dim3(256), 0, stream>>>(
        embed_c, Wx_t, bcell, eproj, EMBD, EMBD / 64, FOURH);

    // images_encoded: split-K=4 in one launch (grid 8x8x4 = 256 blocks)
    gemm_bt_k<float, true, false><<<dim3(OUTN / 128, BB / 64, 4), dim3(256), 0, stream>>>(
        imgs_c, Wimg_t, nullptr, out0, DIMG, 8, OUTN);

    // all 128 LSTM steps: one persistent kernel (t=127 writes h_a)
    void* kargs[6] = {(void*)&Wh_t, (void*)&eproj, (void*)&msg,
                      (void*)&h_a, (void*)&h_b, (void*)&bar};
    hipError_t ce = hipLaunchCooperativeKernel((const void*)lstm_all_k,
                                               dim3(FOURH / 128, BB / 64, 1), dim3(256, 1, 1),
                                               kargs, 163840, stream);
    if (ce != hipSuccess) {
        for (int t = 0; t < TT; t++) {
            const short* hp = (t & 1) ? h_b : h_a;
            short* hn       = (t & 1) ? h_a : h_b;
            lstm_step_k<<<dim3(FOURH / 128, BB / 64), dim3(256), 98304, stream>>>(
                hp, Wh_t, eproj, msg, t, cbuf, hn);
        }
    }

    // hidden_encoded: split-K=4 in one launch
    gemm_bt_k<float, true, false><<<dim3(OUTN / 128, BB / 64, 4), dim3(256), 0, stream>>>(
        h_a, Whid_t, nullptr, out1, HID, 4, OUTN);
}

// Round 11
// 1479.730 us; speedup vs baseline: 3.6737x; 1.0423x over previous
//
#include <hip/hip_runtime.h>
#include <hip/hip_bf16.h>

// Problem constants (from reference)
#define BB    512
#define TT    128
#define HID   1024
#define EMBD  512
#define VOC   1024
#define OUTN  1024
#define DIMG  2048
#define FOURH 4096

typedef __attribute__((ext_vector_type(8))) short  short8;   // 8 bf16 (MFMA A/B frag)
typedef __attribute__((ext_vector_type(4))) float  f32x4;    // MFMA C/D frag
typedef unsigned int u32;
typedef unsigned long long u64;
typedef __attribute__((ext_vector_type(2))) unsigned long long u64x2;  // 16B chunk

// Wh_t interleave (gate in bits 4-5 of n): n = G*64 + gate*16 + u  -> orig gate*1024 + G*16 + u
__device__ __forceinline__ int hmap(int n) {
    return ((n >> 4) & 3) * HID + ((n >> 6) << 4) + (n & 15);
}
// eproj interleave (gate in bits 0-1 of n): n = G*64 + u*4 + gate -> orig gate*1024 + G*16 + u
__device__ __forceinline__ int xmap(int n) {
    return (n & 3) * HID + ((n >> 6) << 4) + ((n >> 2) & 15);
}
// Fast transcendentals: v_exp_f32 + v_rcp_f32 (~1e-5 rel err, far below the
// bf16 quantization already present in h; saturation at +-inf is exact).
__device__ __forceinline__ float sigmoidf_(float x) {
    return __builtin_amdgcn_rcpf(1.0f + __expf(-x));
}
__device__ __forceinline__ float tanhf_(float x) {
    return 1.0f - 2.0f * __builtin_amdgcn_rcpf(1.0f + __expf(2.0f * x));
}
__device__ __forceinline__ short f2bf(float x) { __hip_bfloat16 b = __float2bfloat16(x); return *(short*)&b; }
__device__ __forceinline__ float bf2f(short s) { __hip_bfloat16 b; *(short*)&b = s; return __bfloat162float(b); }

// async global->LDS, 16B per lane; lds base wave-uniform (HW adds lane*16)
__device__ __forceinline__ void async_cp16(void* lds, const void* g) {
    __builtin_amdgcn_global_load_lds((const __attribute__((address_space(1))) u32*)g,
                                     (__attribute__((address_space(3))) u32*)lds, 16, 0, 0);
}

// raw workgroup barrier with compiler memory fences (no vmcnt/lgkmcnt drain)
__device__ __forceinline__ void block_bar() {
    asm volatile("" ::: "memory");
    __builtin_amdgcn_s_barrier();
    asm volatile("" ::: "memory");
}

// Intra-XCD h exchange (producer and consumer guaranteed same XCD by role
// construction, gy = XCC_ID):
//   load:  sc0 = bypass (possibly stale) L1, read the XCD's shared L2
//   store: plain dwordx4 — CDNA L1 is write-through, so the store lands in the
//          shared L2; vmcnt(0) before the barrier slot store orders it.
// Compiler does NOT track these — every consumer is guarded by a manual
// s_waitcnt vmcnt(N) + sched_barrier(0) (ledger in lstm_all_k, rule #18).
__device__ __forceinline__ u64x2 coh_ld128(const short* p) {
    u64x2 r;
    asm volatile("global_load_dwordx4 %0, %1, off sc0" : "=v"(r) : "v"(p) : "memory");
    return r;
}
__device__ __forceinline__ void coh_st128(short* p, u64x2 v) {
    asm volatile("global_store_dwordx4 %0, %1, off" :: "v"(p), "v"(v) : "memory");
}

// Per-group generation barrier — byte-identical to the R8/R10 proven version
// (agent-scope atomics through the coherence point; works regardless of
// placement). 32 blocks/group, store-arrive + 64-lane all-poll, monotonic
// generations (self-healing, R8 evidence), guard 2^14 (R7 lesson).
__device__ __forceinline__ void group_bar(u32* slots, u32 want, int x) {
    asm volatile("s_waitcnt vmcnt(0)" ::: "memory");   // own h stores in shared L2
    block_bar();                                       // whole block drained
    if (threadIdx.x < 64) {
        if (threadIdx.x == 0)
            __hip_atomic_store(slots + x, want, __ATOMIC_RELAXED, __HIP_MEMORY_SCOPE_AGENT);
        const int sl = threadIdx.x & 31;
        u32 guard = 0;
        for (;;) {
            u32 v = __hip_atomic_load(slots + sl, __ATOMIC_RELAXED, __HIP_MEMORY_SCOPE_AGENT);
            if (__all((int)(v >= want))) break;
            __builtin_amdgcn_s_sleep(1);
            if (++guard > (1u << 14)) break;           // safety valve
        }
    }
    block_bar();
}

// ---------------------------------------------------------------------------
// Merged prep (one launch): blocks [0,3584) elementwise setup; blocks
// [3584, 3584+9216) the four tiled weight transposes out[n][k] = bf16(in[k][map(n)]).
__global__ void prep_k(const float* __restrict__ images, short* __restrict__ imgs_c,
                       const float* __restrict__ embed,  short* __restrict__ embed_c,
                       float* __restrict__ c, short* __restrict__ h0,
                       float* __restrict__ o0, float* __restrict__ o1,
                       const float* __restrict__ bimg, const float* __restrict__ bhid,
                       const float* __restrict__ Wc_h, short* __restrict__ Wh_t,
                       const float* __restrict__ Wc_x, short* __restrict__ Wx_t,
                       const float* __restrict__ Wimg, short* __restrict__ Wimg_t,
                       const float* __restrict__ Whid, short* __restrict__ Whid_t) {
    if (blockIdx.x < 3584) {
        int i = blockIdx.x * 256 + threadIdx.x;
        if (i < 262144) {                       // images: 512*2048/4
            float4 v = ((const float4*)images)[i];
            short4 o; o.x = f2bf(v.x); o.y = f2bf(v.y); o.z = f2bf(v.z); o.w = f2bf(v.w);
            ((short4*)imgs_c)[i] = o;
        } else if (i < 393216) {                // embed: 1024*512/4
            int k = i - 262144;
            float4 v = ((const float4*)embed)[k];
            short4 o; o.x = f2bf(v.x); o.y = f2bf(v.y); o.z = f2bf(v.z); o.w = f2bf(v.w);
            ((short4*)embed_c)[k] = o;
        } else {                                // state/out init: 512*1024
            int k = i - 393216;
            int n = k & (OUTN - 1);
            c[k] = 0.0f; h0[k] = 0;
            o0[k] = bimg[n]; o1[k] = bhid[n];
        }
        return;
    }
    int id = blockIdx.x - 3584;
    const float* in; short* out; int K, N_in, bx, by, mapmode;
    if (id < 4096)      { in = Wc_h; out = Wh_t;   K = 1024; N_in = 4096; mapmode = 1; bx = id & 127;  by = id >> 7; }
    else if (id < 6144) { id -= 4096;              in = Wc_x; out = Wx_t; K = 512;  N_in = 4096; mapmode = 2; bx = id & 127;  by = id >> 7; }
    else if (id < 8192) { id -= 6144; in = Wimg; out = Wimg_t; K = 2048; N_in = 1024; mapmode = 0; bx = id & 31; by = id >> 5; }
    else                { id -= 8192; in = Whid; out = Whid_t; K = 1024; N_in = 1024; mapmode = 0; bx = id & 31; by = id >> 5; }

    __shared__ short tile[32][33];
    int n0 = bx * 32, k0 = by * 32;
    int tx = threadIdx.x & 31, ty = threadIdx.x >> 5;   // 32 x 8
    int nn = n0 + tx;
    int nsrc = (mapmode == 1) ? hmap(nn) : (mapmode == 2) ? xmap(nn) : nn;
#pragma unroll
    for (int j = 0; j < 4; j++) {
        int kw = ty + j * 8;
        tile[kw][tx] = f2bf(in[(size_t)(k0 + kw) * N_in + nsrc]);
    }
    __syncthreads();
#pragma unroll
    for (int j = 0; j < 4; j++) {
        int nw = ty + j * 8;
        out[(size_t)(n0 + nw) * K + k0 + tx] = tile[tx][nw];
    }
}

// ---------------------------------------------------------------------------
// Double-buffered MFMA core, tile 64x128, BK=64, 4 waves 2x2 (one-shot GEMMs).
template<typename OutT, bool ATOMIC, bool MAPB>
__global__ __launch_bounds__(256) void gemm_bt_k(
    const short* __restrict__ A, const short* __restrict__ Bt,
    const float* __restrict__ bias, OutT* __restrict__ out,
    int Kf, int niter, int N)
{
    __shared__ __align__(16) short As[2][2][64 * 32];
    __shared__ __align__(16) short Bs[2][2][128 * 32];
    const int tid  = threadIdx.x;
    const int lane = tid & 63, wid = tid >> 6;
    const int wm = wid >> 1, wn = wid & 1;
    const int col16 = lane & 15, quad = lane >> 4;
    const int m0 = blockIdx.y * 64;
    const int n0 = blockIdx.x * 128;
    const int kbeg = blockIdx.z * niter * 64;

    const short* agp = A  + (size_t)(m0 + wid * 16 + (lane >> 2)) * Kf + kbeg + (lane & 3) * 8;
    const short* bgp = Bt + (size_t)(n0 + wid * 32 + (lane >> 2)) * Kf + kbeg + (lane & 3) * 8;

    f32x4 acc[2][4];
#pragma unroll
    for (int i = 0; i < 2; i++)
#pragma unroll
        for (int jj = 0; jj < 4; jj++) acc[i][jj] = (f32x4)0.0f;

    async_cp16(&As[0][0][wid * 512], agp);
    async_cp16(&As[0][1][wid * 512], agp + 32);
    async_cp16(&Bs[0][0][wid * 1024],       bgp);
    async_cp16(&Bs[0][0][wid * 1024 + 512], bgp + (size_t)16 * Kf);
    async_cp16(&Bs[0][1][wid * 1024],       bgp + 32);
    async_cp16(&Bs[0][1][wid * 1024 + 512], bgp + (size_t)16 * Kf + 32);
    __syncthreads();

    int buf = 0;
#pragma unroll 1
    for (int it = 0; it < niter; ++it) {
        if (it + 1 < niter) {
            int k0 = (it + 1) * 64;
            async_cp16(&As[buf ^ 1][0][wid * 512], agp + k0);
            async_cp16(&As[buf ^ 1][1][wid * 512], agp + k0 + 32);
            async_cp16(&Bs[buf ^ 1][0][wid * 1024],       bgp + k0);
            async_cp16(&Bs[buf ^ 1][0][wid * 1024 + 512], bgp + (size_t)16 * Kf + k0);
            async_cp16(&Bs[buf ^ 1][1][wid * 1024],       bgp + k0 + 32);
            async_cp16(&Bs[buf ^ 1][1][wid * 1024 + 512], bgp + (size_t)16 * Kf + k0 + 32);
        }
        short8 af[2][2], bf[4][2];
#pragma unroll
        for (int tr = 0; tr < 2; tr++)
#pragma unroll
            for (int p = 0; p < 2; p++)
                af[tr][p] = *(const short8*)&As[buf][p][(wm * 32 + tr * 16 + col16) * 32 + quad * 8];
#pragma unroll
        for (int tc = 0; tc < 4; tc++)
#pragma unroll
            for (int p = 0; p < 2; p++)
                bf[tc][p] = *(const short8*)&Bs[buf][p][(wn * 64 + tc * 16 + col16) * 32 + quad * 8];
#pragma unroll
        for (int p = 0; p < 2; p++)
#pragma unroll
            for (int tr = 0; tr < 2; tr++)
#pragma unroll
                for (int tc = 0; tc < 4; tc++)
                    acc[tr][tc] = __builtin_amdgcn_mfma_f32_16x16x32_bf16(af[tr][p], bf[tc][p], acc[tr][tc], 0, 0, 0);
        __syncthreads();
        buf ^= 1;
    }

#pragma unroll
    for (int tr = 0; tr < 2; tr++)
#pragma unroll
        for (int tc = 0; tc < 4; tc++) {
            int colg = n0 + wn * 64 + tc * 16 + col16;
            float bv = 0.0f;
            if constexpr (!ATOMIC) bv = bias[MAPB ? xmap(colg) : colg];
#pragma unroll
            for (int r = 0; r < 4; r++) {
                int rowg = m0 + wm * 32 + tr * 16 + quad * 4 + r;
                float v = acc[tr][tc][r] + bv;
                if constexpr (ATOMIC) atomicAdd((float*)&out[(size_t)rowg * N + colg], v);
                else                  out[(size_t)rowg * N + colg] = f2bf(v);
            }
        }
}

// ---------------------------------------------------------------------------
// Persistent LSTM, XCD-local edition (R9 retry, hazards removed). Change vs
// R10 (isolated): block roles come from HW placement — gy = XCC_ID (via
// __builtin_amdgcn_s_getreg, m09-verified), gx = rank within the XCD (one
// startup atomic, broadcast through DYNAMIC LDS — no static __shared__).
// 160KB LDS forces 1 block/CU; coop launch => 256 blocks on 256 CUs => exactly
// 32 blocks/XCD, so row-group gy's h exchange stays inside one shared L2:
// h stores plain (write-through L1 -> L2), h loads sc0 (bypass stale L1, hit
// L2 ~200cy vs MALL ~700-900cy). group_bar kept byte-identical (agent atomics,
// proven). Failure mode if XCC_ID misbehaves: rank collision -> visible
// verification failure (valve, no OOB: gy&7, gx&31).
__global__ __launch_bounds__(256, 1) void lstm_all_k(
    const short* __restrict__ Wh_t, const short* __restrict__ eproj,
    const int* __restrict__ msg,
    short* __restrict__ h_a, short* __restrict__ h_b,
    u32* __restrict__ bar)
{
    constexpr int Kf = HID;
    extern __shared__ __align__(16) short smem[];
    short* As = smem;            // [2][8192]; As[0..2048) doubles as h repack buf
    short* Bs = smem + 16384;    // [2][16384]
    short* Bp = smem + 49152;    // [2][16384] persistent B tiles 0,1

    const int tid  = threadIdx.x;
    const int lane = tid & 63, wid = tid >> 6;
    const int wm = wid >> 1, wn = wid & 1;
    const int col16 = lane & 15, quad = lane >> 4;

    // ---- dynamic role: gy = physical XCD (wave-uniform SGPR read), gx = rank.
    // hwreg encoding: id=20 (HW_REG_XCC_ID) | offset 0<<6 | (32-1)<<11 = 63508.
    const u32 xcd = __builtin_amdgcn_s_getreg(63508) & 7u;
    if (tid == 0) {
        u32 r = __hip_atomic_fetch_add(bar + 2048 + xcd, 1u,
                                       __ATOMIC_RELAXED, __HIP_MEMORY_SCOPE_AGENT);
        *(volatile u32*)smem = r & 31u;      // broadcast via dynamic LDS
    }
    __syncthreads();
    const int gy = (int)xcd;
    const int gx = (int)*(volatile u32*)smem;
    __syncthreads();                         // everyone read before smem reuse

    const int m0 = gy * 64;
    const int n0 = gx * 128;
    u32* slots = bar + gy * 64;   // group slot array (32 u32, own 256B region)

    const int swz_st = (((lane & 3) - ((lane >> 3) & 3)) & 3) * 8;
    const size_t aoff = (size_t)(m0 + wid * 16 + (lane >> 2)) * Kf + swz_st;
    const short* agpA = h_a + aoff;
    const short* agpB = h_b + aoff;
    const short* bgp0 = Wh_t + (size_t)(n0 + wid * 32 + (lane >> 2)) * Kf + swz_st;
    const short* bgp1 = bgp0 + (size_t)16 * Kf;

    const int G = (n0 + wn * 64) >> 6;
    const int j = G * 16 + col16;
    const short* egbase = eproj + G * 64 + col16 * 4;   // + v*FOURH -> short4 of 4 gates

    int moff[2][4];
#pragma unroll
    for (int tr = 0; tr < 2; tr++)
#pragma unroll
        for (int r = 0; r < 4; r++)
            moff[tr][r] = (m0 + wm * 32 + tr * 16 + quad * 4 + r) * TT;

    const int swz_rd = ((quad + (col16 >> 1)) & 3) * 8;
    const int arow = (wm * 32 + col16) * 32 + swz_rd;   // + tr*512
    const int brow = (wn * 64 + col16) * 32 + swz_rd;   // + tc*512
    const int adst = wid * 512 + lane * 8;              // LDS A stripe (shorts)

    // h repack geometry: block owns rows m0..m0+63, cols cbase..cbase+31
    const int cbase   = gx * 32;
    const int reprow  = tid >> 2;            // 0..63
    const int repchk  = tid & 3;             // 0..3 (16B chunk)
    const int repdst  = (wm * 32 + quad * 4) * 32 + wn * 16 + col16;  // + (tr*16+r)*32

    float creg[2][4];
#pragma unroll
    for (int tr = 0; tr < 2; tr++)
#pragma unroll
        for (int r = 0; r < 4; r++) creg[tr][r] = 0.0f;

    // persistent B tiles 0,1 -> Bp (drained by the first group_bar)
#pragma unroll
    for (int p = 0; p < 4; p++) {
        async_cp16(&Bp[p * 4096 + wid * 1024],       bgp0 + p * 32);
        async_cp16(&Bp[p * 4096 + wid * 1024 + 512], bgp1 + p * 32);
        async_cp16(&Bp[16384 + p * 4096 + wid * 1024],       bgp0 + 128 + p * 32);
        async_cp16(&Bp[16384 + p * 4096 + wid * 1024 + 512], bgp1 + 128 + p * 32);
    }

    // cold gather prefetch for t=0
    int vbuf[2][4];
    short4 s4buf[2][4];
#pragma unroll
    for (int tr = 0; tr < 2; tr++)
#pragma unroll
        for (int r = 0; r < 4; r++)
            vbuf[tr][r] = msg[moff[tr][r]];
#pragma unroll
    for (int tr = 0; tr < 2; tr++)
#pragma unroll
        for (int r = 0; r < 4; r++)
            s4buf[tr][r] = *(const short4*)(egbase + (size_t)vbuf[tr][r] * FOURH);

#pragma unroll 1
    for (int t = 0; t < TT; ++t) {
        const short* agp = (t & 1) ? agpB : agpA;
        short* hw        = (t & 1) ? h_a : h_b;

        group_bar(slots, (u32)(t + 1), gx);   // group's h_{t-1} in shared L2

        // ---- prologue: L2 16B A loads t0,t1 -> regs (issue FIRST) ...
        u64x2 areg[2][4];
#pragma unroll
        for (int p = 0; p < 4; p++) areg[0][p] = coh_ld128(agp + p * 32);
#pragma unroll
        for (int p = 0; p < 4; p++) areg[1][p] = coh_ld128(agp + 128 + p * 32);

        // ... then convert the prefetched gather UNDER the load shadow
        float gi[2][4][4];
#pragma unroll
        for (int tr = 0; tr < 2; tr++)
#pragma unroll
            for (int r = 0; r < 4; r++) {
                short4 s4 = s4buf[tr][r];
                gi[tr][0][r] = bf2f(s4.x);
                gi[tr][1][r] = bf2f(s4.y);
                gi[tr][2][r] = bf2f(s4.z);
                gi[tr][3][r] = bf2f(s4.w);
            }

        asm volatile("s_waitcnt vmcnt(4)" ::: "memory");    // A0 landed (A1 in flight)
        __builtin_amdgcn_sched_barrier(0);
#pragma unroll
        for (int p = 0; p < 4; p++)
            *(u64x2*)&As[p * 2048 + adst] = areg[0][p];
        asm volatile("s_waitcnt lgkmcnt(0)" ::: "memory");
        block_bar();

        f32x4 acc[2][4];
#pragma unroll
        for (int i = 0; i < 2; i++)
#pragma unroll
            for (int jj = 0; jj < 4; jj++) acc[i][jj] = (f32x4)0.0f;

#pragma unroll
        for (int it = 0; it < 8; ++it) {
            const int buf = it & 1;
            const short* Ab = &As[buf * 8192];
            const short* Bb = (it < 2) ? &Bp[it * 16384] : &Bs[buf * 16384];
            __builtin_amdgcn_s_setprio(1);
#pragma unroll
            for (int p = 0; p < 4; p++) {
                short8 af0 = *(const short8*)&Ab[p * 2048 + arow];
                short8 af1 = *(const short8*)&Ab[p * 2048 + arow + 512];
                short8 bf0 = *(const short8*)&Bb[p * 4096 + brow];
                short8 bf1 = *(const short8*)&Bb[p * 4096 + brow + 512];
                short8 bf2 = *(const short8*)&Bb[p * 4096 + brow + 1024];
                short8 bf3 = *(const short8*)&Bb[p * 4096 + brow + 1536];
                acc[0][0] = __builtin_amdgcn_mfma_f32_16x16x32_bf16(af0, bf0, acc[0][0], 0, 0, 0);
                acc[0][1] = __builtin_amdgcn_mfma_f32_16x16x32_bf16(af0, bf1, acc[0][1], 0, 0, 0);
                acc[0][2] = __builtin_amdgcn_mfma_f32_16x16x32_bf16(af0, bf2, acc[0][2], 0, 0, 0);
                acc[0][3] = __builtin_amdgcn_mfma_f32_16x16x32_bf16(af0, bf3, acc[0][3], 0, 0, 0);
                acc[1][0] = __builtin_amdgcn_mfma_f32_16x16x32_bf16(af1, bf0, acc[1][0], 0, 0, 0);
                acc[1][1] = __builtin_amdgcn_mfma_f32_16x16x32_bf16(af1, bf1, acc[1][1], 0, 0, 0);
                acc[1][2] = __builtin_amdgcn_mfma_f32_16x16x32_bf16(af1, bf2, acc[1][2], 0, 0, 0);
                acc[1][3] = __builtin_amdgcn_mfma_f32_16x16x32_bf16(af1, bf3, acc[1][3], 0, 0, 0);
            }
            __builtin_amdgcn_s_setprio(0);

            block_bar();   // all waves done reading As[buf]/Bb

            if (it < 6) {
                const int k0 = (it + 2) * 128;
                // L2 A(it+2) -> areg[buf] (slot just freed): 4 x 16B
#pragma unroll
                for (int p = 0; p < 4; p++)
                    areg[buf][p] = coh_ld128(agp + k0 + p * 32);
                // B(it+2) -> Bs[buf] (cached, L2-hot): 8 x cp16
#pragma unroll
                for (int p = 0; p < 4; p++) {
                    async_cp16(&Bs[buf * 16384 + p * 4096 + wid * 1024],       bgp0 + k0 + p * 32);
                    async_cp16(&Bs[buf * 16384 + p * 4096 + wid * 1024 + 512], bgp1 + k0 + p * 32);
                }
                // newest 12 = A(it+2)+B(it+2); A/B(it+1) (the older 12) landed
                asm volatile("s_waitcnt vmcnt(12)" ::: "memory");
                __builtin_amdgcn_sched_barrier(0);
#pragma unroll
                for (int p = 0; p < 4; p++)
                    *(u64x2*)&As[(buf ^ 1) * 8192 + p * 2048 + adst] = areg[buf ^ 1][p];
                asm volatile("s_waitcnt lgkmcnt(0)" ::: "memory");
                block_bar();
            } else if (it == 6) {
                asm volatile("s_waitcnt vmcnt(0)" ::: "memory");   // A7/B7 landed
                __builtin_amdgcn_sched_barrier(0);
#pragma unroll
                for (int p = 0; p < 4; p++)
                    *(u64x2*)&As[8192 + p * 2048 + adst] = areg[1][p];
                asm volatile("s_waitcnt lgkmcnt(0)" ::: "memory");
                block_bar();
                // gather pipeline stage 1: msg indices for t+1 (fly over it==7)
                if (t + 1 < TT) {
#pragma unroll
                    for (int tr = 0; tr < 2; tr++)
#pragma unroll
                        for (int r = 0; r < 4; r++)
                            vbuf[tr][r] = msg[moff[tr][r] + t + 1];
                }
            }
        }

        // gather pipeline stage 2: eproj rows for t+1 (covered by cell VALU)
        if (t + 1 < TT) {
#pragma unroll
            for (int tr = 0; tr < 2; tr++)
#pragma unroll
                for (int r = 0; r < 4; r++)
                    s4buf[tr][r] = *(const short4*)(egbase + (size_t)vbuf[tr][r] * FOURH);
        }

        // fused cell update; c in regs; h repacked into LDS (As[0..2048), dead now)
#pragma unroll
        for (int tr = 0; tr < 2; tr++)
#pragma unroll
            for (int r = 0; r < 4; r++) {
                float i_ = acc[tr][0][r] + gi[tr][0][r];
                float g_ = acc[tr][1][r] + gi[tr][1][r];
                float f_ = acc[tr][2][r] + gi[tr][2][r];
                float o_ = acc[tr][3][r] + gi[tr][3][r];
                float cn = sigmoidf_(f_ + 1.0f) * creg[tr][r] + sigmoidf_(i_) * tanhf_(g_);
                creg[tr][r] = cn;
                As[repdst + (tr * 16 + r) * 32] = f2bf(sigmoidf_(o_) * tanhf_(cn));
            }
        block_bar();                         // repack complete
        {
            u64x2 v = *(const u64x2*)&As[reprow * 32 + repchk * 8];
            coh_st128(hw + (size_t)(m0 + reprow) * HID + cbase + repchk * 8, v);
        }
        // store drained by next group_bar's vmcnt(0); its block_bar also orders
        // the LDS repack read vs next step's prologue As writes.
    }
}

// ---------------------------------------------------------------------------
// Fallback per-step kernel (proven; used only if cooperative launch fails).
__global__ __launch_bounds__(256) void lstm_step_k(
    const short* __restrict__ h_prev, const short* __restrict__ Wh_t,
    const short* __restrict__ eproj, const int* __restrict__ msg, int t,
    float* __restrict__ c, short* __restrict__ h_next)
{
    constexpr int Kf = HID;
    extern __shared__ __align__(16) short smem[];
    short* As = smem;           // [2][4][2048] shorts
    short* Bs = smem + 16384;   // [2][4][4096] shorts

    const int tid  = threadIdx.x;
    const int lane = tid & 63, wid = tid >> 6;
    const int wm = wid >> 1, wn = wid & 1;
    const int col16 = lane & 15, quad = lane >> 4;
    const int m0 = blockIdx.y * 64;
    const int n0 = blockIdx.x * 128;

    const int swz_st = (((lane & 3) - ((lane >> 3) & 3)) & 3) * 8;
    const short* agp  = h_prev + (size_t)(m0 + wid * 16 + (lane >> 2)) * Kf + swz_st;
    const short* bgp0 = Wh_t   + (size_t)(n0 + wid * 32 + (lane >> 2)) * Kf + swz_st;
    const short* bgp1 = bgp0 + (size_t)16 * Kf;

    const int G = (n0 + wn * 64) >> 6;
    const int j = G * 16 + col16;
    float gi[2][4][4], cold[2][4];
#pragma unroll
    for (int tr = 0; tr < 2; tr++)
#pragma unroll
        for (int r = 0; r < 4; r++) {
            int b = m0 + wm * 32 + tr * 16 + quad * 4 + r;
            int v = msg[b * TT + t];
            short4 s4 = *(const short4*)(eproj + (size_t)v * FOURH + G * 64 + col16 * 4);
            gi[tr][0][r] = bf2f(s4.x);
            gi[tr][1][r] = bf2f(s4.y);
            gi[tr][2][r] = bf2f(s4.z);
            gi[tr][3][r] = bf2f(s4.w);
            cold[tr][r] = c[(size_t)b * HID + j];
        }

#pragma unroll
    for (int p = 0; p < 4; p++) {
        async_cp16(&As[p * 2048 + wid * 512], agp + p * 32);
        async_cp16(&Bs[p * 4096 + wid * 1024],       bgp0 + p * 32);
        async_cp16(&Bs[p * 4096 + wid * 1024 + 512], bgp1 + p * 32);
    }
#pragma unroll
    for (int p = 0; p < 4; p++) {
        async_cp16(&As[8192 + p * 2048 + wid * 512], agp + 128 + p * 32);
        async_cp16(&Bs[16384 + p * 4096 + wid * 1024],       bgp0 + 128 + p * 32);
        async_cp16(&Bs[16384 + p * 4096 + wid * 1024 + 512], bgp1 + 128 + p * 32);
    }

    f32x4 acc[2][4];
#pragma unroll
    for (int i = 0; i < 2; i++)
#pragma unroll
        for (int jj = 0; jj < 4; jj++) acc[i][jj] = (f32x4)0.0f;

    const int swz_rd = ((quad + (col16 >> 1)) & 3) * 8;
    const int arow = (wm * 32 + col16) * 32 + swz_rd;
    const int brow = (wn * 64 + col16) * 32 + swz_rd;

    asm volatile("s_waitcnt vmcnt(12)" ::: "memory");
    block_bar();

    int buf = 0;
#pragma unroll 1
    for (int it = 0; it < 8; ++it) {
        const short* Ab = &As[buf * 8192];
        const short* Bb = &Bs[buf * 16384];
        __builtin_amdgcn_s_setprio(1);
#pragma unroll
        for (int p = 0; p < 4; p++) {
            short8 af0 = *(const short8*)&Ab[p * 2048 + arow];
            short8 af1 = *(const short8*)&Ab[p * 2048 + arow + 512];
            short8 bf0 = *(const short8*)&Bb[p * 4096 + brow];
            short8 bf1 = *(const short8*)&Bb[p * 4096 + brow + 512];
            short8 bf2 = *(const short8*)&Bb[p * 4096 + brow + 1024];
            short8 bf3 = *(const short8*)&Bb[p * 4096 + brow + 1536];
            acc[0][0] = __builtin_amdgcn_mfma_f32_16x16x32_bf16(af0, bf0, acc[0][0], 0, 0, 0);
            acc[0][1] = __builtin_amdgcn_mfma_f32_16x16x32_bf16(af0, bf1, acc[0][1], 0, 0, 0);
            acc[0][2] = __builtin_amdgcn_mfma_f32_16x16x32_bf16(af0, bf2, acc[0][2], 0, 0, 0);
            acc[0][3] = __builtin_amdgcn_mfma_f32_16x16x32_bf16(af0, bf3, acc[0][3], 0, 0, 0);
            acc[1][0] = __builtin_amdgcn_mfma_f32_16x16x32_bf16(af1, bf0, acc[1][0], 0, 0, 0);
            acc[1][1] = __builtin_amdgcn_mfma_f32_16x16x32_bf16(af1, bf1, acc[1][1], 0, 0, 0);
            acc[1][2] = __builtin_amdgcn_mfma_f32_16x16x32_bf16(af1, bf2, acc[1][2], 0, 0, 0);
            acc[1][3] = __builtin_amdgcn_mfma_f32_16x16x32_bf16(af1, bf3, acc[1][3], 0, 0, 0);
        }
        __builtin_amdgcn_s_setprio(0);
        block_bar();
        if (it < 6) {
            const int k0 = (it + 2) * 128;
#pragma unroll
            for (int p = 0; p < 4; p++) {
                async_cp16(&As[buf * 8192 + p * 2048 + wid * 512], agp + k0 + p * 32);
                async_cp16(&Bs[buf * 16384 + p * 4096 + wid * 1024],       bgp0 + k0 + p * 32);
                async_cp16(&Bs[buf * 16384 + p * 4096 + wid * 1024 + 512], bgp1 + k0 + p * 32);
            }
            asm volatile("s_waitcnt vmcnt(12)" ::: "memory");
        } else if (it == 6) {
            asm volatile("s_waitcnt vmcnt(0)" ::: "memory");
        }
        if (it < 7) block_bar();
        buf ^= 1;
    }

#pragma unroll
    for (int tr = 0; tr < 2; tr++)
#pragma unroll
        for (int r = 0; r < 4; r++) {
            int b = m0 + wm * 32 + tr * 16 + quad * 4 + r;
            float i_ = acc[tr][0][r] + gi[tr][0][r];
            float g_ = acc[tr][1][r] + gi[tr][1][r];
            float f_ = acc[tr][2][r] + gi[tr][2][r];
            float o_ = acc[tr][3][r] + gi[tr][3][r];
            size_t idx = (size_t)b * HID + j;
            float cn = sigmoidf_(f_ + 1.0f) * cold[tr][r] + sigmoidf_(i_) * tanhf_(g_);
            c[idx] = cn;
            h_next[idx] = f2bf(sigmoidf_(o_) * tanhf_(cn));
        }
}

// ---------------------------------------------------------------------------
extern "C" void kernel_launch(void* const* d_in, const int* in_sizes, int n_in,
                              void* d_out, int out_size, void* d_ws, size_t ws_size,
                              hipStream_t stream) {
    const float* images = (const float*)d_in[0];
    const float* embed  = (const float*)d_in[1];
    const float* Wcell  = (const float*)d_in[2];
    const float* bcell  = (const float*)d_in[3];
    const float* Wimg   = (const float*)d_in[4];
    const float* bimg   = (const float*)d_in[5];
    const float* Whid   = (const float*)d_in[6];
    const float* bhid   = (const float*)d_in[7];
    const int*   msg    = (const int*)d_in[8];

    float* out0 = (float*)d_out;                   // images_encoded [512,1024] f32
    float* out1 = out0 + (size_t)BB * OUTN;        // hidden_encoded [512,1024] f32

    // Workspace layout (33 MB)
    char* ws = (char*)d_ws;
    const size_t MB = 1024 * 1024;
    short* Wh_t    = (short*)(ws);            //  8 MB [4096][1024] bf16, hmap
    short* Wx_t    = (short*)(ws + 8 * MB);   //  4 MB [4096][512]  bf16, xmap
    short* Wimg_t  = (short*)(ws + 12 * MB);  //  4 MB [1024][2048] bf16
    short* Whid_t  = (short*)(ws + 16 * MB);  //  2 MB [1024][1024] bf16
    short* eproj   = (short*)(ws + 18 * MB);  //  8 MB [1024][4096] bf16, bias folded, xmap layout
    short* h_a     = (short*)(ws + 26 * MB);  //  1 MB
    short* h_b     = (short*)(ws + 27 * MB);  //  1 MB
    float* cbuf    = (float*)(ws + 28 * MB);  //  2 MB (fallback c; barrier slots + rank counters)
    short* imgs_c  = (short*)(ws + 30 * MB);  //  2 MB [512][2048] bf16
    short* embed_c = (short*)(ws + 32 * MB);  //  1 MB [1024][512] bf16

    u32* bar = (u32*)cbuf;            // zeroed by prep_k every replay (c[k]=0)

    (void)hipFuncSetAttribute((const void*)lstm_all_k,  hipFuncAttributeMaxDynamicSharedMemorySize, 163840);
    (void)hipFuncSetAttribute((const void*)lstm_step_k, hipFuncAttributeMaxDynamicSharedMemorySize, 98304);

    // merged prep: elementwise setup + all four weight transposes (one launch)
    prep_k<<<dim3(3584 + 9216), dim3(256), 0, stream>>>(
        images, imgs_c, embed, embed_c, cbuf, h_a, out0, out1, bimg, bhid,
        Wcell + (size_t)EMBD * FOURH, Wh_t, Wcell, Wx_t, Wimg, Wimg_t, Whid, Whid_t);

    // eproj = bf16(embed @ W_x + b_cell), xmap gate-interleaved (single launch)
    gemm_bt_k<short, false, true><<<dim3(FOURH / 128, VOC / 64, 1), dim3(256), 0, stream>>>(
        embed_c, Wx_t, bcell, eproj, EMBD, EMBD / 64, FOURH);

    // images_encoded: split-K=4 in one launch (grid 8x8x4 = 256 blocks)
    gemm_bt_k<float, true, false><<<dim3(OUTN / 128, BB / 64, 4), dim3(256), 0, stream>>>(
        imgs_c, Wimg_t, nullptr, out0, DIMG, 8, OUTN);

    // all 128 LSTM steps: one persistent kernel (t=127 writes h_a)
    void* kargs[6] = {(void*)&Wh_t, (void*)&eproj, (void*)&msg,
                      (void*)&h_a, (void*)&h_b, (void*)&bar};
    hipError_t ce = hipLaunchCooperativeKernel((const void*)lstm_all_k,
                                               dim3(FOURH / 128, BB / 64, 1), dim3(256, 1, 1),
                                               kargs, 163840, stream);
    if (ce != hipSuccess) {
        for (int t = 0; t < TT; t++) {
            const short* hp = (t & 1) ? h_b : h_a;
            short* hn       = (t & 1) ? h_a : h_b;
            lstm_step_k<<<dim3(FOURH / 128, BB / 64), dim3(256), 98304, stream>>>(
                hp, Wh_t, eproj, msg, t, cbuf, hn);
        }
    }

    // hidden_encoded: split-K=4 in one launch
    gemm_bt_k<float, true, false><<<dim3(OUTN / 128, BB / 64, 4), dim3(256), 0, stream>>>(
        h_a, Whid_t, nullptr, out1, HID, 4, OUTN);
}